// Round 1
// 1165.735 us; speedup vs baseline: 1.0172x; 1.0172x over previous
//
#include <hip/hip_runtime.h>
#include <hip/hip_bf16.h>
#include <math.h>

// Problem constants
#define NB 1024    // batch
#define NAG 64     // agents
#define OBS 128
#define ACTD 16
#define HID 256
#define GD 64
#define NH 4       // heads

typedef short bhalf8 __attribute__((ext_vector_type(8)));
typedef float f32x4 __attribute__((ext_vector_type(4)));

__device__ inline unsigned short f2bf_u(float f) {
  __hip_bfloat16 h = __float2bfloat16(f);
  return *(unsigned short*)&h;
}
__device__ inline float bfu2f(unsigned short u) {
  unsigned v = ((unsigned)u) << 16;
  return *(float*)&v;
}
__device__ inline unsigned pk2(float x, float y) {
  float2 f2; f2.x = x; f2.y = y;
  __hip_bfloat162 h = __float22bfloat162_rn(f2);
  return *(unsigned*)&h;
}

// ---------------- row softmax ----------------
__global__ __launch_bounds__(64) void softmax_rows_k(const float* __restrict__ in,
                                                     float* __restrict__ out, int n) {
  int row = blockIdx.x;
  int lane = threadIdx.x;
  const float* r = in + (size_t)row * n;
  float m = -INFINITY;
  for (int j = lane; j < n; j += 64) m = fmaxf(m, r[j]);
#pragma unroll
  for (int off = 32; off; off >>= 1) m = fmaxf(m, __shfl_xor(m, off));
  float s = 0.f;
  for (int j = lane; j < n; j += 64) s += expf(r[j] - m);
#pragma unroll
  for (int off = 32; off; off >>= 1) s += __shfl_xor(s, off);
  float inv = 1.f / s;
  for (int j = lane; j < n; j += 64) out[(size_t)row * n + j] = expf(r[j] - m) * inv;
}

// ---------------- batched transpose+cvt: in (Z,K,N) f32 -> out (Z,N,K) bf16 ----------------
__global__ __launch_bounds__(256) void transpose_cvt_k(const float* __restrict__ in,
                                                       unsigned short* __restrict__ out,
                                                       int K, int N) {
  __shared__ float t[32][33];
  int k0 = blockIdx.x * 32, n0 = blockIdx.y * 32, z = blockIdx.z;
  int tx = threadIdx.x, ty = threadIdx.y;  // 32 x 8
  const float* ib = in + (size_t)z * K * N;
  unsigned short* ob = out + (size_t)z * N * K;
#pragma unroll
  for (int i = 0; i < 4; ++i) {
    int k = k0 + ty + 8 * i, n = n0 + tx;
    if (k < K && n < N) t[ty + 8 * i][tx] = ib[(size_t)k * N + n];
  }
  __syncthreads();
#pragma unroll
  for (int i = 0; i < 4; ++i) {
    int n = n0 + ty + 8 * i, k = k0 + tx;
    if (n < N && k < K) ob[(size_t)n * K + k] = f2bf_u(t[tx][ty + 8 * i]);
  }
}

// ---------------- GAT weight repack: W (H,F,D) -> WcT bf16 (H*D, F) ----------------
__global__ void repack_wT_k(const float* __restrict__ W, unsigned short* __restrict__ WcT, int F) {
  int idx = blockIdx.x * 256 + threadIdx.x;
  if (idx >= NH * F * 64) return;
  int d = idx & 63;
  int f = (idx >> 6) % F;
  int h = idx / (F * 64);
  WcT[((size_t)(h * 64 + d)) * F + f] = f2bf_u(W[idx]);
}

// ---------------- bf16 MFMA GEMM, 64x64 tile (small-N cases) ----------------
__global__ __launch_bounds__(256) void gemm_mfma_k(
    const float* __restrict__ A, const unsigned short* __restrict__ BT,
    const float* __restrict__ bias, float* __restrict__ C,
    int M, int N, int K,
    long long lda, long long ldc,
    long long aBS, long long btBS, long long biasBS, long long cBS,
    int act, int kPerSplit) {
  __shared__ unsigned short As[64 * 40];
  __shared__ unsigned short Bs[64 * 40];
  int tid = threadIdx.x;
  int wave = tid >> 6, lane = tid & 63;
  int m0 = blockIdx.x * 64, n0 = blockIdx.y * 64;
  int z = blockIdx.z;
  const float* Ab;
  const unsigned short* Bb;
  const float* biasb = nullptr;
  float* Cb;
  int k_begin, k_end;
  if (kPerSplit > 0) {
    Ab = A; Bb = BT; Cb = C + (long long)z * cBS;
    k_begin = z * kPerSplit;
    k_end = k_begin + kPerSplit;
    if (k_end > K) k_end = K;
  } else {
    Ab = A + (long long)z * aBS;
    Bb = BT + (long long)z * btBS;
    if (bias) biasb = bias + (long long)z * biasBS;
    Cb = C + (long long)z * cBS;
    k_begin = 0; k_end = K;
  }
  int sr = tid >> 2;
  int sk = (tid & 3) * 8;
  int fr = lane & 15;
  int kq = (lane >> 4) * 8;

  f32x4 zf = {0.f, 0.f, 0.f, 0.f};
  f32x4 acc[4] = {zf, zf, zf, zf};

  const unsigned short* bRow = Bb + (long long)(n0 + sr) * K;
  bool bValid = (n0 + sr) < N;
  const float* aRow = Ab + (long long)(m0 + sr) * lda;

  for (int k0 = k_begin; k0 < k_end; k0 += 32) {
    int kk = k0 + sk;
    uint4 aw;
    if (kk + 7 < k_end) {
      const float* ap = aRow + kk;
      float4 v0 = *(const float4*)ap;
      float4 v1 = *(const float4*)(ap + 4);
      aw.x = pk2(v0.x, v0.y); aw.y = pk2(v0.z, v0.w);
      aw.z = pk2(v1.x, v1.y); aw.w = pk2(v1.z, v1.w);
    } else {
      float t[8];
#pragma unroll
      for (int j = 0; j < 8; ++j) t[j] = (kk + j < k_end) ? aRow[kk + j] : 0.f;
      aw.x = pk2(t[0], t[1]); aw.y = pk2(t[2], t[3]);
      aw.z = pk2(t[4], t[5]); aw.w = pk2(t[6], t[7]);
    }
    *(uint4*)&As[sr * 40 + sk] = aw;
    uint4 bw = {0u, 0u, 0u, 0u};
    if (bValid) {
      if (kk + 7 < k_end) {
        bw = *(const uint4*)(bRow + kk);
      } else {
        unsigned short tb[8];
#pragma unroll
        for (int j = 0; j < 8; ++j) tb[j] = (kk + j < k_end) ? bRow[kk + j] : (unsigned short)0;
        bw.x = (unsigned)tb[0] | ((unsigned)tb[1] << 16);
        bw.y = (unsigned)tb[2] | ((unsigned)tb[3] << 16);
        bw.z = (unsigned)tb[4] | ((unsigned)tb[5] << 16);
        bw.w = (unsigned)tb[6] | ((unsigned)tb[7] << 16);
      }
    }
    *(uint4*)&Bs[sr * 40 + sk] = bw;
    __syncthreads();
    bhalf8 af = *(bhalf8*)&As[(16 * wave + fr) * 40 + kq];
#pragma unroll
    for (int t = 0; t < 4; ++t) {
      bhalf8 bf = *(bhalf8*)&Bs[(16 * t + fr) * 40 + kq];
      acc[t] = __builtin_amdgcn_mfma_f32_16x16x32_bf16(af, bf, acc[t], 0, 0, 0);
    }
    __syncthreads();
  }
  int rb = (lane >> 4) * 4;
#pragma unroll
  for (int t = 0; t < 4; ++t) {
    int col = n0 + 16 * t + fr;
    if (col < N) {
      float bv = biasb ? biasb[col] : 0.f;
#pragma unroll
      for (int r = 0; r < 4; ++r) {
        long long row = m0 + 16 * wave + rb + r;
        float v = acc[t][r] + bv;
        if (act == 1) v = fmaxf(v, 0.f);
        Cb[row * ldc + col] = v;
      }
    }
  }
}

// ---------------- bf16 MFMA GEMM, 128x128 tile, 4x4 16x16 tiles per wave ----------------
// Requires M % 128 == 0. N guarded. A (M,K) f32; BT (N,K) bf16.
__global__ __launch_bounds__(256) void gemm_mfma128_k(
    const float* __restrict__ A, const unsigned short* __restrict__ BT,
    const float* __restrict__ bias, float* __restrict__ C,
    int M, int N, int K,
    long long lda, long long ldc,
    long long aBS, long long btBS, long long biasBS, long long cBS,
    int act, int kPerSplit) {
  __shared__ unsigned short As[128 * 40];
  __shared__ unsigned short Bs[128 * 40];
  int tid = threadIdx.x;
  int wave = tid >> 6, lane = tid & 63;
  int m0 = blockIdx.x * 128, n0 = blockIdx.y * 128;
  int z = blockIdx.z;
  const float* Ab;
  const unsigned short* Bb;
  const float* biasb = nullptr;
  float* Cb;
  int k_begin, k_end;
  if (kPerSplit > 0) {
    Ab = A; Bb = BT; Cb = C + (long long)z * cBS;
    k_begin = z * kPerSplit;
    k_end = k_begin + kPerSplit;
    if (k_end > K) k_end = K;
  } else {
    Ab = A + (long long)z * aBS;
    Bb = BT + (long long)z * btBS;
    if (bias) biasb = bias + (long long)z * biasBS;
    Cb = C + (long long)z * cBS;
    k_begin = 0; k_end = K;
  }
  int sr = tid >> 1;          // staging row 0..127
  int sk = (tid & 1) * 16;    // k-half
  int mq = (wave >> 1) * 64;  // wave quadrant
  int nq = (wave & 1) * 64;
  int fr = lane & 15;
  int kq = (lane >> 4) * 8;

  f32x4 zf = {0.f, 0.f, 0.f, 0.f};
  f32x4 acc[4][4];
#pragma unroll
  for (int i = 0; i < 4; ++i)
#pragma unroll
    for (int j = 0; j < 4; ++j) acc[i][j] = zf;

  const float* aRow = Ab + (long long)(m0 + sr) * lda;
  const unsigned short* bRow = Bb + (long long)(n0 + sr) * K;
  bool bValid = (n0 + sr) < N;

  for (int k0 = k_begin; k0 < k_end; k0 += 32) {
    int kk = k0 + sk;
    // ---- stage A: 16 floats -> bf16
    uint4 aw0, aw1;
    if (kk + 15 < k_end) {
      const float* ap = aRow + kk;
      float4 v0 = *(const float4*)ap;
      float4 v1 = *(const float4*)(ap + 4);
      float4 v2 = *(const float4*)(ap + 8);
      float4 v3 = *(const float4*)(ap + 12);
      aw0.x = pk2(v0.x, v0.y); aw0.y = pk2(v0.z, v0.w);
      aw0.z = pk2(v1.x, v1.y); aw0.w = pk2(v1.z, v1.w);
      aw1.x = pk2(v2.x, v2.y); aw1.y = pk2(v2.z, v2.w);
      aw1.z = pk2(v3.x, v3.y); aw1.w = pk2(v3.z, v3.w);
    } else {
      float t[16];
#pragma unroll
      for (int j = 0; j < 16; ++j) t[j] = (kk + j < k_end) ? aRow[kk + j] : 0.f;
      aw0.x = pk2(t[0], t[1]);   aw0.y = pk2(t[2], t[3]);
      aw0.z = pk2(t[4], t[5]);   aw0.w = pk2(t[6], t[7]);
      aw1.x = pk2(t[8], t[9]);   aw1.y = pk2(t[10], t[11]);
      aw1.z = pk2(t[12], t[13]); aw1.w = pk2(t[14], t[15]);
    }
    *(uint4*)&As[sr * 40 + sk] = aw0;
    *(uint4*)&As[sr * 40 + sk + 8] = aw1;
    // ---- stage B: 16 bf16 passthrough
    uint4 bw0 = {0u, 0u, 0u, 0u}, bw1 = {0u, 0u, 0u, 0u};
    if (bValid) {
      if (kk + 15 < k_end) {
        bw0 = *(const uint4*)(bRow + kk);
        bw1 = *(const uint4*)(bRow + kk + 8);
      } else {
        unsigned short tb[16];
#pragma unroll
        for (int j = 0; j < 16; ++j) tb[j] = (kk + j < k_end) ? bRow[kk + j] : (unsigned short)0;
        bw0.x = (unsigned)tb[0] | ((unsigned)tb[1] << 16);
        bw0.y = (unsigned)tb[2] | ((unsigned)tb[3] << 16);
        bw0.z = (unsigned)tb[4] | ((unsigned)tb[5] << 16);
        bw0.w = (unsigned)tb[6] | ((unsigned)tb[7] << 16);
        bw1.x = (unsigned)tb[8] | ((unsigned)tb[9] << 16);
        bw1.y = (unsigned)tb[10] | ((unsigned)tb[11] << 16);
        bw1.z = (unsigned)tb[12] | ((unsigned)tb[13] << 16);
        bw1.w = (unsigned)tb[14] | ((unsigned)tb[15] << 16);
      }
    }
    *(uint4*)&Bs[sr * 40 + sk] = bw0;
    *(uint4*)&Bs[sr * 40 + sk + 8] = bw1;
    __syncthreads();
    // ---- compute: 4x4 tiles, 16 MFMA per iter per wave
    bhalf8 af[4], bf[4];
#pragma unroll
    for (int i = 0; i < 4; ++i) af[i] = *(bhalf8*)&As[(mq + 16 * i + fr) * 40 + kq];
#pragma unroll
    for (int j = 0; j < 4; ++j) bf[j] = *(bhalf8*)&Bs[(nq + 16 * j + fr) * 40 + kq];
#pragma unroll
    for (int i = 0; i < 4; ++i)
#pragma unroll
      for (int j = 0; j < 4; ++j)
        acc[i][j] = __builtin_amdgcn_mfma_f32_16x16x32_bf16(af[i], bf[j], acc[i][j], 0, 0, 0);
    __syncthreads();
  }
  // ---- epilogue
  int rb = (lane >> 4) * 4;
#pragma unroll
  for (int j = 0; j < 4; ++j) {
    int col = n0 + nq + 16 * j + fr;
    if (col < N) {
      float bv = biasb ? biasb[col] : 0.f;
#pragma unroll
      for (int i = 0; i < 4; ++i) {
#pragma unroll
        for (int r = 0; r < 4; ++r) {
          long long row = m0 + mq + 16 * i + rb + r;
          float v = acc[i][j][r] + bv;
          if (act == 1) v = fmaxf(v, 0.f);
          Cb[row * ldc + col] = v;
        }
      }
    }
  }
}

// ---------------- GAT attention, 4 waves per graph, head loop inside ----------------
// xt layout: (B*N, NH*GD). mode: 0 = comm = 0.25*sum_h att ; 1 = comm += ; 2 = concat+ELU
// P @ xt aggregation done on MFMA with bf16 hi/lo split (f32-equivalent accuracy):
//   P = P1 + P2, X = X1 + X2  ->  out ~= P1@X1 + P1@X2 + P2@X1  (P2@X2 ~ 2^-18, dropped)
__global__ __launch_bounds__(256) void gat_attn4_k(
    const float* __restrict__ xt, const float* __restrict__ a,
    const float* __restrict__ adj, float* __restrict__ out, int mode) {
  int b = blockIdx.x;
  int tid = threadIdx.x;
  int wave = tid >> 6, lane = tid & 63;
  __shared__ unsigned short xT1[64 * 72];  // xt^T hi  (d-major: [d][j])
  __shared__ unsigned short xT2[64 * 72];  // xt^T lo
  __shared__ unsigned short P1[64 * 72];   // softmax weights hi (row-major: [i][j])
  __shared__ unsigned short P2[64 * 72];   // softmax weights lo
  __shared__ float si_s[64], sj_s[64];

  const float* adjb = adj + (size_t)b * 4096;
  float adjv[16];
#pragma unroll
  for (int r = 0; r < 16; ++r) adjv[r] = adjb[(size_t)(wave * 16 + r) * 64 + lane];

  int lrow = tid >> 2;   // j (agent) this thread stages
  int cg = tid & 3;      // 16-wide column group
  int fr = lane & 15;
  int kq = (lane >> 4) * 8;
  int ibase = wave * 16;

  f32x4 zf = {0.f, 0.f, 0.f, 0.f};
  f32x4 accm[4] = {zf, zf, zf, zf};  // head-mean accum (mode 0/1)

  for (int h = 0; h < 4; ++h) {
    // ---- stage xt -> bf16 hi/lo transposed; fused si/sj projections
    const float* xrow = xt + ((size_t)(b * 64 + lrow)) * 256 + h * 64 + cg * 16;
    const float* ah = a + h * 128;
    float p1 = 0.f, p2 = 0.f;
#pragma unroll
    for (int q = 0; q < 4; ++q) {
      float4 v = *(const float4*)(xrow + 4 * q);
      int c = cg * 16 + 4 * q;
      p1 += v.x * ah[c] + v.y * ah[c + 1] + v.z * ah[c + 2] + v.w * ah[c + 3];
      p2 += v.x * ah[64 + c] + v.y * ah[64 + c + 1] + v.z * ah[64 + c + 2] + v.w * ah[64 + c + 3];
      float vv[4] = {v.x, v.y, v.z, v.w};
#pragma unroll
      for (int u = 0; u < 4; ++u) {
        int d = c + u;
        unsigned short hi = f2bf_u(vv[u]);
        xT1[d * 72 + lrow] = hi;
        xT2[d * 72 + lrow] = f2bf_u(vv[u] - bfu2f(hi));
      }
    }
    p1 += __shfl_xor(p1, 1); p1 += __shfl_xor(p1, 2);
    p2 += __shfl_xor(p2, 1); p2 += __shfl_xor(p2, 2);
    if (cg == 0) { si_s[lrow] = p1; sj_s[lrow] = p2; }
    __syncthreads();

    // ---- softmax rows (wave owns rows ibase..ibase+15; lane = j)
    float sjv = sj_s[lane];
#pragma unroll
    for (int r = 0; r < 16; ++r) {
      int i = ibase + r;
      float e = si_s[i] + sjv;
      e = e > 0.f ? e : 0.2f * e;
      if (adjv[r] == 0.f) e = -INFINITY;
      float mx = e;
#pragma unroll
      for (int off = 32; off; off >>= 1) mx = fmaxf(mx, __shfl_xor(mx, off));
      float p = (e == -INFINITY) ? 0.f : expf(e - mx);
      float sm = p;
#pragma unroll
      for (int off = 32; off; off >>= 1) sm += __shfl_xor(sm, off);
      float w = (sm > 0.f) ? p / sm : 0.f;
      unsigned short whi = f2bf_u(w);
      P1[i * 72 + lane] = whi;
      P2[i * 72 + lane] = f2bf_u(w - bfu2f(whi));
    }
    // P rows for this wave are written/read only by this wave -> no block barrier needed.

    // ---- MFMA aggregation: out[i][d] = sum_j P[i][j] * xt[j][d]
    bhalf8 a1[2], a2[2];
#pragma unroll
    for (int ks = 0; ks < 2; ++ks) {
      a1[ks] = *(bhalf8*)&P1[(ibase + fr) * 72 + ks * 32 + kq];
      a2[ks] = *(bhalf8*)&P2[(ibase + fr) * 72 + ks * 32 + kq];
    }
    f32x4 acc[4] = {zf, zf, zf, zf};
#pragma unroll
    for (int ks = 0; ks < 2; ++ks) {
#pragma unroll
      for (int t = 0; t < 4; ++t) {
        bhalf8 b1 = *(bhalf8*)&xT1[(16 * t + fr) * 72 + ks * 32 + kq];
        bhalf8 b2 = *(bhalf8*)&xT2[(16 * t + fr) * 72 + ks * 32 + kq];
        acc[t] = __builtin_amdgcn_mfma_f32_16x16x32_bf16(a1[ks], b1, acc[t], 0, 0, 0);
        acc[t] = __builtin_amdgcn_mfma_f32_16x16x32_bf16(a1[ks], b2, acc[t], 0, 0, 0);
        acc[t] = __builtin_amdgcn_mfma_f32_16x16x32_bf16(a2[ks], b1, acc[t], 0, 0, 0);
      }
    }
    int rb = (lane >> 4) * 4;
    if (mode == 2) {
#pragma unroll
      for (int t = 0; t < 4; ++t) {
#pragma unroll
        for (int r = 0; r < 4; ++r) {
          int i = ibase + rb + r;
          float v = acc[t][r];
          v = v > 0.f ? v : expf(v) - 1.f;
          out[((size_t)(b * 64 + i)) * 256 + h * 64 + 16 * t + fr] = v;
        }
      }
    } else {
#pragma unroll
      for (int t = 0; t < 4; ++t)
#pragma unroll
        for (int r = 0; r < 4; ++r) accm[t][r] += 0.25f * acc[t][r];
    }
    __syncthreads();  // protect xT/si/sj for next head's staging
  }

  if (mode != 2) {
    int rb = (lane >> 4) * 4;
    float* cb = out + (size_t)b * 4096;
#pragma unroll
    for (int t = 0; t < 4; ++t) {
#pragma unroll
      for (int r = 0; r < 4; ++r) {
        int i = ibase + rb + r;
        int col = 16 * t + fr;
        if (mode == 1) cb[i * 64 + col] += accm[t][r];
        else cb[i * 64 + col] = accm[t][r];
      }
    }
  }
}

// ---------------- ai = [obs, comm] (B,N,192) ----------------
__global__ void build_ai_k(const float* __restrict__ obs, const float* __restrict__ comm,
                           float* __restrict__ ai) {
  size_t idx = (size_t)blockIdx.x * 256 + threadIdx.x;
  if (idx >= (size_t)NB * NAG * 192) return;
  int c = (int)(idx % 192);
  size_t bn = idx / 192;
  ai[idx] = (c < 128) ? obs[bn * 128 + c] : comm[bn * 64 + (c - 128)];
}

// ---------------- combined = [obs, actions] (B,N,144) ----------------
__global__ void build_combined_k(const float* __restrict__ obs, const float* __restrict__ act,
                                 float* __restrict__ cmb) {
  size_t idx = (size_t)blockIdx.x * 256 + threadIdx.x;
  if (idx >= (size_t)NB * NAG * 144) return;
  int c = (int)(idx % 144);
  size_t bn = idx / 144;
  cmb[idx] = (c < 128) ? obs[bn * 128 + c] : act[bn * 16 + (c - 128)];
}

// ---------------- split-K reduce + bias + relu for cent l1 ----------------
__global__ void reduce_bias_relu_k(const float* __restrict__ part, const float* __restrict__ bias,
                                   float* __restrict__ out) {
  int idx = blockIdx.x * 256 + threadIdx.x;
  float s = 0.f;
#pragma unroll
  for (int zz = 0; zz < 16; ++zz) s += part[(size_t)zz * 262144 + idx];
  s += bias[idx & 255];
  out[idx] = fmaxf(s, 0.f);
}

// ---------------- scm_pred = cw @ ce + noise ----------------
__global__ __launch_bounds__(256) void se_noise_k(const float* __restrict__ cw,
                                                  const float* __restrict__ ce,
                                                  const float* __restrict__ nz,
                                                  float* __restrict__ out) {
  int b = blockIdx.x;
  __shared__ float ceL[64 * 128];
  __shared__ float cwL[64 * 64];
  const float* cb = ce + (size_t)b * 8192;
  for (int idx = threadIdx.x; idx < 8192; idx += 256) ceL[idx] = cb[idx];
  for (int idx = threadIdx.x; idx < 4096; idx += 256) cwL[idx] = cw[idx];
  __syncthreads();
  for (int idx = threadIdx.x; idx < 8192; idx += 256) {
    int i = idx >> 7, d = idx & 127;
    float acc = 0.f;
    for (int j = 0; j < 64; ++j) acc += cwL[i * 64 + j] * ceL[j * 128 + d];
    out[(size_t)b * 8192 + idx] = acc + nz[(size_t)b * 8192 + idx];
  }
}

extern "C" void kernel_launch(void* const* d_in, const int* in_sizes, int n_in,
                              void* d_out, int out_size, void* d_ws, size_t ws_size,
                              hipStream_t stream) {
  (void)in_sizes; (void)n_in; (void)out_size; (void)ws_size;
  const float* obs = (const float*)d_in[0];
  const float* acts = (const float*)d_in[1];
  const float* adj = (const float*)d_in[2];
  const float* causal = (const float*)d_in[3];
  const float* gat_W = (const float*)d_in[4];
  const float* gat_a = (const float*)d_in[5];
  const float* cg_W0 = (const float*)d_in[6];
  const float* cg_a0 = (const float*)d_in[7];
  const float* cg_W1 = (const float*)d_in[8];
  const float* cg_a1 = (const float*)d_in[9];
  const float* aw1 = (const float*)d_in[10]; const float* ab1 = (const float*)d_in[11];
  const float* aw2 = (const float*)d_in[12]; const float* ab2 = (const float*)d_in[13];
  const float* aw3 = (const float*)d_in[14]; const float* ab3 = (const float*)d_in[15];
  const float* crw1 = (const float*)d_in[16]; const float* crb1 = (const float*)d_in[17];
  const float* crw2 = (const float*)d_in[18]; const float* crb2 = (const float*)d_in[19];
  const float* crw3 = (const float*)d_in[20]; const float* crb3 = (const float*)d_in[21];
  const float* cew1 = (const float*)d_in[22]; const float* ceb1 = (const float*)d_in[23];
  const float* cew2 = (const float*)d_in[24]; const float* ceb2 = (const float*)d_in[25];
  const float* cew3 = (const float*)d_in[26]; const float* ceb3 = (const float*)d_in[27];
  const float* scm_causal = (const float*)d_in[28];
  const float* mw1 = (const float*)d_in[29]; const float* mb1 = (const float*)d_in[30];
  const float* mw2 = (const float*)d_in[31]; const float* mb2 = (const float*)d_in[32];
  const float* mw3 = (const float*)d_in[33]; const float* mb3 = (const float*)d_in[34];
  const float* nw1 = (const float*)d_in[35]; const float* nb1 = (const float*)d_in[36];
  const float* nw2 = (const float*)d_in[37]; const float* nb2 = (const float*)d_in[38];

  // workspace layout (floats); total 65,515,520 floats = 249.9 MiB
  float* ws = (float*)d_ws;
  float* Ssm  = ws;               // 16384
  float* cwsm = ws + 16384;       // 4096
  float* comm = ws + 20480;       // 4,194,304  (B,N,64)
  float* AI   = ws + 4214784;     // 12,582,912 (B,N,192): ai -> combined -> ce
  float* H1   = ws + 16797696;    // 16,777,216 (B,N,256)
  float* HCG  = ws + 33574912;    // 16,777,216 (B,N,256)
  unsigned short* wbf = (unsigned short*)(ws + 50352128);  // bf16 weights
  unsigned short* SsmT  = wbf;             // 16384
  unsigned short* wcT   = wbf + 16384;     // 65536 (reused per GAT layer)
  unsigned short* aw1T  = wbf + 81920;     // 3,145,728
  unsigned short* aw2T  = wbf + 3227648;   // 4,194,304
  unsigned short* aw3T  = wbf + 7421952;   // 262,144
  unsigned short* crw1T = wbf + 7684096;   // 3,145,728
  unsigned short* crw2T = wbf + 10829824;  // 4,194,304
  unsigned short* crw3T = wbf + 15024128;  // 16,384
  unsigned short* cew1T = wbf + 15040512;  // 2,359,296
  unsigned short* cew2T = wbf + 17399808;  // 65,536
  unsigned short* cew3T = wbf + 17465344;  // 16,384
  unsigned short* mw1T  = wbf + 17481728;  // 2,359,296
  unsigned short* mw2T  = wbf + 19841024;  // 4,194,304
  unsigned short* mw3T  = wbf + 24035328;  // 2,097,152
  unsigned short* nw1T  = wbf + 26132480;  // 2,097,152
  unsigned short* nw2T  = wbf + 28229632;  // 2,097,152

  float* out_actor = (float*)d_out;
  float* out_critic = out_actor + 1048576;
  float* out_cent = out_critic + 65536;
  float* out_scm = out_cent + 65536;

  auto GEMM64 = [&](const float* A, const unsigned short* BT, const float* bias, float* C,
                    int M, int N, int K, long long lda, long long ldc,
                    long long aBS, long long btBS, long long biasBS, long long cBS,
                    int act, int gz, int kPerSplit) {
    dim3 grid(M / 64, (N + 63) / 64, gz);
    hipLaunchKernelGGL(gemm_mfma_k, grid, dim3(256), 0, stream, A, BT, bias, C, M, N, K,
                       lda, ldc, aBS, btBS, biasBS, cBS, act, kPerSplit);
  };
  auto GEMM128 = [&](const float* A, const unsigned short* BT, const float* bias, float* C,
                     int M, int N, int K, long long lda, long long ldc,
                     long long aBS, long long btBS, long long biasBS, long long cBS,
                     int act, int gz, int kPerSplit) {
    dim3 grid(M / 128, (N + 127) / 128, gz);
    hipLaunchKernelGGL(gemm_mfma128_k, grid, dim3(256), 0, stream, A, BT, bias, C, M, N, K,
                       lda, ldc, aBS, btBS, biasBS, cBS, act, kPerSplit);
  };
  auto TRN = [&](const float* in, unsigned short* out, int Z, int K, int N) {
    dim3 grid((K + 31) / 32, (N + 31) / 32, Z);
    hipLaunchKernelGGL(transpose_cvt_k, grid, dim3(32, 8), 0, stream, in, out, K, N);
  };

  // 0) small softmaxes + weight conversions (one-time per launch)
  hipLaunchKernelGGL(softmax_rows_k, dim3(128), dim3(64), 0, stream, causal, Ssm, 128);
  hipLaunchKernelGGL(softmax_rows_k, dim3(64), dim3(64), 0, stream, scm_causal, cwsm, 64);
  TRN(Ssm, SsmT, 1, 128, 128);
  TRN(aw1, aw1T, 64, 192, 256);  TRN(aw2, aw2T, 64, 256, 256);  TRN(aw3, aw3T, 64, 256, 16);
  TRN(crw1, crw1T, 64, 192, 256); TRN(crw2, crw2T, 64, 256, 256); TRN(crw3, crw3T, 64, 256, 1);
  TRN(cew1, cew1T, 1, 9216, 256); TRN(cew2, cew2T, 1, 256, 256);  TRN(cew3, cew3T, 1, 256, 64);
  TRN(mw1, mw1T, 64, 144, 256);  TRN(mw2, mw2T, 64, 256, 256);  TRN(mw3, mw3T, 64, 256, 128);
  TRN(nw1, nw1T, 64, 128, 256);  TRN(nw2, nw2T, 64, 256, 128);

  // 1) plain GAT -> comm (init)
  hipLaunchKernelGGL(repack_wT_k, dim3((NH * 128 * 64 + 255) / 256), dim3(256), 0, stream, gat_W, wcT, 128);
  GEMM128(obs, wcT, nullptr, H1, 65536, 256, 128, 128, 256, 0, 0, 0, 0, 0, 1, 0);     // xt1
  hipLaunchKernelGGL(gat_attn4_k, dim3(1024), dim3(256), 0, stream, H1, gat_a, adj, comm, 0);

  // 2) causal GAT
  GEMM128(obs, SsmT, nullptr, HCG, 65536, 128, 128, 128, 128, 0, 0, 0, 0, 0, 1, 0);   // xm
  hipLaunchKernelGGL(repack_wT_k, dim3((NH * 128 * 64 + 255) / 256), dim3(256), 0, stream, cg_W0, wcT, 128);
  GEMM128(HCG, wcT, nullptr, H1, 65536, 256, 128, 128, 256, 0, 0, 0, 0, 0, 1, 0);     // xt_cg0
  hipLaunchKernelGGL(gat_attn4_k, dim3(1024), dim3(256), 0, stream, H1, cg_a0, adj, HCG, 2); // hcg (ELU)
  hipLaunchKernelGGL(repack_wT_k, dim3((NH * 256 * 64 + 255) / 256), dim3(256), 0, stream, cg_W1, wcT, 256);
  GEMM128(HCG, wcT, nullptr, H1, 65536, 256, 256, 256, 256, 0, 0, 0, 0, 0, 1, 0);     // xt_cg1
  hipLaunchKernelGGL(gat_attn4_k, dim3(1024), dim3(256), 0, stream, H1, cg_a1, adj, comm, 1);

  // 3) ai = [obs, comm]
  hipLaunchKernelGGL(build_ai_k, dim3((12582912 + 255) / 256), dim3(256), 0, stream, obs, comm, AI);

  // 4) actor MLP (per-agent)
  GEMM128(AI, aw1T, ab1, H1, 1024, 256, 192, 12288, 16384, 192, 49152, 256, 256, 1, 64, 0);
  GEMM128(H1, aw2T, ab2, HCG, 1024, 256, 256, 16384, 16384, 256, 65536, 256, 256, 1, 64, 0);
  GEMM64(HCG, aw3T, ab3, out_actor, 1024, 16, 256, 16384, 1024, 256, 4096, 16, 16, 0, 64, 0);

  // 5) critic MLP (per-agent)
  GEMM128(AI, crw1T, crb1, H1, 1024, 256, 192, 12288, 16384, 192, 49152, 256, 256, 1, 64, 0);
  GEMM128(H1, crw2T, crb2, HCG, 1024, 256, 256, 16384, 16384, 256, 65536, 256, 256, 1, 64, 0);
  GEMM64(HCG, crw3T, crb3, out_critic, 1024, 1, 256, 16384, 64, 256, 256, 1, 1, 0, 64, 0);

  // 6) centralized critic (combined -> AI)
  hipLaunchKernelGGL(build_combined_k, dim3((9437184 + 255) / 256), dim3(256), 0, stream, obs, acts, AI);
  GEMM128(AI, cew1T, nullptr, H1, 1024, 256, 9216, 9216, 256, 0, 0, 0, 262144, 0, 16, 576);
  hipLaunchKernelGGL(reduce_bias_relu_k, dim3(1024), dim3(256), 0, stream, H1, ceb1, HCG);
  GEMM64(HCG, cew2T, ceb2, H1, 1024, 256, 256, 256, 256, 0, 0, 0, 0, 1, 1, 0);
  GEMM64(H1, cew3T, ceb3, out_cent, 1024, 64, 256, 256, 64, 0, 0, 0, 0, 0, 1, 0);

  // 7) SCM mechanisms (input = combined in AI)
  GEMM128(AI, mw1T, mb1, H1, 1024, 256, 144, 9216, 16384, 144, 36864, 256, 256, 1, 64, 0);
  GEMM128(H1, mw2T, mb2, HCG, 1024, 256, 256, 16384, 16384, 256, 65536, 256, 256, 1, 64, 0);
  GEMM128(HCG, mw3T, mb3, AI, 1024, 128, 256, 16384, 8192, 256, 32768, 128, 128, 0, 64, 0); // ce -> AI

  // 8) noise model (input = obs)
  GEMM128(obs, nw1T, nb1, H1, 1024, 256, 128, 8192, 16384, 128, 32768, 256, 256, 1, 64, 0);
  GEMM128(H1, nw2T, nb2, HCG, 1024, 128, 256, 16384, 8192, 256, 32768, 128, 128, 0, 64, 0); // noise -> HCG

  // 9) scm_pred = softmax(scm_causal) @ ce + noise
  hipLaunchKernelGGL(se_noise_k, dim3(1024), dim3(256), 0, stream, cwsm, AI, HCG, out_scm);
}

// Round 2
// 1027.164 us; speedup vs baseline: 1.1544x; 1.1349x over previous
//
#include <hip/hip_runtime.h>
#include <hip/hip_bf16.h>
#include <math.h>

// Problem constants
#define NB 1024    // batch
#define NAG 64     // agents
#define OBS 128
#define ACTD 16
#define HID 256
#define GD 64
#define NH 4       // heads

typedef short bhalf8 __attribute__((ext_vector_type(8)));
typedef float f32x4 __attribute__((ext_vector_type(4)));

__device__ inline unsigned short f2bf_u(float f) {
  __hip_bfloat16 h = __float2bfloat16(f);
  return *(unsigned short*)&h;
}
__device__ inline float bfu2f(unsigned short u) {
  unsigned v = ((unsigned)u) << 16;
  return *(float*)&v;
}
__device__ inline unsigned pk2(float x, float y) {
  float2 f2; f2.x = x; f2.y = y;
  __hip_bfloat162 h = __float22bfloat162_rn(f2);
  return *(unsigned*)&h;
}

// ---------------- row softmax ----------------
__global__ __launch_bounds__(64) void softmax_rows_k(const float* __restrict__ in,
                                                     float* __restrict__ out, int n) {
  int row = blockIdx.x;
  int lane = threadIdx.x;
  const float* r = in + (size_t)row * n;
  float m = -INFINITY;
  for (int j = lane; j < n; j += 64) m = fmaxf(m, r[j]);
#pragma unroll
  for (int off = 32; off; off >>= 1) m = fmaxf(m, __shfl_xor(m, off));
  float s = 0.f;
  for (int j = lane; j < n; j += 64) s += expf(r[j] - m);
#pragma unroll
  for (int off = 32; off; off >>= 1) s += __shfl_xor(s, off);
  float inv = 1.f / s;
  for (int j = lane; j < n; j += 64) out[(size_t)row * n + j] = expf(r[j] - m) * inv;
}

// ---------------- batched transpose+cvt: in (Z,K,N) f32 -> out (Z,N,K) bf16 ----------------
__global__ __launch_bounds__(256) void transpose_cvt_k(const float* __restrict__ in,
                                                       unsigned short* __restrict__ out,
                                                       int K, int N) {
  __shared__ float t[32][33];
  int k0 = blockIdx.x * 32, n0 = blockIdx.y * 32, z = blockIdx.z;
  int tx = threadIdx.x, ty = threadIdx.y;  // 32 x 8
  const float* ib = in + (size_t)z * K * N;
  unsigned short* ob = out + (size_t)z * N * K;
#pragma unroll
  for (int i = 0; i < 4; ++i) {
    int k = k0 + ty + 8 * i, n = n0 + tx;
    if (k < K && n < N) t[ty + 8 * i][tx] = ib[(size_t)k * N + n];
  }
  __syncthreads();
#pragma unroll
  for (int i = 0; i < 4; ++i) {
    int n = n0 + ty + 8 * i, k = k0 + tx;
    if (n < N && k < K) ob[(size_t)n * K + k] = f2bf_u(t[tx][ty + 8 * i]);
  }
}

// ---------------- GAT weight repack: W (H,F,D) -> WcT bf16 (H*D, F) ----------------
__global__ void repack_wT_k(const float* __restrict__ W, unsigned short* __restrict__ WcT, int F) {
  int idx = blockIdx.x * 256 + threadIdx.x;
  if (idx >= NH * F * 64) return;
  int d = idx & 63;
  int f = (idx >> 6) % F;
  int h = idx / (F * 64);
  WcT[((size_t)(h * 64 + d)) * F + f] = f2bf_u(W[idx]);
}

// ---------------- bf16 MFMA GEMM, 64x64 tile (small-N cases) ----------------
__global__ __launch_bounds__(256) void gemm_mfma_k(
    const float* __restrict__ A, const unsigned short* __restrict__ BT,
    const float* __restrict__ bias, float* __restrict__ C,
    int M, int N, int K,
    long long lda, long long ldc,
    long long aBS, long long btBS, long long biasBS, long long cBS,
    int act, int kPerSplit) {
  __shared__ unsigned short As[64 * 40];
  __shared__ unsigned short Bs[64 * 40];
  int tid = threadIdx.x;
  int wave = tid >> 6, lane = tid & 63;
  int m0 = blockIdx.x * 64, n0 = blockIdx.y * 64;
  int z = blockIdx.z;
  const float* Ab;
  const unsigned short* Bb;
  const float* biasb = nullptr;
  float* Cb;
  int k_begin, k_end;
  if (kPerSplit > 0) {
    Ab = A; Bb = BT; Cb = C + (long long)z * cBS;
    k_begin = z * kPerSplit;
    k_end = k_begin + kPerSplit;
    if (k_end > K) k_end = K;
  } else {
    Ab = A + (long long)z * aBS;
    Bb = BT + (long long)z * btBS;
    if (bias) biasb = bias + (long long)z * biasBS;
    Cb = C + (long long)z * cBS;
    k_begin = 0; k_end = K;
  }
  int sr = tid >> 2;
  int sk = (tid & 3) * 8;
  int fr = lane & 15;
  int kq = (lane >> 4) * 8;

  f32x4 zf = {0.f, 0.f, 0.f, 0.f};
  f32x4 acc[4] = {zf, zf, zf, zf};

  const unsigned short* bRow = Bb + (long long)(n0 + sr) * K;
  bool bValid = (n0 + sr) < N;
  const float* aRow = Ab + (long long)(m0 + sr) * lda;

  for (int k0 = k_begin; k0 < k_end; k0 += 32) {
    int kk = k0 + sk;
    uint4 aw;
    if (kk + 7 < k_end) {
      const float* ap = aRow + kk;
      float4 v0 = *(const float4*)ap;
      float4 v1 = *(const float4*)(ap + 4);
      aw.x = pk2(v0.x, v0.y); aw.y = pk2(v0.z, v0.w);
      aw.z = pk2(v1.x, v1.y); aw.w = pk2(v1.z, v1.w);
    } else {
      float t[8];
#pragma unroll
      for (int j = 0; j < 8; ++j) t[j] = (kk + j < k_end) ? aRow[kk + j] : 0.f;
      aw.x = pk2(t[0], t[1]); aw.y = pk2(t[2], t[3]);
      aw.z = pk2(t[4], t[5]); aw.w = pk2(t[6], t[7]);
    }
    *(uint4*)&As[sr * 40 + sk] = aw;
    uint4 bw = {0u, 0u, 0u, 0u};
    if (bValid) {
      if (kk + 7 < k_end) {
        bw = *(const uint4*)(bRow + kk);
      } else {
        unsigned short tb[8];
#pragma unroll
        for (int j = 0; j < 8; ++j) tb[j] = (kk + j < k_end) ? bRow[kk + j] : (unsigned short)0;
        bw.x = (unsigned)tb[0] | ((unsigned)tb[1] << 16);
        bw.y = (unsigned)tb[2] | ((unsigned)tb[3] << 16);
        bw.z = (unsigned)tb[4] | ((unsigned)tb[5] << 16);
        bw.w = (unsigned)tb[6] | ((unsigned)tb[7] << 16);
      }
    }
    *(uint4*)&Bs[sr * 40 + sk] = bw;
    __syncthreads();
    bhalf8 af = *(bhalf8*)&As[(16 * wave + fr) * 40 + kq];
#pragma unroll
    for (int t = 0; t < 4; ++t) {
      bhalf8 bf = *(bhalf8*)&Bs[(16 * t + fr) * 40 + kq];
      acc[t] = __builtin_amdgcn_mfma_f32_16x16x32_bf16(af, bf, acc[t], 0, 0, 0);
    }
    __syncthreads();
  }
  int rb = (lane >> 4) * 4;
#pragma unroll
  for (int t = 0; t < 4; ++t) {
    int col = n0 + 16 * t + fr;
    if (col < N) {
      float bv = biasb ? biasb[col] : 0.f;
#pragma unroll
      for (int r = 0; r < 4; ++r) {
        long long row = m0 + 16 * wave + rb + r;
        float v = acc[t][r] + bv;
        if (act == 1) v = fmaxf(v, 0.f);
        Cb[row * ldc + col] = v;
      }
    }
  }
}

// ---------------- bf16 MFMA GEMM, 128x128 tile, 4x4 16x16 tiles per wave ----------------
// Requires M % 128 == 0. N guarded. A (M,K) f32; BT (N,K) bf16.
__global__ __launch_bounds__(256) void gemm_mfma128_k(
    const float* __restrict__ A, const unsigned short* __restrict__ BT,
    const float* __restrict__ bias, float* __restrict__ C,
    int M, int N, int K,
    long long lda, long long ldc,
    long long aBS, long long btBS, long long biasBS, long long cBS,
    int act, int kPerSplit) {
  __shared__ unsigned short As[128 * 40];
  __shared__ unsigned short Bs[128 * 40];
  int tid = threadIdx.x;
  int wave = tid >> 6, lane = tid & 63;
  int m0 = blockIdx.x * 128, n0 = blockIdx.y * 128;
  int z = blockIdx.z;
  const float* Ab;
  const unsigned short* Bb;
  const float* biasb = nullptr;
  float* Cb;
  int k_begin, k_end;
  if (kPerSplit > 0) {
    Ab = A; Bb = BT; Cb = C + (long long)z * cBS;
    k_begin = z * kPerSplit;
    k_end = k_begin + kPerSplit;
    if (k_end > K) k_end = K;
  } else {
    Ab = A + (long long)z * aBS;
    Bb = BT + (long long)z * btBS;
    if (bias) biasb = bias + (long long)z * biasBS;
    Cb = C + (long long)z * cBS;
    k_begin = 0; k_end = K;
  }
  int sr = tid >> 1;          // staging row 0..127
  int sk = (tid & 1) * 16;    // k-half
  int mq = (wave >> 1) * 64;  // wave quadrant
  int nq = (wave & 1) * 64;
  int fr = lane & 15;
  int kq = (lane >> 4) * 8;

  f32x4 zf = {0.f, 0.f, 0.f, 0.f};
  f32x4 acc[4][4];
#pragma unroll
  for (int i = 0; i < 4; ++i)
#pragma unroll
    for (int j = 0; j < 4; ++j) acc[i][j] = zf;

  const float* aRow = Ab + (long long)(m0 + sr) * lda;
  const unsigned short* bRow = Bb + (long long)(n0 + sr) * K;
  bool bValid = (n0 + sr) < N;

  for (int k0 = k_begin; k0 < k_end; k0 += 32) {
    int kk = k0 + sk;
    // ---- stage A: 16 floats -> bf16
    uint4 aw0, aw1;
    if (kk + 15 < k_end) {
      const float* ap = aRow + kk;
      float4 v0 = *(const float4*)ap;
      float4 v1 = *(const float4*)(ap + 4);
      float4 v2 = *(const float4*)(ap + 8);
      float4 v3 = *(const float4*)(ap + 12);
      aw0.x = pk2(v0.x, v0.y); aw0.y = pk2(v0.z, v0.w);
      aw0.z = pk2(v1.x, v1.y); aw0.w = pk2(v1.z, v1.w);
      aw1.x = pk2(v2.x, v2.y); aw1.y = pk2(v2.z, v2.w);
      aw1.z = pk2(v3.x, v3.y); aw1.w = pk2(v3.z, v3.w);
    } else {
      float t[16];
#pragma unroll
      for (int j = 0; j < 16; ++j) t[j] = (kk + j < k_end) ? aRow[kk + j] : 0.f;
      aw0.x = pk2(t[0], t[1]);   aw0.y = pk2(t[2], t[3]);
      aw0.z = pk2(t[4], t[5]);   aw0.w = pk2(t[6], t[7]);
      aw1.x = pk2(t[8], t[9]);   aw1.y = pk2(t[10], t[11]);
      aw1.z = pk2(t[12], t[13]); aw1.w = pk2(t[14], t[15]);
    }
    *(uint4*)&As[sr * 40 + sk] = aw0;
    *(uint4*)&As[sr * 40 + sk + 8] = aw1;
    // ---- stage B: 16 bf16 passthrough
    uint4 bw0 = {0u, 0u, 0u, 0u}, bw1 = {0u, 0u, 0u, 0u};
    if (bValid) {
      if (kk + 15 < k_end) {
        bw0 = *(const uint4*)(bRow + kk);
        bw1 = *(const uint4*)(bRow + kk + 8);
      } else {
        unsigned short tb[16];
#pragma unroll
        for (int j = 0; j < 16; ++j) tb[j] = (kk + j < k_end) ? bRow[kk + j] : (unsigned short)0;
        bw0.x = (unsigned)tb[0] | ((unsigned)tb[1] << 16);
        bw0.y = (unsigned)tb[2] | ((unsigned)tb[3] << 16);
        bw0.z = (unsigned)tb[4] | ((unsigned)tb[5] << 16);
        bw0.w = (unsigned)tb[6] | ((unsigned)tb[7] << 16);
        bw1.x = (unsigned)tb[8] | ((unsigned)tb[9] << 16);
        bw1.y = (unsigned)tb[10] | ((unsigned)tb[11] << 16);
        bw1.z = (unsigned)tb[12] | ((unsigned)tb[13] << 16);
        bw1.w = (unsigned)tb[14] | ((unsigned)tb[15] << 16);
      }
    }
    *(uint4*)&Bs[sr * 40 + sk] = bw0;
    *(uint4*)&Bs[sr * 40 + sk + 8] = bw1;
    __syncthreads();
    // ---- compute: 4x4 tiles, 16 MFMA per iter per wave
    bhalf8 af[4], bf[4];
#pragma unroll
    for (int i = 0; i < 4; ++i) af[i] = *(bhalf8*)&As[(mq + 16 * i + fr) * 40 + kq];
#pragma unroll
    for (int j = 0; j < 4; ++j) bf[j] = *(bhalf8*)&Bs[(nq + 16 * j + fr) * 40 + kq];
#pragma unroll
    for (int i = 0; i < 4; ++i)
#pragma unroll
      for (int j = 0; j < 4; ++j)
        acc[i][j] = __builtin_amdgcn_mfma_f32_16x16x32_bf16(af[i], bf[j], acc[i][j], 0, 0, 0);
    __syncthreads();
  }
  // ---- epilogue
  int rb = (lane >> 4) * 4;
#pragma unroll
  for (int j = 0; j < 4; ++j) {
    int col = n0 + nq + 16 * j + fr;
    if (col < N) {
      float bv = biasb ? biasb[col] : 0.f;
#pragma unroll
      for (int i = 0; i < 4; ++i) {
#pragma unroll
        for (int r = 0; r < 4; ++r) {
          long long row = m0 + mq + 16 * i + rb + r;
          float v = acc[i][j][r] + bv;
          if (act == 1) v = fmaxf(v, 0.f);
          Cb[row * ldc + col] = v;
        }
      }
    }
  }
}

// ---------------- GAT attention, 4 waves per graph, head loop inside ----------------
// xt layout: (B*N, NH*GD). mode: 0 = comm = 0.25*sum_h att ; 1 = comm += ; 2 = concat+ELU
// v3: X^T staged from global column loads (L2-hot re-read), pitch-72 b128 LDS writes
//     (8-phase optimal). No per-row max (monotone leaky bound Mi) and no per-row sum
//     reduction (row sums via all-ones MFMA B-fragment, replicated to all lanes).
//     Unnormalized p stored bf16 hi/lo; normalize by 1/rowsum in f32 epilogue.
__global__ __launch_bounds__(256, 4) void gat_attn4_k(
    const float* __restrict__ xt, const float* __restrict__ a,
    const float* __restrict__ adj, float* __restrict__ out, int mode) {
  int b = blockIdx.x;
  int tid = threadIdx.x;
  int wave = tid >> 6, lane = tid & 63;
  __shared__ unsigned short xT1[64 * 72];  // X^T hi  [d][j]
  __shared__ unsigned short xT2[64 * 72];  // X^T lo
  __shared__ unsigned short P1[64 * 72];   // exp weights hi [i][j]
  __shared__ unsigned short P2[64 * 72];   // exp weights lo
  __shared__ float si_s[64], sj_s[64];

  const float* adjb = adj + (size_t)b * 4096;
  float adjv[16];
#pragma unroll
  for (int r = 0; r < 16; ++r) adjv[r] = adjb[(size_t)(wave * 16 + r) * 64 + lane];

  int lrow = tid >> 2;   // j (agent) this thread projects (phase A1)
  int cg = tid & 3;      // 16-wide column group
  int fr = lane & 15;
  int kq = (lane >> 4) * 8;
  int ibase = wave * 16;

  bhalf8 ones;
#pragma unroll
  for (int u = 0; u < 8; ++u) ones[u] = (short)0x3F80;  // 1.0 bf16

  f32x4 zf = {0.f, 0.f, 0.f, 0.f};
  f32x4 accm[4] = {zf, zf, zf, zf};  // head-mean accum (mode 0/1)

  for (int h = 0; h < 4; ++h) {
    // ---- A2 loads: column gather for X^T (coalesced across lanes; L2-hot)
    const float* xcol = xt + ((size_t)(b * 64 + 16 * wave)) * 256 + h * 64 + lane;
    float v[16];
#pragma unroll
    for (int u = 0; u < 16; ++u) v[u] = xcol[(size_t)u * 256];

    // ---- A1: si/sj projections (row loads)
    const float* xrow = xt + ((size_t)(b * 64 + lrow)) * 256 + h * 64 + cg * 16;
    const float* ah = a + h * 128;
    float p1 = 0.f, p2 = 0.f;
#pragma unroll
    for (int q = 0; q < 4; ++q) {
      float4 rv = *(const float4*)(xrow + 4 * q);
      int c = cg * 16 + 4 * q;
      p1 += rv.x * ah[c] + rv.y * ah[c + 1] + rv.z * ah[c + 2] + rv.w * ah[c + 3];
      p2 += rv.x * ah[64 + c] + rv.y * ah[64 + c + 1] + rv.z * ah[64 + c + 2] + rv.w * ah[64 + c + 3];
    }
    p1 += __shfl_xor(p1, 1); p1 += __shfl_xor(p1, 2);
    p2 += __shfl_xor(p2, 1); p2 += __shfl_xor(p2, 2);
    if (cg == 0) { si_s[lrow] = p1; sj_s[lrow] = p2; }

    // ---- A2 stores: cvt hi/lo, pack, b128 writes (row d=lane, j block 16*wave)
    {
      float hf[16];
      uint4 h0, h1, l0, l1;
#pragma unroll
      for (int u = 0; u < 16; ++u) hf[u] = bfu2f(f2bf_u(v[u]));
      h0.x = pk2(hf[0], hf[1]);   h0.y = pk2(hf[2], hf[3]);
      h0.z = pk2(hf[4], hf[5]);   h0.w = pk2(hf[6], hf[7]);
      h1.x = pk2(hf[8], hf[9]);   h1.y = pk2(hf[10], hf[11]);
      h1.z = pk2(hf[12], hf[13]); h1.w = pk2(hf[14], hf[15]);
      l0.x = pk2(v[0] - hf[0], v[1] - hf[1]);     l0.y = pk2(v[2] - hf[2], v[3] - hf[3]);
      l0.z = pk2(v[4] - hf[4], v[5] - hf[5]);     l0.w = pk2(v[6] - hf[6], v[7] - hf[7]);
      l1.x = pk2(v[8] - hf[8], v[9] - hf[9]);     l1.y = pk2(v[10] - hf[10], v[11] - hf[11]);
      l1.z = pk2(v[12] - hf[12], v[13] - hf[13]); l1.w = pk2(v[14] - hf[14], v[15] - hf[15]);
      int base = lane * 72 + 16 * wave;
      *(uint4*)&xT1[base] = h0;
      *(uint4*)&xT1[base + 8] = h1;
      *(uint4*)&xT2[base] = l0;
      *(uint4*)&xT2[base + 8] = l1;
    }
    __syncthreads();

    // ---- B: per-row exp weights, no reductions
    float sjv = sj_s[lane];
    float maxsj = sjv;
#pragma unroll
    for (int off = 32; off; off >>= 1) maxsj = fmaxf(maxsj, __shfl_xor(maxsj, off));
#pragma unroll
    for (int r = 0; r < 16; ++r) {
      int i = ibase + r;
      float siv = si_s[i];
      float tM = siv + maxsj;
      float Mi = tM > 0.f ? tM : 0.2f * tM;   // >= max_j e (leaky monotone)
      float e = siv + sjv;
      e = e > 0.f ? e : 0.2f * e;
      float p = (adjv[r] == 0.f) ? 0.f : expf(e - Mi);
      unsigned short phi = f2bf_u(p);
      P1[i * 72 + lane] = phi;
      P2[i * 72 + lane] = f2bf_u(p - bfu2f(phi));
    }
    // P rows are wave-local (written and read by the same wave) -> no barrier.

    // ---- C: MFMA aggregation + row sums
    bhalf8 a1[2], a2[2];
#pragma unroll
    for (int ks = 0; ks < 2; ++ks) {
      a1[ks] = *(bhalf8*)&P1[(ibase + fr) * 72 + ks * 32 + kq];
      a2[ks] = *(bhalf8*)&P2[(ibase + fr) * 72 + ks * 32 + kq];
    }
    f32x4 accS = zf;
#pragma unroll
    for (int ks = 0; ks < 2; ++ks) {
      accS = __builtin_amdgcn_mfma_f32_16x16x32_bf16(a1[ks], ones, accS, 0, 0, 0);
      accS = __builtin_amdgcn_mfma_f32_16x16x32_bf16(a2[ks], ones, accS, 0, 0, 0);
    }
    f32x4 acc[4] = {zf, zf, zf, zf};
#pragma unroll
    for (int ks = 0; ks < 2; ++ks) {
#pragma unroll
      for (int t = 0; t < 4; ++t) {
        bhalf8 b1 = *(bhalf8*)&xT1[(16 * t + fr) * 72 + ks * 32 + kq];
        bhalf8 b2 = *(bhalf8*)&xT2[(16 * t + fr) * 72 + ks * 32 + kq];
        acc[t] = __builtin_amdgcn_mfma_f32_16x16x32_bf16(a1[ks], b1, acc[t], 0, 0, 0);
        acc[t] = __builtin_amdgcn_mfma_f32_16x16x32_bf16(a1[ks], b2, acc[t], 0, 0, 0);
        acc[t] = __builtin_amdgcn_mfma_f32_16x16x32_bf16(a2[ks], b1, acc[t], 0, 0, 0);
      }
    }
    f32x4 inv;
#pragma unroll
    for (int r = 0; r < 4; ++r) inv[r] = (accS[r] > 0.f) ? 1.f / accS[r] : 0.f;

    int rb = (lane >> 4) * 4;
    if (mode == 2) {
#pragma unroll
      for (int t = 0; t < 4; ++t) {
#pragma unroll
        for (int r = 0; r < 4; ++r) {
          int i = ibase + rb + r;
          float vv = acc[t][r] * inv[r];
          vv = vv > 0.f ? vv : expf(vv) - 1.f;
          out[((size_t)(b * 64 + i)) * 256 + h * 64 + 16 * t + fr] = vv;
        }
      }
    } else {
#pragma unroll
      for (int t = 0; t < 4; ++t)
#pragma unroll
        for (int r = 0; r < 4; ++r) accm[t][r] += 0.25f * acc[t][r] * inv[r];
    }
    __syncthreads();  // xT/si/sj reuse for next head
  }

  if (mode != 2) {
    int rb = (lane >> 4) * 4;
    float* cb = out + (size_t)b * 4096;
#pragma unroll
    for (int t = 0; t < 4; ++t) {
#pragma unroll
      for (int r = 0; r < 4; ++r) {
        int i = ibase + rb + r;
        int col = 16 * t + fr;
        if (mode == 1) cb[i * 64 + col] += accm[t][r];
        else cb[i * 64 + col] = accm[t][r];
      }
    }
  }
}

// ---------------- ai = [obs, comm] (B,N,192) ----------------
__global__ void build_ai_k(const float* __restrict__ obs, const float* __restrict__ comm,
                           float* __restrict__ ai) {
  size_t idx = (size_t)blockIdx.x * 256 + threadIdx.x;
  if (idx >= (size_t)NB * NAG * 192) return;
  int c = (int)(idx % 192);
  size_t bn = idx / 192;
  ai[idx] = (c < 128) ? obs[bn * 128 + c] : comm[bn * 64 + (c - 128)];
}

// ---------------- combined = [obs, actions] (B,N,144) ----------------
__global__ void build_combined_k(const float* __restrict__ obs, const float* __restrict__ act,
                                 float* __restrict__ cmb) {
  size_t idx = (size_t)blockIdx.x * 256 + threadIdx.x;
  if (idx >= (size_t)NB * NAG * 144) return;
  int c = (int)(idx % 144);
  size_t bn = idx / 144;
  cmb[idx] = (c < 128) ? obs[bn * 128 + c] : act[bn * 16 + (c - 128)];
}

// ---------------- split-K reduce + bias + relu for cent l1 ----------------
__global__ void reduce_bias_relu_k(const float* __restrict__ part, const float* __restrict__ bias,
                                   float* __restrict__ out) {
  int idx = blockIdx.x * 256 + threadIdx.x;
  float s = 0.f;
#pragma unroll
  for (int zz = 0; zz < 16; ++zz) s += part[(size_t)zz * 262144 + idx];
  s += bias[idx & 255];
  out[idx] = fmaxf(s, 0.f);
}

// ---------------- scm_pred = cw @ ce + noise ----------------
__global__ __launch_bounds__(256) void se_noise_k(const float* __restrict__ cw,
                                                  const float* __restrict__ ce,
                                                  const float* __restrict__ nz,
                                                  float* __restrict__ out) {
  int b = blockIdx.x;
  __shared__ float ceL[64 * 128];
  __shared__ float cwL[64 * 64];
  const float* cb = ce + (size_t)b * 8192;
  for (int idx = threadIdx.x; idx < 8192; idx += 256) ceL[idx] = cb[idx];
  for (int idx = threadIdx.x; idx < 4096; idx += 256) cwL[idx] = cw[idx];
  __syncthreads();
  for (int idx = threadIdx.x; idx < 8192; idx += 256) {
    int i = idx >> 7, d = idx & 127;
    float acc = 0.f;
    for (int j = 0; j < 64; ++j) acc += cwL[i * 64 + j] * ceL[j * 128 + d];
    out[(size_t)b * 8192 + idx] = acc + nz[(size_t)b * 8192 + idx];
  }
}

extern "C" void kernel_launch(void* const* d_in, const int* in_sizes, int n_in,
                              void* d_out, int out_size, void* d_ws, size_t ws_size,
                              hipStream_t stream) {
  (void)in_sizes; (void)n_in; (void)out_size; (void)ws_size;
  const float* obs = (const float*)d_in[0];
  const float* acts = (const float*)d_in[1];
  const float* adj = (const float*)d_in[2];
  const float* causal = (const float*)d_in[3];
  const float* gat_W = (const float*)d_in[4];
  const float* gat_a = (const float*)d_in[5];
  const float* cg_W0 = (const float*)d_in[6];
  const float* cg_a0 = (const float*)d_in[7];
  const float* cg_W1 = (const float*)d_in[8];
  const float* cg_a1 = (const float*)d_in[9];
  const float* aw1 = (const float*)d_in[10]; const float* ab1 = (const float*)d_in[11];
  const float* aw2 = (const float*)d_in[12]; const float* ab2 = (const float*)d_in[13];
  const float* aw3 = (const float*)d_in[14]; const float* ab3 = (const float*)d_in[15];
  const float* crw1 = (const float*)d_in[16]; const float* crb1 = (const float*)d_in[17];
  const float* crw2 = (const float*)d_in[18]; const float* crb2 = (const float*)d_in[19];
  const float* crw3 = (const float*)d_in[20]; const float* crb3 = (const float*)d_in[21];
  const float* cew1 = (const float*)d_in[22]; const float* ceb1 = (const float*)d_in[23];
  const float* cew2 = (const float*)d_in[24]; const float* ceb2 = (const float*)d_in[25];
  const float* cew3 = (const float*)d_in[26]; const float* ceb3 = (const float*)d_in[27];
  const float* scm_causal = (const float*)d_in[28];
  const float* mw1 = (const float*)d_in[29]; const float* mb1 = (const float*)d_in[30];
  const float* mw2 = (const float*)d_in[31]; const float* mb2 = (const float*)d_in[32];
  const float* mw3 = (const float*)d_in[33]; const float* mb3 = (const float*)d_in[34];
  const float* nw1 = (const float*)d_in[35]; const float* nb1 = (const float*)d_in[36];
  const float* nw2 = (const float*)d_in[37]; const float* nb2 = (const float*)d_in[38];

  // workspace layout (floats); total 65,515,520 floats = 249.9 MiB
  float* ws = (float*)d_ws;
  float* Ssm  = ws;               // 16384
  float* cwsm = ws + 16384;       // 4096
  float* comm = ws + 20480;       // 4,194,304  (B,N,64)
  float* AI   = ws + 4214784;     // 12,582,912 (B,N,192): ai -> combined -> ce
  float* H1   = ws + 16797696;    // 16,777,216 (B,N,256)
  float* HCG  = ws + 33574912;    // 16,777,216 (B,N,256)
  unsigned short* wbf = (unsigned short*)(ws + 50352128);  // bf16 weights
  unsigned short* SsmT  = wbf;             // 16384
  unsigned short* wcT   = wbf + 16384;     // 65536 (reused per GAT layer)
  unsigned short* aw1T  = wbf + 81920;     // 3,145,728
  unsigned short* aw2T  = wbf + 3227648;   // 4,194,304
  unsigned short* aw3T  = wbf + 7421952;   // 262,144
  unsigned short* crw1T = wbf + 7684096;   // 3,145,728
  unsigned short* crw2T = wbf + 10829824;  // 4,194,304
  unsigned short* crw3T = wbf + 15024128;  // 16,384
  unsigned short* cew1T = wbf + 15040512;  // 2,359,296
  unsigned short* cew2T = wbf + 17399808;  // 65,536
  unsigned short* cew3T = wbf + 17465344;  // 16,384
  unsigned short* mw1T  = wbf + 17481728;  // 2,359,296
  unsigned short* mw2T  = wbf + 19841024;  // 4,194,304
  unsigned short* mw3T  = wbf + 24035328;  // 2,097,152
  unsigned short* nw1T  = wbf + 26132480;  // 2,097,152
  unsigned short* nw2T  = wbf + 28229632;  // 2,097,152

  float* out_actor = (float*)d_out;
  float* out_critic = out_actor + 1048576;
  float* out_cent = out_critic + 65536;
  float* out_scm = out_cent + 65536;

  auto GEMM64 = [&](const float* A, const unsigned short* BT, const float* bias, float* C,
                    int M, int N, int K, long long lda, long long ldc,
                    long long aBS, long long btBS, long long biasBS, long long cBS,
                    int act, int gz, int kPerSplit) {
    dim3 grid(M / 64, (N + 63) / 64, gz);
    hipLaunchKernelGGL(gemm_mfma_k, grid, dim3(256), 0, stream, A, BT, bias, C, M, N, K,
                       lda, ldc, aBS, btBS, biasBS, cBS, act, kPerSplit);
  };
  auto GEMM128 = [&](const float* A, const unsigned short* BT, const float* bias, float* C,
                     int M, int N, int K, long long lda, long long ldc,
                     long long aBS, long long btBS, long long biasBS, long long cBS,
                     int act, int gz, int kPerSplit) {
    dim3 grid(M / 128, (N + 127) / 128, gz);
    hipLaunchKernelGGL(gemm_mfma128_k, grid, dim3(256), 0, stream, A, BT, bias, C, M, N, K,
                       lda, ldc, aBS, btBS, biasBS, cBS, act, kPerSplit);
  };
  auto TRN = [&](const float* in, unsigned short* out, int Z, int K, int N) {
    dim3 grid((K + 31) / 32, (N + 31) / 32, Z);
    hipLaunchKernelGGL(transpose_cvt_k, grid, dim3(32, 8), 0, stream, in, out, K, N);
  };

  // 0) small softmaxes + weight conversions (one-time per launch)
  hipLaunchKernelGGL(softmax_rows_k, dim3(128), dim3(64), 0, stream, causal, Ssm, 128);
  hipLaunchKernelGGL(softmax_rows_k, dim3(64), dim3(64), 0, stream, scm_causal, cwsm, 64);
  TRN(Ssm, SsmT, 1, 128, 128);
  TRN(aw1, aw1T, 64, 192, 256);  TRN(aw2, aw2T, 64, 256, 256);  TRN(aw3, aw3T, 64, 256, 16);
  TRN(crw1, crw1T, 64, 192, 256); TRN(crw2, crw2T, 64, 256, 256); TRN(crw3, crw3T, 64, 256, 1);
  TRN(cew1, cew1T, 1, 9216, 256); TRN(cew2, cew2T, 1, 256, 256);  TRN(cew3, cew3T, 1, 256, 64);
  TRN(mw1, mw1T, 64, 144, 256);  TRN(mw2, mw2T, 64, 256, 256);  TRN(mw3, mw3T, 64, 256, 128);
  TRN(nw1, nw1T, 64, 128, 256);  TRN(nw2, nw2T, 64, 256, 128);

  // 1) plain GAT -> comm (init)
  hipLaunchKernelGGL(repack_wT_k, dim3((NH * 128 * 64 + 255) / 256), dim3(256), 0, stream, gat_W, wcT, 128);
  GEMM128(obs, wcT, nullptr, H1, 65536, 256, 128, 128, 256, 0, 0, 0, 0, 0, 1, 0);     // xt1
  hipLaunchKernelGGL(gat_attn4_k, dim3(1024), dim3(256), 0, stream, H1, gat_a, adj, comm, 0);

  // 2) causal GAT
  GEMM128(obs, SsmT, nullptr, HCG, 65536, 128, 128, 128, 128, 0, 0, 0, 0, 0, 1, 0);   // xm
  hipLaunchKernelGGL(repack_wT_k, dim3((NH * 128 * 64 + 255) / 256), dim3(256), 0, stream, cg_W0, wcT, 128);
  GEMM128(HCG, wcT, nullptr, H1, 65536, 256, 128, 128, 256, 0, 0, 0, 0, 0, 1, 0);     // xt_cg0
  hipLaunchKernelGGL(gat_attn4_k, dim3(1024), dim3(256), 0, stream, H1, cg_a0, adj, HCG, 2); // hcg (ELU)
  hipLaunchKernelGGL(repack_wT_k, dim3((NH * 256 * 64 + 255) / 256), dim3(256), 0, stream, cg_W1, wcT, 256);
  GEMM128(HCG, wcT, nullptr, H1, 65536, 256, 256, 256, 256, 0, 0, 0, 0, 0, 1, 0);     // xt_cg1
  hipLaunchKernelGGL(gat_attn4_k, dim3(1024), dim3(256), 0, stream, H1, cg_a1, adj, comm, 1);

  // 3) ai = [obs, comm]
  hipLaunchKernelGGL(build_ai_k, dim3((12582912 + 255) / 256), dim3(256), 0, stream, obs, comm, AI);

  // 4) actor MLP (per-agent)
  GEMM128(AI, aw1T, ab1, H1, 1024, 256, 192, 12288, 16384, 192, 49152, 256, 256, 1, 64, 0);
  GEMM128(H1, aw2T, ab2, HCG, 1024, 256, 256, 16384, 16384, 256, 65536, 256, 256, 1, 64, 0);
  GEMM64(HCG, aw3T, ab3, out_actor, 1024, 16, 256, 16384, 1024, 256, 4096, 16, 16, 0, 64, 0);

  // 5) critic MLP (per-agent)
  GEMM128(AI, crw1T, crb1, H1, 1024, 256, 192, 12288, 16384, 192, 49152, 256, 256, 1, 64, 0);
  GEMM128(H1, crw2T, crb2, HCG, 1024, 256, 256, 16384, 16384, 256, 65536, 256, 256, 1, 64, 0);
  GEMM64(HCG, crw3T, crb3, out_critic, 1024, 1, 256, 16384, 64, 256, 256, 1, 1, 0, 64, 0);

  // 6) centralized critic (combined -> AI)
  hipLaunchKernelGGL(build_combined_k, dim3((9437184 + 255) / 256), dim3(256), 0, stream, obs, acts, AI);
  GEMM128(AI, cew1T, nullptr, H1, 1024, 256, 9216, 9216, 256, 0, 0, 0, 262144, 0, 16, 576);
  hipLaunchKernelGGL(reduce_bias_relu_k, dim3(1024), dim3(256), 0, stream, H1, ceb1, HCG);
  GEMM64(HCG, cew2T, ceb2, H1, 1024, 256, 256, 256, 256, 0, 0, 0, 0, 1, 1, 0);
  GEMM64(H1, cew3T, ceb3, out_cent, 1024, 64, 256, 256, 64, 0, 0, 0, 0, 0, 1, 0);

  // 7) SCM mechanisms (input = combined in AI)
  GEMM128(AI, mw1T, mb1, H1, 1024, 256, 144, 9216, 16384, 144, 36864, 256, 256, 1, 64, 0);
  GEMM128(H1, mw2T, mb2, HCG, 1024, 256, 256, 16384, 16384, 256, 65536, 256, 256, 1, 64, 0);
  GEMM128(HCG, mw3T, mb3, AI, 1024, 128, 256, 16384, 8192, 256, 32768, 128, 128, 0, 64, 0); // ce -> AI

  // 8) noise model (input = obs)
  GEMM128(obs, nw1T, nb1, H1, 1024, 256, 128, 8192, 16384, 128, 32768, 256, 256, 1, 64, 0);
  GEMM128(H1, nw2T, nb2, HCG, 1024, 128, 256, 16384, 8192, 256, 32768, 128, 128, 0, 64, 0); // noise -> HCG

  // 9) scm_pred = softmax(scm_causal) @ ce + noise
  hipLaunchKernelGGL(se_noise_k, dim3(1024), dim3(256), 0, stream, cwsm, AI, HCG, out_scm);
}

// Round 3
// 1006.787 us; speedup vs baseline: 1.1778x; 1.0202x over previous
//
#include <hip/hip_runtime.h>
#include <hip/hip_bf16.h>
#include <math.h>

// Problem constants
#define NB 1024    // batch
#define NAG 64     // agents
#define OBS 128
#define ACTD 16
#define HID 256
#define GD 64
#define NH 4       // heads

typedef short bhalf8 __attribute__((ext_vector_type(8)));
typedef float f32x4 __attribute__((ext_vector_type(4)));

__device__ inline unsigned short f2bf_u(float f) {
  __hip_bfloat16 h = __float2bfloat16(f);
  return *(unsigned short*)&h;
}
__device__ inline float bfu2f(unsigned short u) {
  unsigned v = ((unsigned)u) << 16;
  return *(float*)&v;
}
__device__ inline unsigned pk2(float x, float y) {
  float2 f2; f2.x = x; f2.y = y;
  __hip_bfloat162 h = __float22bfloat162_rn(f2);
  return *(unsigned*)&h;
}

// ---------------- row softmax ----------------
__global__ __launch_bounds__(64) void softmax_rows_k(const float* __restrict__ in,
                                                     float* __restrict__ out, int n) {
  int row = blockIdx.x;
  int lane = threadIdx.x;
  const float* r = in + (size_t)row * n;
  float m = -INFINITY;
  for (int j = lane; j < n; j += 64) m = fmaxf(m, r[j]);
#pragma unroll
  for (int off = 32; off; off >>= 1) m = fmaxf(m, __shfl_xor(m, off));
  float s = 0.f;
  for (int j = lane; j < n; j += 64) s += expf(r[j] - m);
#pragma unroll
  for (int off = 32; off; off >>= 1) s += __shfl_xor(s, off);
  float inv = 1.f / s;
  for (int j = lane; j < n; j += 64) out[(size_t)row * n + j] = expf(r[j] - m) * inv;
}

// ---------------- cw softmax -> bf16 hi/lo global ----------------
__global__ void cwbf_k(const float* __restrict__ cwsm, unsigned short* __restrict__ cw1,
                       unsigned short* __restrict__ cw2) {
  int idx = blockIdx.x * 256 + threadIdx.x;
  if (idx >= 4096) return;
  float v = cwsm[idx];
  unsigned short hi = f2bf_u(v);
  cw1[idx] = hi;
  cw2[idx] = f2bf_u(v - bfu2f(hi));
}

// ---------------- batched transpose+cvt: in (Z,K,N) f32 -> out (Z,N,K) bf16 ----------------
__global__ __launch_bounds__(256) void transpose_cvt_k(const float* __restrict__ in,
                                                       unsigned short* __restrict__ out,
                                                       int K, int N) {
  __shared__ float t[32][33];
  int k0 = blockIdx.x * 32, n0 = blockIdx.y * 32, z = blockIdx.z;
  int tx = threadIdx.x, ty = threadIdx.y;  // 32 x 8
  const float* ib = in + (size_t)z * K * N;
  unsigned short* ob = out + (size_t)z * N * K;
#pragma unroll
  for (int i = 0; i < 4; ++i) {
    int k = k0 + ty + 8 * i, n = n0 + tx;
    if (k < K && n < N) t[ty + 8 * i][tx] = ib[(size_t)k * N + n];
  }
  __syncthreads();
#pragma unroll
  for (int i = 0; i < 4; ++i) {
    int n = n0 + ty + 8 * i, k = k0 + tx;
    if (n < N && k < K) ob[(size_t)n * K + k] = f2bf_u(t[tx][ty + 8 * i]);
  }
}

// ---------------- GAT weight repack: W (H,F,D) -> WcT bf16 (H*D, F) ----------------
__global__ void repack_wT_k(const float* __restrict__ W, unsigned short* __restrict__ WcT, int F) {
  int idx = blockIdx.x * 256 + threadIdx.x;
  if (idx >= NH * F * 64) return;
  int d = idx & 63;
  int f = (idx >> 6) % F;
  int h = idx / (F * 64);
  WcT[((size_t)(h * 64 + d)) * F + f] = f2bf_u(W[idx]);
}

// ---------------- bf16 MFMA GEMM, 64x64 tile (small-N cases) ----------------
__global__ __launch_bounds__(256) void gemm_mfma_k(
    const float* __restrict__ A, const unsigned short* __restrict__ BT,
    const float* __restrict__ bias, float* __restrict__ C,
    int M, int N, int K,
    long long lda, long long ldc,
    long long aBS, long long btBS, long long biasBS, long long cBS,
    int act, int kPerSplit) {
  __shared__ unsigned short As[64 * 40];
  __shared__ unsigned short Bs[64 * 40];
  int tid = threadIdx.x;
  int wave = tid >> 6, lane = tid & 63;
  int m0 = blockIdx.x * 64, n0 = blockIdx.y * 64;
  int z = blockIdx.z;
  const float* Ab;
  const unsigned short* Bb;
  const float* biasb = nullptr;
  float* Cb;
  int k_begin, k_end;
  if (kPerSplit > 0) {
    Ab = A; Bb = BT; Cb = C + (long long)z * cBS;
    k_begin = z * kPerSplit;
    k_end = k_begin + kPerSplit;
    if (k_end > K) k_end = K;
  } else {
    Ab = A + (long long)z * aBS;
    Bb = BT + (long long)z * btBS;
    if (bias) biasb = bias + (long long)z * biasBS;
    Cb = C + (long long)z * cBS;
    k_begin = 0; k_end = K;
  }
  int sr = tid >> 2;
  int sk = (tid & 3) * 8;
  int fr = lane & 15;
  int kq = (lane >> 4) * 8;

  f32x4 zf = {0.f, 0.f, 0.f, 0.f};
  f32x4 acc[4] = {zf, zf, zf, zf};

  const unsigned short* bRow = Bb + (long long)(n0 + sr) * K;
  bool bValid = (n0 + sr) < N;
  const float* aRow = Ab + (long long)(m0 + sr) * lda;

  for (int k0 = k_begin; k0 < k_end; k0 += 32) {
    int kk = k0 + sk;
    uint4 aw;
    if (kk + 7 < k_end) {
      const float* ap = aRow + kk;
      float4 v0 = *(const float4*)ap;
      float4 v1 = *(const float4*)(ap + 4);
      aw.x = pk2(v0.x, v0.y); aw.y = pk2(v0.z, v0.w);
      aw.z = pk2(v1.x, v1.y); aw.w = pk2(v1.z, v1.w);
    } else {
      float t[8];
#pragma unroll
      for (int j = 0; j < 8; ++j) t[j] = (kk + j < k_end) ? aRow[kk + j] : 0.f;
      aw.x = pk2(t[0], t[1]); aw.y = pk2(t[2], t[3]);
      aw.z = pk2(t[4], t[5]); aw.w = pk2(t[6], t[7]);
    }
    *(uint4*)&As[sr * 40 + sk] = aw;
    uint4 bw = {0u, 0u, 0u, 0u};
    if (bValid) {
      if (kk + 7 < k_end) {
        bw = *(const uint4*)(bRow + kk);
      } else {
        unsigned short tb[8];
#pragma unroll
        for (int j = 0; j < 8; ++j) tb[j] = (kk + j < k_end) ? bRow[kk + j] : (unsigned short)0;
        bw.x = (unsigned)tb[0] | ((unsigned)tb[1] << 16);
        bw.y = (unsigned)tb[2] | ((unsigned)tb[3] << 16);
        bw.z = (unsigned)tb[4] | ((unsigned)tb[5] << 16);
        bw.w = (unsigned)tb[6] | ((unsigned)tb[7] << 16);
      }
    }
    *(uint4*)&Bs[sr * 40 + sk] = bw;
    __syncthreads();
    bhalf8 af = *(bhalf8*)&As[(16 * wave + fr) * 40 + kq];
#pragma unroll
    for (int t = 0; t < 4; ++t) {
      bhalf8 bf = *(bhalf8*)&Bs[(16 * t + fr) * 40 + kq];
      acc[t] = __builtin_amdgcn_mfma_f32_16x16x32_bf16(af, bf, acc[t], 0, 0, 0);
    }
    __syncthreads();
  }
  int rb = (lane >> 4) * 4;
#pragma unroll
  for (int t = 0; t < 4; ++t) {
    int col = n0 + 16 * t + fr;
    if (col < N) {
      float bv = biasb ? biasb[col] : 0.f;
#pragma unroll
      for (int r = 0; r < 4; ++r) {
        long long row = m0 + 16 * wave + rb + r;
        float v = acc[t][r] + bv;
        if (act == 1) v = fmaxf(v, 0.f);
        Cb[row * ldc + col] = v;
      }
    }
  }
}

// ---------------- bf16 MFMA GEMM, 128x128 tile, 4x4 16x16 tiles per wave ----------------
// Requires M % 128 == 0. N guarded. A (M,K) f32; BT (N,K) bf16.
__global__ __launch_bounds__(256) void gemm_mfma128_k(
    const float* __restrict__ A, const unsigned short* __restrict__ BT,
    const float* __restrict__ bias, float* __restrict__ C,
    int M, int N, int K,
    long long lda, long long ldc,
    long long aBS, long long btBS, long long biasBS, long long cBS,
    int act, int kPerSplit) {
  __shared__ unsigned short As[128 * 40];
  __shared__ unsigned short Bs[128 * 40];
  int tid = threadIdx.x;
  int wave = tid >> 6, lane = tid & 63;
  int m0 = blockIdx.x * 128, n0 = blockIdx.y * 128;
  int z = blockIdx.z;
  const float* Ab;
  const unsigned short* Bb;
  const float* biasb = nullptr;
  float* Cb;
  int k_begin, k_end;
  if (kPerSplit > 0) {
    Ab = A; Bb = BT; Cb = C + (long long)z * cBS;
    k_begin = z * kPerSplit;
    k_end = k_begin + kPerSplit;
    if (k_end > K) k_end = K;
  } else {
    Ab = A + (long long)z * aBS;
    Bb = BT + (long long)z * btBS;
    if (bias) biasb = bias + (long long)z * biasBS;
    Cb = C + (long long)z * cBS;
    k_begin = 0; k_end = K;
  }
  int sr = tid >> 1;          // staging row 0..127
  int sk = (tid & 1) * 16;    // k-half
  int mq = (wave >> 1) * 64;  // wave quadrant
  int nq = (wave & 1) * 64;
  int fr = lane & 15;
  int kq = (lane >> 4) * 8;

  f32x4 zf = {0.f, 0.f, 0.f, 0.f};
  f32x4 acc[4][4];
#pragma unroll
  for (int i = 0; i < 4; ++i)
#pragma unroll
    for (int j = 0; j < 4; ++j) acc[i][j] = zf;

  const float* aRow = Ab + (long long)(m0 + sr) * lda;
  const unsigned short* bRow = Bb + (long long)(n0 + sr) * K;
  bool bValid = (n0 + sr) < N;

  for (int k0 = k_begin; k0 < k_end; k0 += 32) {
    int kk = k0 + sk;
    // ---- stage A: 16 floats -> bf16
    uint4 aw0, aw1;
    if (kk + 15 < k_end) {
      const float* ap = aRow + kk;
      float4 v0 = *(const float4*)ap;
      float4 v1 = *(const float4*)(ap + 4);
      float4 v2 = *(const float4*)(ap + 8);
      float4 v3 = *(const float4*)(ap + 12);
      aw0.x = pk2(v0.x, v0.y); aw0.y = pk2(v0.z, v0.w);
      aw0.z = pk2(v1.x, v1.y); aw0.w = pk2(v1.z, v1.w);
      aw1.x = pk2(v2.x, v2.y); aw1.y = pk2(v2.z, v2.w);
      aw1.z = pk2(v3.x, v3.y); aw1.w = pk2(v3.z, v3.w);
    } else {
      float t[16];
#pragma unroll
      for (int j = 0; j < 16; ++j) t[j] = (kk + j < k_end) ? aRow[kk + j] : 0.f;
      aw0.x = pk2(t[0], t[1]);   aw0.y = pk2(t[2], t[3]);
      aw0.z = pk2(t[4], t[5]);   aw0.w = pk2(t[6], t[7]);
      aw1.x = pk2(t[8], t[9]);   aw1.y = pk2(t[10], t[11]);
      aw1.z = pk2(t[12], t[13]); aw1.w = pk2(t[14], t[15]);
    }
    *(uint4*)&As[sr * 40 + sk] = aw0;
    *(uint4*)&As[sr * 40 + sk + 8] = aw1;
    // ---- stage B: 16 bf16 passthrough
    uint4 bw0 = {0u, 0u, 0u, 0u}, bw1 = {0u, 0u, 0u, 0u};
    if (bValid) {
      if (kk + 15 < k_end) {
        bw0 = *(const uint4*)(bRow + kk);
        bw1 = *(const uint4*)(bRow + kk + 8);
      } else {
        unsigned short tb[16];
#pragma unroll
        for (int j = 0; j < 16; ++j) tb[j] = (kk + j < k_end) ? bRow[kk + j] : (unsigned short)0;
        bw0.x = (unsigned)tb[0] | ((unsigned)tb[1] << 16);
        bw0.y = (unsigned)tb[2] | ((unsigned)tb[3] << 16);
        bw0.z = (unsigned)tb[4] | ((unsigned)tb[5] << 16);
        bw0.w = (unsigned)tb[6] | ((unsigned)tb[7] << 16);
        bw1.x = (unsigned)tb[8] | ((unsigned)tb[9] << 16);
        bw1.y = (unsigned)tb[10] | ((unsigned)tb[11] << 16);
        bw1.z = (unsigned)tb[12] | ((unsigned)tb[13] << 16);
        bw1.w = (unsigned)tb[14] | ((unsigned)tb[15] << 16);
      }
    }
    *(uint4*)&Bs[sr * 40 + sk] = bw0;
    *(uint4*)&Bs[sr * 40 + sk + 8] = bw1;
    __syncthreads();
    // ---- compute: 4x4 tiles, 16 MFMA per iter per wave
    bhalf8 af[4], bf[4];
#pragma unroll
    for (int i = 0; i < 4; ++i) af[i] = *(bhalf8*)&As[(mq + 16 * i + fr) * 40 + kq];
#pragma unroll
    for (int j = 0; j < 4; ++j) bf[j] = *(bhalf8*)&Bs[(nq + 16 * j + fr) * 40 + kq];
#pragma unroll
    for (int i = 0; i < 4; ++i)
#pragma unroll
      for (int j = 0; j < 4; ++j)
        acc[i][j] = __builtin_amdgcn_mfma_f32_16x16x32_bf16(af[i], bf[j], acc[i][j], 0, 0, 0);
    __syncthreads();
  }
  // ---- epilogue
  int rb = (lane >> 4) * 4;
#pragma unroll
  for (int j = 0; j < 4; ++j) {
    int col = n0 + nq + 16 * j + fr;
    if (col < N) {
      float bv = biasb ? biasb[col] : 0.f;
#pragma unroll
      for (int i = 0; i < 4; ++i) {
#pragma unroll
        for (int r = 0; r < 4; ++r) {
          long long row = m0 + mq + 16 * i + rb + r;
          float v = acc[i][j][r] + bv;
          if (act == 1) v = fmaxf(v, 0.f);
          Cb[row * ldc + col] = v;
        }
      }
    }
  }
}

// ---------------- GAT attention, 4 waves per graph, head loop inside ----------------
// xt layout: (B*N, NH*GD). mode: 0 = comm = 0.25*sum_h att ; 1 = comm += ; 2 = concat+ELU
__global__ __launch_bounds__(256, 4) void gat_attn4_k(
    const float* __restrict__ xt, const float* __restrict__ a,
    const float* __restrict__ adj, float* __restrict__ out, int mode) {
  int b = blockIdx.x;
  int tid = threadIdx.x;
  int wave = tid >> 6, lane = tid & 63;
  __shared__ unsigned short xT1[64 * 72];  // X^T hi  [d][j]
  __shared__ unsigned short xT2[64 * 72];  // X^T lo
  __shared__ unsigned short P1[64 * 72];   // exp weights hi [i][j]
  __shared__ unsigned short P2[64 * 72];   // exp weights lo
  __shared__ float si_s[64], sj_s[64];

  const float* adjb = adj + (size_t)b * 4096;
  float adjv[16];
#pragma unroll
  for (int r = 0; r < 16; ++r) adjv[r] = adjb[(size_t)(wave * 16 + r) * 64 + lane];

  int lrow = tid >> 2;   // j (agent) this thread projects (phase A1)
  int cg = tid & 3;      // 16-wide column group
  int fr = lane & 15;
  int kq = (lane >> 4) * 8;
  int ibase = wave * 16;

  bhalf8 ones;
#pragma unroll
  for (int u = 0; u < 8; ++u) ones[u] = (short)0x3F80;  // 1.0 bf16

  f32x4 zf = {0.f, 0.f, 0.f, 0.f};
  f32x4 accm[4] = {zf, zf, zf, zf};  // head-mean accum (mode 0/1)

  for (int h = 0; h < 4; ++h) {
    // ---- A2 loads: column gather for X^T (coalesced across lanes; L2-hot)
    const float* xcol = xt + ((size_t)(b * 64 + 16 * wave)) * 256 + h * 64 + lane;
    float v[16];
#pragma unroll
    for (int u = 0; u < 16; ++u) v[u] = xcol[(size_t)u * 256];

    // ---- A1: si/sj projections (row loads)
    const float* xrow = xt + ((size_t)(b * 64 + lrow)) * 256 + h * 64 + cg * 16;
    const float* ah = a + h * 128;
    float p1 = 0.f, p2 = 0.f;
#pragma unroll
    for (int q = 0; q < 4; ++q) {
      float4 rv = *(const float4*)(xrow + 4 * q);
      int c = cg * 16 + 4 * q;
      p1 += rv.x * ah[c] + rv.y * ah[c + 1] + rv.z * ah[c + 2] + rv.w * ah[c + 3];
      p2 += rv.x * ah[64 + c] + rv.y * ah[64 + c + 1] + rv.z * ah[64 + c + 2] + rv.w * ah[64 + c + 3];
    }
    p1 += __shfl_xor(p1, 1); p1 += __shfl_xor(p1, 2);
    p2 += __shfl_xor(p2, 1); p2 += __shfl_xor(p2, 2);
    if (cg == 0) { si_s[lrow] = p1; sj_s[lrow] = p2; }

    // ---- A2 stores: cvt hi/lo, pack, b128 writes (row d=lane, j block 16*wave)
    {
      float hf[16];
      uint4 h0, h1, l0, l1;
#pragma unroll
      for (int u = 0; u < 16; ++u) hf[u] = bfu2f(f2bf_u(v[u]));
      h0.x = pk2(hf[0], hf[1]);   h0.y = pk2(hf[2], hf[3]);
      h0.z = pk2(hf[4], hf[5]);   h0.w = pk2(hf[6], hf[7]);
      h1.x = pk2(hf[8], hf[9]);   h1.y = pk2(hf[10], hf[11]);
      h1.z = pk2(hf[12], hf[13]); h1.w = pk2(hf[14], hf[15]);
      l0.x = pk2(v[0] - hf[0], v[1] - hf[1]);     l0.y = pk2(v[2] - hf[2], v[3] - hf[3]);
      l0.z = pk2(v[4] - hf[4], v[5] - hf[5]);     l0.w = pk2(v[6] - hf[6], v[7] - hf[7]);
      l1.x = pk2(v[8] - hf[8], v[9] - hf[9]);     l1.y = pk2(v[10] - hf[10], v[11] - hf[11]);
      l1.z = pk2(v[12] - hf[12], v[13] - hf[13]); l1.w = pk2(v[14] - hf[14], v[15] - hf[15]);
      int base = lane * 72 + 16 * wave;
      *(uint4*)&xT1[base] = h0;
      *(uint4*)&xT1[base + 8] = h1;
      *(uint4*)&xT2[base] = l0;
      *(uint4*)&xT2[base + 8] = l1;
    }
    __syncthreads();

    // ---- B: per-row exp weights, no reductions
    float sjv = sj_s[lane];
    float maxsj = sjv;
#pragma unroll
    for (int off = 32; off; off >>= 1) maxsj = fmaxf(maxsj, __shfl_xor(maxsj, off));
#pragma unroll
    for (int r = 0; r < 16; ++r) {
      int i = ibase + r;
      float siv = si_s[i];
      float tM = siv + maxsj;
      float Mi = tM > 0.f ? tM : 0.2f * tM;   // >= max_j e (leaky monotone)
      float e = siv + sjv;
      e = e > 0.f ? e : 0.2f * e;
      float p = (adjv[r] == 0.f) ? 0.f : expf(e - Mi);
      unsigned short phi = f2bf_u(p);
      P1[i * 72 + lane] = phi;
      P2[i * 72 + lane] = f2bf_u(p - bfu2f(phi));
    }
    // P rows are wave-local (written and read by the same wave) -> no barrier.

    // ---- C: MFMA aggregation + row sums
    bhalf8 a1[2], a2[2];
#pragma unroll
    for (int ks = 0; ks < 2; ++ks) {
      a1[ks] = *(bhalf8*)&P1[(ibase + fr) * 72 + ks * 32 + kq];
      a2[ks] = *(bhalf8*)&P2[(ibase + fr) * 72 + ks * 32 + kq];
    }
    f32x4 accS = zf;
#pragma unroll
    for (int ks = 0; ks < 2; ++ks) {
      accS = __builtin_amdgcn_mfma_f32_16x16x32_bf16(a1[ks], ones, accS, 0, 0, 0);
      accS = __builtin_amdgcn_mfma_f32_16x16x32_bf16(a2[ks], ones, accS, 0, 0, 0);
    }
    f32x4 acc[4] = {zf, zf, zf, zf};
#pragma unroll
    for (int ks = 0; ks < 2; ++ks) {
#pragma unroll
      for (int t = 0; t < 4; ++t) {
        bhalf8 b1 = *(bhalf8*)&xT1[(16 * t + fr) * 72 + ks * 32 + kq];
        bhalf8 b2 = *(bhalf8*)&xT2[(16 * t + fr) * 72 + ks * 32 + kq];
        acc[t] = __builtin_amdgcn_mfma_f32_16x16x32_bf16(a1[ks], b1, acc[t], 0, 0, 0);
        acc[t] = __builtin_amdgcn_mfma_f32_16x16x32_bf16(a1[ks], b2, acc[t], 0, 0, 0);
        acc[t] = __builtin_amdgcn_mfma_f32_16x16x32_bf16(a2[ks], b1, acc[t], 0, 0, 0);
      }
    }
    f32x4 inv;
#pragma unroll
    for (int r = 0; r < 4; ++r) inv[r] = (accS[r] > 0.f) ? 1.f / accS[r] : 0.f;

    int rb = (lane >> 4) * 4;
    if (mode == 2) {
#pragma unroll
      for (int t = 0; t < 4; ++t) {
#pragma unroll
        for (int r = 0; r < 4; ++r) {
          int i = ibase + rb + r;
          float vv = acc[t][r] * inv[r];
          vv = vv > 0.f ? vv : expf(vv) - 1.f;
          out[((size_t)(b * 64 + i)) * 256 + h * 64 + 16 * t + fr] = vv;
        }
      }
    } else {
#pragma unroll
      for (int t = 0; t < 4; ++t)
#pragma unroll
        for (int r = 0; r < 4; ++r) accm[t][r] += 0.25f * acc[t][r] * inv[r];
    }
    __syncthreads();  // xT/si/sj reuse for next head
  }

  if (mode != 2) {
    int rb = (lane >> 4) * 4;
    float* cb = out + (size_t)b * 4096;
#pragma unroll
    for (int t = 0; t < 4; ++t) {
#pragma unroll
      for (int r = 0; r < 4; ++r) {
        int i = ibase + rb + r;
        int col = 16 * t + fr;
        if (mode == 1) cb[i * 64 + col] += accm[t][r];
        else cb[i * 64 + col] = accm[t][r];
      }
    }
  }
}

// ---------------- ai = [obs, comm] (B,N,192) ----------------
__global__ void build_ai_k(const float* __restrict__ obs, const float* __restrict__ comm,
                           float* __restrict__ ai) {
  size_t idx = (size_t)blockIdx.x * 256 + threadIdx.x;
  if (idx >= (size_t)NB * NAG * 192) return;
  int c = (int)(idx % 192);
  size_t bn = idx / 192;
  ai[idx] = (c < 128) ? obs[bn * 128 + c] : comm[bn * 64 + (c - 128)];
}

// ---------------- combined = [obs, actions] (B,N,144) ----------------
__global__ void build_combined_k(const float* __restrict__ obs, const float* __restrict__ act,
                                 float* __restrict__ cmb) {
  size_t idx = (size_t)blockIdx.x * 256 + threadIdx.x;
  if (idx >= (size_t)NB * NAG * 144) return;
  int c = (int)(idx % 144);
  size_t bn = idx / 144;
  cmb[idx] = (c < 128) ? obs[bn * 128 + c] : act[bn * 16 + (c - 128)];
}

// ---------------- split-K reduce + bias + relu for cent l1 ----------------
__global__ void reduce_bias_relu_k(const float* __restrict__ part, const float* __restrict__ bias,
                                   float* __restrict__ out) {
  int idx = blockIdx.x * 256 + threadIdx.x;
  float s = 0.f;
#pragma unroll
  for (int zz = 0; zz < 16; ++zz) s += part[(size_t)zz * 262144 + idx];
  s += bias[idx & 255];
  out[idx] = fmaxf(s, 0.f);
}

// ---------------- scm_pred = cw @ ce + noise (MFMA, hi/lo split) ----------------
// cw1/cw2: bf16 hi/lo of softmax(scm_causal) (64x64, row-major, global/L2).
// ce (B,64,128) f32; per block: stage ce^T hi/lo in LDS, 48 MFMA/wave, fuse +noise.
__global__ __launch_bounds__(256, 4) void se_noise_mfma_k(
    const unsigned short* __restrict__ cw1, const unsigned short* __restrict__ cw2,
    const float* __restrict__ ce, const float* __restrict__ nz,
    float* __restrict__ out) {
  int b = blockIdx.x;
  int tid = threadIdx.x;
  int wave = tid >> 6, lane = tid & 63;
  __shared__ unsigned short xT1[128 * 72];  // ce^T hi [d][j]
  __shared__ unsigned short xT2[128 * 72];  // ce^T lo

  // ---- stage: column gather (lane-consecutive d -> coalesced), hi/lo split
  int dd = tid & 127;
  int jh = tid >> 7;  // 0 or 1 -> j block of 32
  const float* cecol = ce + (size_t)b * 8192 + dd;
#pragma unroll
  for (int c = 0; c < 2; ++c) {
    int j0 = jh * 32 + c * 16;
    float v[16];
#pragma unroll
    for (int u = 0; u < 16; ++u) v[u] = cecol[(size_t)(j0 + u) * 128];
    float hf[16];
#pragma unroll
    for (int u = 0; u < 16; ++u) hf[u] = bfu2f(f2bf_u(v[u]));
    uint4 h0, h1, l0, l1;
    h0.x = pk2(hf[0], hf[1]);   h0.y = pk2(hf[2], hf[3]);
    h0.z = pk2(hf[4], hf[5]);   h0.w = pk2(hf[6], hf[7]);
    h1.x = pk2(hf[8], hf[9]);   h1.y = pk2(hf[10], hf[11]);
    h1.z = pk2(hf[12], hf[13]); h1.w = pk2(hf[14], hf[15]);
    l0.x = pk2(v[0] - hf[0], v[1] - hf[1]);     l0.y = pk2(v[2] - hf[2], v[3] - hf[3]);
    l0.z = pk2(v[4] - hf[4], v[5] - hf[5]);     l0.w = pk2(v[6] - hf[6], v[7] - hf[7]);
    l1.x = pk2(v[8] - hf[8], v[9] - hf[9]);     l1.y = pk2(v[10] - hf[10], v[11] - hf[11]);
    l1.z = pk2(v[12] - hf[12], v[13] - hf[13]); l1.w = pk2(v[14] - hf[14], v[15] - hf[15]);
    int base = dd * 72 + j0;
    *(uint4*)&xT1[base] = h0;
    *(uint4*)&xT1[base + 8] = h1;
    *(uint4*)&xT2[base] = l0;
    *(uint4*)&xT2[base + 8] = l1;
  }
  __syncthreads();

  // ---- compute: wave owns d quadrant [wave*32, wave*32+32)
  int fr = lane & 15;
  int kq = (lane >> 4) * 8;
  int dq = wave * 32;

  bhalf8 bb1[2][2], bb2[2][2];
#pragma unroll
  for (int dt = 0; dt < 2; ++dt)
#pragma unroll
    for (int ks = 0; ks < 2; ++ks) {
      bb1[dt][ks] = *(bhalf8*)&xT1[(dq + dt * 16 + fr) * 72 + ks * 32 + kq];
      bb2[dt][ks] = *(bhalf8*)&xT2[(dq + dt * 16 + fr) * 72 + ks * 32 + kq];
    }

  f32x4 zf = {0.f, 0.f, 0.f, 0.f};
  f32x4 acc[4][2];
#pragma unroll
  for (int it = 0; it < 4; ++it)
#pragma unroll
    for (int dt = 0; dt < 2; ++dt) acc[it][dt] = zf;

#pragma unroll
  for (int it = 0; it < 4; ++it) {
    bhalf8 a1[2], a2[2];
#pragma unroll
    for (int ks = 0; ks < 2; ++ks) {
      a1[ks] = *(const bhalf8*)(cw1 + (it * 16 + fr) * 64 + ks * 32 + kq);
      a2[ks] = *(const bhalf8*)(cw2 + (it * 16 + fr) * 64 + ks * 32 + kq);
    }
#pragma unroll
    for (int dt = 0; dt < 2; ++dt)
#pragma unroll
      for (int ks = 0; ks < 2; ++ks) {
        acc[it][dt] = __builtin_amdgcn_mfma_f32_16x16x32_bf16(a1[ks], bb1[dt][ks], acc[it][dt], 0, 0, 0);
        acc[it][dt] = __builtin_amdgcn_mfma_f32_16x16x32_bf16(a1[ks], bb2[dt][ks], acc[it][dt], 0, 0, 0);
        acc[it][dt] = __builtin_amdgcn_mfma_f32_16x16x32_bf16(a2[ks], bb1[dt][ks], acc[it][dt], 0, 0, 0);
      }
  }

  // ---- epilogue: + noise, f32 store
  int rb = (lane >> 4) * 4;
#pragma unroll
  for (int it = 0; it < 4; ++it)
#pragma unroll
    for (int dt = 0; dt < 2; ++dt) {
      int dcol = dq + dt * 16 + fr;
#pragma unroll
      for (int r = 0; r < 4; ++r) {
        int i = it * 16 + rb + r;
        size_t off = (size_t)b * 8192 + (size_t)i * 128 + dcol;
        out[off] = acc[it][dt][r] + nz[off];
      }
    }
}

extern "C" void kernel_launch(void* const* d_in, const int* in_sizes, int n_in,
                              void* d_out, int out_size, void* d_ws, size_t ws_size,
                              hipStream_t stream) {
  (void)in_sizes; (void)n_in; (void)out_size; (void)ws_size;
  const float* obs = (const float*)d_in[0];
  const float* acts = (const float*)d_in[1];
  const float* adj = (const float*)d_in[2];
  const float* causal = (const float*)d_in[3];
  const float* gat_W = (const float*)d_in[4];
  const float* gat_a = (const float*)d_in[5];
  const float* cg_W0 = (const float*)d_in[6];
  const float* cg_a0 = (const float*)d_in[7];
  const float* cg_W1 = (const float*)d_in[8];
  const float* cg_a1 = (const float*)d_in[9];
  const float* aw1 = (const float*)d_in[10]; const float* ab1 = (const float*)d_in[11];
  const float* aw2 = (const float*)d_in[12]; const float* ab2 = (const float*)d_in[13];
  const float* aw3 = (const float*)d_in[14]; const float* ab3 = (const float*)d_in[15];
  const float* crw1 = (const float*)d_in[16]; const float* crb1 = (const float*)d_in[17];
  const float* crw2 = (const float*)d_in[18]; const float* crb2 = (const float*)d_in[19];
  const float* crw3 = (const float*)d_in[20]; const float* crb3 = (const float*)d_in[21];
  const float* cew1 = (const float*)d_in[22]; const float* ceb1 = (const float*)d_in[23];
  const float* cew2 = (const float*)d_in[24]; const float* ceb2 = (const float*)d_in[25];
  const float* cew3 = (const float*)d_in[26]; const float* ceb3 = (const float*)d_in[27];
  const float* scm_causal = (const float*)d_in[28];
  const float* mw1 = (const float*)d_in[29]; const float* mb1 = (const float*)d_in[30];
  const float* mw2 = (const float*)d_in[31]; const float* mb2 = (const float*)d_in[32];
  const float* mw3 = (const float*)d_in[33]; const float* mb3 = (const float*)d_in[34];
  const float* nw1 = (const float*)d_in[35]; const float* nb1 = (const float*)d_in[36];
  const float* nw2 = (const float*)d_in[37]; const float* nb2 = (const float*)d_in[38];

  // workspace layout (floats); total 65,515,520 floats = 249.9 MiB
  float* ws = (float*)d_ws;
  float* Ssm  = ws;               // 16384 (dead after TRN -> reused for cw1g/cw2g)
  float* cwsm = ws + 16384;       // 4096
  float* comm = ws + 20480;       // 4,194,304  (B,N,64)
  float* AI   = ws + 4214784;     // 12,582,912 (B,N,192): ai -> combined -> ce
  float* H1   = ws + 16797696;    // 16,777,216 (B,N,256)
  float* HCG  = ws + 33574912;    // 16,777,216 (B,N,256)
  unsigned short* wbf = (unsigned short*)(ws + 50352128);  // bf16 weights
  unsigned short* SsmT  = wbf;             // 16384
  unsigned short* wcT   = wbf + 16384;     // 65536 (reused per GAT layer)
  unsigned short* aw1T  = wbf + 81920;     // 3,145,728
  unsigned short* aw2T  = wbf + 3227648;   // 4,194,304
  unsigned short* aw3T  = wbf + 7421952;   // 262,144
  unsigned short* crw1T = wbf + 7684096;   // 3,145,728
  unsigned short* crw2T = wbf + 10829824;  // 4,194,304
  unsigned short* crw3T = wbf + 15024128;  // 16,384
  unsigned short* cew1T = wbf + 15040512;  // 2,359,296
  unsigned short* cew2T = wbf + 17399808;  // 65,536
  unsigned short* cew3T = wbf + 17465344;  // 16,384
  unsigned short* mw1T  = wbf + 17481728;  // 2,359,296
  unsigned short* mw2T  = wbf + 19841024;  // 4,194,304
  unsigned short* mw3T  = wbf + 24035328;  // 2,097,152
  unsigned short* nw1T  = wbf + 26132480;  // 2,097,152
  unsigned short* nw2T  = wbf + 28229632;  // 2,097,152
  // cw bf16 hi/lo live in the dead Ssm region (after TRN(Ssm) has consumed it)
  unsigned short* cw1g = (unsigned short*)ws;   // 4096
  unsigned short* cw2g = cw1g + 4096;           // 4096

  float* out_actor = (float*)d_out;
  float* out_critic = out_actor + 1048576;
  float* out_cent = out_critic + 65536;
  float* out_scm = out_cent + 65536;

  auto GEMM64 = [&](const float* A, const unsigned short* BT, const float* bias, float* C,
                    int M, int N, int K, long long lda, long long ldc,
                    long long aBS, long long btBS, long long biasBS, long long cBS,
                    int act, int gz, int kPerSplit) {
    dim3 grid(M / 64, (N + 63) / 64, gz);
    hipLaunchKernelGGL(gemm_mfma_k, grid, dim3(256), 0, stream, A, BT, bias, C, M, N, K,
                       lda, ldc, aBS, btBS, biasBS, cBS, act, kPerSplit);
  };
  auto GEMM128 = [&](const float* A, const unsigned short* BT, const float* bias, float* C,
                     int M, int N, int K, long long lda, long long ldc,
                     long long aBS, long long btBS, long long biasBS, long long cBS,
                     int act, int gz, int kPerSplit) {
    dim3 grid(M / 128, (N + 127) / 128, gz);
    hipLaunchKernelGGL(gemm_mfma128_k, grid, dim3(256), 0, stream, A, BT, bias, C, M, N, K,
                       lda, ldc, aBS, btBS, biasBS, cBS, act, kPerSplit);
  };
  auto TRN = [&](const float* in, unsigned short* out, int Z, int K, int N) {
    dim3 grid((K + 31) / 32, (N + 31) / 32, Z);
    hipLaunchKernelGGL(transpose_cvt_k, grid, dim3(32, 8), 0, stream, in, out, K, N);
  };

  // 0) small softmaxes + weight conversions (one-time per launch)
  hipLaunchKernelGGL(softmax_rows_k, dim3(128), dim3(64), 0, stream, causal, Ssm, 128);
  hipLaunchKernelGGL(softmax_rows_k, dim3(64), dim3(64), 0, stream, scm_causal, cwsm, 64);
  TRN(Ssm, SsmT, 1, 128, 128);
  hipLaunchKernelGGL(cwbf_k, dim3(16), dim3(256), 0, stream, cwsm, cw1g, cw2g);  // after TRN(Ssm)
  TRN(aw1, aw1T, 64, 192, 256);  TRN(aw2, aw2T, 64, 256, 256);  TRN(aw3, aw3T, 64, 256, 16);
  TRN(crw1, crw1T, 64, 192, 256); TRN(crw2, crw2T, 64, 256, 256); TRN(crw3, crw3T, 64, 256, 1);
  TRN(cew1, cew1T, 1, 9216, 256); TRN(cew2, cew2T, 1, 256, 256);  TRN(cew3, cew3T, 1, 256, 64);
  TRN(mw1, mw1T, 64, 144, 256);  TRN(mw2, mw2T, 64, 256, 256);  TRN(mw3, mw3T, 64, 256, 128);
  TRN(nw1, nw1T, 64, 128, 256);  TRN(nw2, nw2T, 64, 256, 128);

  // 1) plain GAT -> comm (init)
  hipLaunchKernelGGL(repack_wT_k, dim3((NH * 128 * 64 + 255) / 256), dim3(256), 0, stream, gat_W, wcT, 128);
  GEMM128(obs, wcT, nullptr, H1, 65536, 256, 128, 128, 256, 0, 0, 0, 0, 0, 1, 0);     // xt1
  hipLaunchKernelGGL(gat_attn4_k, dim3(1024), dim3(256), 0, stream, H1, gat_a, adj, comm, 0);

  // 2) causal GAT
  GEMM128(obs, SsmT, nullptr, HCG, 65536, 128, 128, 128, 128, 0, 0, 0, 0, 0, 1, 0);   // xm
  hipLaunchKernelGGL(repack_wT_k, dim3((NH * 128 * 64 + 255) / 256), dim3(256), 0, stream, cg_W0, wcT, 128);
  GEMM128(HCG, wcT, nullptr, H1, 65536, 256, 128, 128, 256, 0, 0, 0, 0, 0, 1, 0);     // xt_cg0
  hipLaunchKernelGGL(gat_attn4_k, dim3(1024), dim3(256), 0, stream, H1, cg_a0, adj, HCG, 2); // hcg (ELU)
  hipLaunchKernelGGL(repack_wT_k, dim3((NH * 256 * 64 + 255) / 256), dim3(256), 0, stream, cg_W1, wcT, 256);
  GEMM128(HCG, wcT, nullptr, H1, 65536, 256, 256, 256, 256, 0, 0, 0, 0, 0, 1, 0);     // xt_cg1
  hipLaunchKernelGGL(gat_attn4_k, dim3(1024), dim3(256), 0, stream, H1, cg_a1, adj, comm, 1);

  // 3) ai = [obs, comm]
  hipLaunchKernelGGL(build_ai_k, dim3((12582912 + 255) / 256), dim3(256), 0, stream, obs, comm, AI);

  // 4) actor MLP (per-agent)
  GEMM128(AI, aw1T, ab1, H1, 1024, 256, 192, 12288, 16384, 192, 49152, 256, 256, 1, 64, 0);
  GEMM128(H1, aw2T, ab2, HCG, 1024, 256, 256, 16384, 16384, 256, 65536, 256, 256, 1, 64, 0);
  GEMM64(HCG, aw3T, ab3, out_actor, 1024, 16, 256, 16384, 1024, 256, 4096, 16, 16, 0, 64, 0);

  // 5) critic MLP (per-agent)
  GEMM128(AI, crw1T, crb1, H1, 1024, 256, 192, 12288, 16384, 192, 49152, 256, 256, 1, 64, 0);
  GEMM128(H1, crw2T, crb2, HCG, 1024, 256, 256, 16384, 16384, 256, 65536, 256, 256, 1, 64, 0);
  GEMM64(HCG, crw3T, crb3, out_critic, 1024, 1, 256, 16384, 64, 256, 256, 1, 1, 0, 64, 0);

  // 6) centralized critic (combined -> AI)
  hipLaunchKernelGGL(build_combined_k, dim3((9437184 + 255) / 256), dim3(256), 0, stream, obs, acts, AI);
  GEMM128(AI, cew1T, nullptr, H1, 1024, 256, 9216, 9216, 256, 0, 0, 0, 262144, 0, 16, 576);
  hipLaunchKernelGGL(reduce_bias_relu_k, dim3(1024), dim3(256), 0, stream, H1, ceb1, HCG);
  GEMM64(HCG, cew2T, ceb2, H1, 1024, 256, 256, 256, 256, 0, 0, 0, 0, 1, 1, 0);
  GEMM64(H1, cew3T, ceb3, out_cent, 1024, 64, 256, 256, 64, 0, 0, 0, 0, 0, 1, 0);

  // 7) SCM mechanisms (input = combined in AI)
  GEMM128(AI, mw1T, mb1, H1, 1024, 256, 144, 9216, 16384, 144, 36864, 256, 256, 1, 64, 0);
  GEMM128(H1, mw2T, mb2, HCG, 1024, 256, 256, 16384, 16384, 256, 65536, 256, 256, 1, 64, 0);
  GEMM128(HCG, mw3T, mb3, AI, 1024, 128, 256, 16384, 8192, 256, 32768, 128, 128, 0, 64, 0); // ce -> AI

  // 8) noise model (input = obs)
  GEMM128(obs, nw1T, nb1, H1, 1024, 256, 128, 8192, 16384, 128, 32768, 256, 256, 1, 64, 0);
  GEMM128(H1, nw2T, nb2, HCG, 1024, 128, 256, 16384, 8192, 256, 32768, 128, 128, 0, 64, 0); // noise -> HCG

  // 9) scm_pred = softmax(scm_causal) @ ce + noise  (MFMA)
  hipLaunchKernelGGL(se_noise_mfma_k, dim3(1024), dim3(256), 0, stream, cw1g, cw2g, AI, HCG, out_scm);
}

// Round 4
// 936.412 us; speedup vs baseline: 1.2663x; 1.0752x over previous
//
#include <hip/hip_runtime.h>
#include <hip/hip_bf16.h>
#include <math.h>

// Problem constants
#define NB 1024    // batch
#define NAG 64     // agents
#define OBS 128
#define ACTD 16
#define HID 256
#define GD 64
#define NH 4       // heads

typedef short bhalf8 __attribute__((ext_vector_type(8)));
typedef float f32x4 __attribute__((ext_vector_type(4)));

__device__ inline unsigned short f2bf_u(float f) {
  __hip_bfloat16 h = __float2bfloat16(f);
  return *(unsigned short*)&h;
}
__device__ inline float bfu2f(unsigned short u) {
  unsigned v = ((unsigned)u) << 16;
  return *(float*)&v;
}
__device__ inline unsigned pk2(float x, float y) {
  float2 f2; f2.x = x; f2.y = y;
  __hip_bfloat162 h = __float22bfloat162_rn(f2);
  return *(unsigned*)&h;
}

// ---------------- row softmax ----------------
__global__ __launch_bounds__(64) void softmax_rows_k(const float* __restrict__ in,
                                                     float* __restrict__ out, int n) {
  int row = blockIdx.x;
  int lane = threadIdx.x;
  const float* r = in + (size_t)row * n;
  float m = -INFINITY;
  for (int j = lane; j < n; j += 64) m = fmaxf(m, r[j]);
#pragma unroll
  for (int off = 32; off; off >>= 1) m = fmaxf(m, __shfl_xor(m, off));
  float s = 0.f;
  for (int j = lane; j < n; j += 64) s += expf(r[j] - m);
#pragma unroll
  for (int off = 32; off; off >>= 1) s += __shfl_xor(s, off);
  float inv = 1.f / s;
  for (int j = lane; j < n; j += 64) out[(size_t)row * n + j] = expf(r[j] - m) * inv;
}

// ---------------- cw softmax -> bf16 hi/lo global ----------------
__global__ void cwbf_k(const float* __restrict__ cwsm, unsigned short* __restrict__ cw1,
                       unsigned short* __restrict__ cw2) {
  int idx = blockIdx.x * 256 + threadIdx.x;
  if (idx >= 4096) return;
  float v = cwsm[idx];
  unsigned short hi = f2bf_u(v);
  cw1[idx] = hi;
  cw2[idx] = f2bf_u(v - bfu2f(hi));
}

// ---------------- batched transpose+cvt: in (Z,K,N) f32 -> out (Z,N,K) bf16 ----------------
__global__ __launch_bounds__(256) void transpose_cvt_k(const float* __restrict__ in,
                                                       unsigned short* __restrict__ out,
                                                       int K, int N) {
  __shared__ float t[32][33];
  int k0 = blockIdx.x * 32, n0 = blockIdx.y * 32, z = blockIdx.z;
  int tx = threadIdx.x, ty = threadIdx.y;  // 32 x 8
  const float* ib = in + (size_t)z * K * N;
  unsigned short* ob = out + (size_t)z * N * K;
#pragma unroll
  for (int i = 0; i < 4; ++i) {
    int k = k0 + ty + 8 * i, n = n0 + tx;
    if (k < K && n < N) t[ty + 8 * i][tx] = ib[(size_t)k * N + n];
  }
  __syncthreads();
#pragma unroll
  for (int i = 0; i < 4; ++i) {
    int n = n0 + ty + 8 * i, k = k0 + tx;
    if (n < N && k < K) ob[(size_t)n * K + k] = f2bf_u(t[tx][ty + 8 * i]);
  }
}

// ---------------- GAT weight repack: W (H,F,D) -> WcT bf16 (H*D, F) ----------------
__global__ void repack_wT_k(const float* __restrict__ W, unsigned short* __restrict__ WcT, int F) {
  int idx = blockIdx.x * 256 + threadIdx.x;
  if (idx >= NH * F * 64) return;
  int d = idx & 63;
  int f = (idx >> 6) % F;
  int h = idx / (F * 64);
  WcT[((size_t)(h * 64 + d)) * F + f] = f2bf_u(W[idx]);
}

// ---------------- bf16 MFMA GEMM, 64x64 tile, pipelined (reg-prefetch + LDS ping-pong) ----
__global__ __launch_bounds__(256) void gemm_mfma_k(
    const float* __restrict__ A, const unsigned short* __restrict__ BT,
    const float* __restrict__ bias, float* __restrict__ C,
    int M, int N, int K,
    long long lda, long long ldc,
    long long aBS, long long btBS, long long biasBS, long long cBS,
    int act, int kPerSplit) {
  __shared__ unsigned short As[2][64 * 40];
  __shared__ unsigned short Bs[2][64 * 40];
  int tid = threadIdx.x;
  int wave = tid >> 6, lane = tid & 63;
  int m0 = blockIdx.x * 64, n0 = blockIdx.y * 64;
  int z = blockIdx.z;
  const float* Ab;
  const unsigned short* Bb;
  const float* biasb = nullptr;
  float* Cb;
  int k_begin, k_end;
  if (kPerSplit > 0) {
    Ab = A; Bb = BT; Cb = C + (long long)z * cBS;
    k_begin = z * kPerSplit;
    k_end = k_begin + kPerSplit;
    if (k_end > K) k_end = K;
  } else {
    Ab = A + (long long)z * aBS;
    Bb = BT + (long long)z * btBS;
    if (bias) biasb = bias + (long long)z * biasBS;
    Cb = C + (long long)z * cBS;
    k_begin = 0; k_end = K;
  }
  int sr = tid >> 2;
  int sk = (tid & 3) * 8;
  int fr = lane & 15;
  int kq = (lane >> 4) * 8;

  f32x4 zf = {0.f, 0.f, 0.f, 0.f};
  f32x4 acc[4] = {zf, zf, zf, zf};

  const unsigned short* bRow = Bb + (long long)(n0 + sr) * K;
  bool bValid = (n0 + sr) < N;
  const float* aRow = Ab + (long long)(m0 + sr) * lda;

  int nt = (k_end - k_begin + 31) / 32;

  float av[8];
  uint4 bv;

  auto LOADT = [&](int t) {
    int kk = k_begin + 32 * t + sk;
    if (kk + 7 < k_end) {
      const float* ap = aRow + kk;
      *(float4*)&av[0] = *(const float4*)ap;
      *(float4*)&av[4] = *(const float4*)(ap + 4);
    } else {
#pragma unroll
      for (int j = 0; j < 8; ++j) av[j] = (kk + j < k_end) ? aRow[kk + j] : 0.f;
    }
    bv.x = bv.y = bv.z = bv.w = 0u;
    if (bValid) {
      if (kk + 7 < k_end) {
        bv = *(const uint4*)(bRow + kk);
      } else {
        unsigned short tb[8];
#pragma unroll
        for (int j = 0; j < 8; ++j) tb[j] = (kk + j < k_end) ? bRow[kk + j] : (unsigned short)0;
        bv.x = (unsigned)tb[0] | ((unsigned)tb[1] << 16);
        bv.y = (unsigned)tb[2] | ((unsigned)tb[3] << 16);
        bv.z = (unsigned)tb[4] | ((unsigned)tb[5] << 16);
        bv.w = (unsigned)tb[6] | ((unsigned)tb[7] << 16);
      }
    }
  };
  auto STORE = [&](int buf) {
    uint4 aw;
    aw.x = pk2(av[0], av[1]); aw.y = pk2(av[2], av[3]);
    aw.z = pk2(av[4], av[5]); aw.w = pk2(av[6], av[7]);
    *(uint4*)&As[buf][sr * 40 + sk] = aw;
    *(uint4*)&Bs[buf][sr * 40 + sk] = bv;
  };

  LOADT(0);
  STORE(0);
  if (nt > 1) LOADT(1);
  __syncthreads();

  for (int t = 0; t < nt; ++t) {
    int cur = t & 1;
    if (t + 1 < nt) {
      STORE(cur ^ 1);               // regs hold tile t+1 (loaded last iter)
      if (t + 2 < nt) LOADT(t + 2); // issue next loads; hide under MFMA below
    }
    bhalf8 af = *(bhalf8*)&As[cur][(16 * wave + fr) * 40 + kq];
#pragma unroll
    for (int t4 = 0; t4 < 4; ++t4) {
      bhalf8 bf = *(bhalf8*)&Bs[cur][(16 * t4 + fr) * 40 + kq];
      acc[t4] = __builtin_amdgcn_mfma_f32_16x16x32_bf16(af, bf, acc[t4], 0, 0, 0);
    }
    if (t + 1 < nt) __syncthreads();
  }
  int rb = (lane >> 4) * 4;
#pragma unroll
  for (int t = 0; t < 4; ++t) {
    int col = n0 + 16 * t + fr;
    if (col < N) {
      float bv2 = biasb ? biasb[col] : 0.f;
#pragma unroll
      for (int r = 0; r < 4; ++r) {
        long long row = m0 + 16 * wave + rb + r;
        float v = acc[t][r] + bv2;
        if (act == 1) v = fmaxf(v, 0.f);
        Cb[row * ldc + col] = v;
      }
    }
  }
}

// ---------------- bf16 MFMA GEMM, 128x128 tile, pipelined (reg-prefetch + LDS ping-pong) ----
// Requires M % 128 == 0. N guarded. A (M,K) f32; BT (N,K) bf16.
__global__ __launch_bounds__(256, 4) void gemm_mfma128_k(
    const float* __restrict__ A, const unsigned short* __restrict__ BT,
    const float* __restrict__ bias, float* __restrict__ C,
    int M, int N, int K,
    long long lda, long long ldc,
    long long aBS, long long btBS, long long biasBS, long long cBS,
    int act, int kPerSplit) {
  __shared__ unsigned short As[2][128 * 40];
  __shared__ unsigned short Bs[2][128 * 40];
  int tid = threadIdx.x;
  int wave = tid >> 6, lane = tid & 63;
  int m0 = blockIdx.x * 128, n0 = blockIdx.y * 128;
  int z = blockIdx.z;
  const float* Ab;
  const unsigned short* Bb;
  const float* biasb = nullptr;
  float* Cb;
  int k_begin, k_end;
  if (kPerSplit > 0) {
    Ab = A; Bb = BT; Cb = C + (long long)z * cBS;
    k_begin = z * kPerSplit;
    k_end = k_begin + kPerSplit;
    if (k_end > K) k_end = K;
  } else {
    Ab = A + (long long)z * aBS;
    Bb = BT + (long long)z * btBS;
    if (bias) biasb = bias + (long long)z * biasBS;
    Cb = C + (long long)z * cBS;
    k_begin = 0; k_end = K;
  }
  int sr = tid >> 1;          // staging row 0..127
  int sk = (tid & 1) * 16;    // k-half
  int mq = (wave >> 1) * 64;  // wave quadrant
  int nq = (wave & 1) * 64;
  int fr = lane & 15;
  int kq = (lane >> 4) * 8;

  f32x4 zf = {0.f, 0.f, 0.f, 0.f};
  f32x4 acc[4][4];
#pragma unroll
  for (int i = 0; i < 4; ++i)
#pragma unroll
    for (int j = 0; j < 4; ++j) acc[i][j] = zf;

  const float* aRow = Ab + (long long)(m0 + sr) * lda;
  const unsigned short* bRow = Bb + (long long)(n0 + sr) * K;
  bool bValid = (n0 + sr) < N;

  int nt = (k_end - k_begin + 31) / 32;

  float av[16];
  uint4 bv0, bv1;

  auto LOADT = [&](int t) {
    int kk = k_begin + 32 * t + sk;
    if (kk + 15 < k_end) {
      const float* ap = aRow + kk;
      *(float4*)&av[0]  = *(const float4*)ap;
      *(float4*)&av[4]  = *(const float4*)(ap + 4);
      *(float4*)&av[8]  = *(const float4*)(ap + 8);
      *(float4*)&av[12] = *(const float4*)(ap + 12);
    } else {
#pragma unroll
      for (int j = 0; j < 16; ++j) av[j] = (kk + j < k_end) ? aRow[kk + j] : 0.f;
    }
    bv0.x = bv0.y = bv0.z = bv0.w = 0u;
    bv1.x = bv1.y = bv1.z = bv1.w = 0u;
    if (bValid) {
      if (kk + 15 < k_end) {
        bv0 = *(const uint4*)(bRow + kk);
        bv1 = *(const uint4*)(bRow + kk + 8);
      } else {
        unsigned short tb[16];
#pragma unroll
        for (int j = 0; j < 16; ++j) tb[j] = (kk + j < k_end) ? bRow[kk + j] : (unsigned short)0;
        bv0.x = (unsigned)tb[0] | ((unsigned)tb[1] << 16);
        bv0.y = (unsigned)tb[2] | ((unsigned)tb[3] << 16);
        bv0.z = (unsigned)tb[4] | ((unsigned)tb[5] << 16);
        bv0.w = (unsigned)tb[6] | ((unsigned)tb[7] << 16);
        bv1.x = (unsigned)tb[8] | ((unsigned)tb[9] << 16);
        bv1.y = (unsigned)tb[10] | ((unsigned)tb[11] << 16);
        bv1.z = (unsigned)tb[12] | ((unsigned)tb[13] << 16);
        bv1.w = (unsigned)tb[14] | ((unsigned)tb[15] << 16);
      }
    }
  };
  auto STORE = [&](int buf) {
    uint4 aw0, aw1;
    aw0.x = pk2(av[0], av[1]);   aw0.y = pk2(av[2], av[3]);
    aw0.z = pk2(av[4], av[5]);   aw0.w = pk2(av[6], av[7]);
    aw1.x = pk2(av[8], av[9]);   aw1.y = pk2(av[10], av[11]);
    aw1.z = pk2(av[12], av[13]); aw1.w = pk2(av[14], av[15]);
    *(uint4*)&As[buf][sr * 40 + sk] = aw0;
    *(uint4*)&As[buf][sr * 40 + sk + 8] = aw1;
    *(uint4*)&Bs[buf][sr * 40 + sk] = bv0;
    *(uint4*)&Bs[buf][sr * 40 + sk + 8] = bv1;
  };

  LOADT(0);
  STORE(0);
  if (nt > 1) LOADT(1);
  __syncthreads();

  for (int t = 0; t < nt; ++t) {
    int cur = t & 1;
    if (t + 1 < nt) {
      STORE(cur ^ 1);               // regs hold tile t+1 (loaded last iter)
      if (t + 2 < nt) LOADT(t + 2); // issue next loads; hide under MFMA below
    }
    bhalf8 af[4], bf[4];
#pragma unroll
    for (int i = 0; i < 4; ++i) af[i] = *(bhalf8*)&As[cur][(mq + 16 * i + fr) * 40 + kq];
#pragma unroll
    for (int j = 0; j < 4; ++j) bf[j] = *(bhalf8*)&Bs[cur][(nq + 16 * j + fr) * 40 + kq];
#pragma unroll
    for (int i = 0; i < 4; ++i)
#pragma unroll
      for (int j = 0; j < 4; ++j)
        acc[i][j] = __builtin_amdgcn_mfma_f32_16x16x32_bf16(af[i], bf[j], acc[i][j], 0, 0, 0);
    if (t + 1 < nt) __syncthreads();
  }
  // ---- epilogue
  int rb = (lane >> 4) * 4;
#pragma unroll
  for (int j = 0; j < 4; ++j) {
    int col = n0 + nq + 16 * j + fr;
    if (col < N) {
      float bv2 = biasb ? biasb[col] : 0.f;
#pragma unroll
      for (int i = 0; i < 4; ++i) {
#pragma unroll
        for (int r = 0; r < 4; ++r) {
          long long row = m0 + mq + 16 * i + rb + r;
          float v = acc[i][j][r] + bv2;
          if (act == 1) v = fmaxf(v, 0.f);
          Cb[row * ldc + col] = v;
        }
      }
    }
  }
}

// ---------------- GAT attention, 4 waves per graph, head loop inside ----------------
// xt layout: (B*N, NH*GD). mode: 0 = comm = 0.25*sum_h att ; 1 = comm += ; 2 = concat+ELU
__global__ __launch_bounds__(256, 4) void gat_attn4_k(
    const float* __restrict__ xt, const float* __restrict__ a,
    const float* __restrict__ adj, float* __restrict__ out, int mode) {
  int b = blockIdx.x;
  int tid = threadIdx.x;
  int wave = tid >> 6, lane = tid & 63;
  __shared__ unsigned short xT1[64 * 72];  // X^T hi  [d][j]
  __shared__ unsigned short xT2[64 * 72];  // X^T lo
  __shared__ unsigned short P1[64 * 72];   // exp weights hi [i][j]
  __shared__ unsigned short P2[64 * 72];   // exp weights lo
  __shared__ float si_s[64], sj_s[64];

  const float* adjb = adj + (size_t)b * 4096;
  float adjv[16];
#pragma unroll
  for (int r = 0; r < 16; ++r) adjv[r] = adjb[(size_t)(wave * 16 + r) * 64 + lane];

  int lrow = tid >> 2;   // j (agent) this thread projects (phase A1)
  int cg = tid & 3;      // 16-wide column group
  int fr = lane & 15;
  int kq = (lane >> 4) * 8;
  int ibase = wave * 16;

  bhalf8 ones;
#pragma unroll
  for (int u = 0; u < 8; ++u) ones[u] = (short)0x3F80;  // 1.0 bf16

  f32x4 zf = {0.f, 0.f, 0.f, 0.f};
  f32x4 accm[4] = {zf, zf, zf, zf};  // head-mean accum (mode 0/1)

  for (int h = 0; h < 4; ++h) {
    // ---- A2 loads: column gather for X^T (coalesced across lanes; L2-hot)
    const float* xcol = xt + ((size_t)(b * 64 + 16 * wave)) * 256 + h * 64 + lane;
    float v[16];
#pragma unroll
    for (int u = 0; u < 16; ++u) v[u] = xcol[(size_t)u * 256];

    // ---- A1: si/sj projections (row loads)
    const float* xrow = xt + ((size_t)(b * 64 + lrow)) * 256 + h * 64 + cg * 16;
    const float* ah = a + h * 128;
    float p1 = 0.f, p2 = 0.f;
#pragma unroll
    for (int q = 0; q < 4; ++q) {
      float4 rv = *(const float4*)(xrow + 4 * q);
      int c = cg * 16 + 4 * q;
      p1 += rv.x * ah[c] + rv.y * ah[c + 1] + rv.z * ah[c + 2] + rv.w * ah[c + 3];
      p2 += rv.x * ah[64 + c] + rv.y * ah[64 + c + 1] + rv.z * ah[64 + c + 2] + rv.w * ah[64 + c + 3];
    }
    p1 += __shfl_xor(p1, 1); p1 += __shfl_xor(p1, 2);
    p2 += __shfl_xor(p2, 1); p2 += __shfl_xor(p2, 2);
    if (cg == 0) { si_s[lrow] = p1; sj_s[lrow] = p2; }

    // ---- A2 stores: cvt hi/lo, pack, b128 writes (row d=lane, j block 16*wave)
    {
      float hf[16];
      uint4 h0, h1, l0, l1;
#pragma unroll
      for (int u = 0; u < 16; ++u) hf[u] = bfu2f(f2bf_u(v[u]));
      h0.x = pk2(hf[0], hf[1]);   h0.y = pk2(hf[2], hf[3]);
      h0.z = pk2(hf[4], hf[5]);   h0.w = pk2(hf[6], hf[7]);
      h1.x = pk2(hf[8], hf[9]);   h1.y = pk2(hf[10], hf[11]);
      h1.z = pk2(hf[12], hf[13]); h1.w = pk2(hf[14], hf[15]);
      l0.x = pk2(v[0] - hf[0], v[1] - hf[1]);     l0.y = pk2(v[2] - hf[2], v[3] - hf[3]);
      l0.z = pk2(v[4] - hf[4], v[5] - hf[5]);     l0.w = pk2(v[6] - hf[6], v[7] - hf[7]);
      l1.x = pk2(v[8] - hf[8], v[9] - hf[9]);     l1.y = pk2(v[10] - hf[10], v[11] - hf[11]);
      l1.z = pk2(v[12] - hf[12], v[13] - hf[13]); l1.w = pk2(v[14] - hf[14], v[15] - hf[15]);
      int base = lane * 72 + 16 * wave;
      *(uint4*)&xT1[base] = h0;
      *(uint4*)&xT1[base + 8] = h1;
      *(uint4*)&xT2[base] = l0;
      *(uint4*)&xT2[base + 8] = l1;
    }
    __syncthreads();

    // ---- B: per-row exp weights, no reductions
    float sjv = sj_s[lane];
    float maxsj = sjv;
#pragma unroll
    for (int off = 32; off; off >>= 1) maxsj = fmaxf(maxsj, __shfl_xor(maxsj, off));
#pragma unroll
    for (int r = 0; r < 16; ++r) {
      int i = ibase + r;
      float siv = si_s[i];
      float tM = siv + maxsj;
      float Mi = tM > 0.f ? tM : 0.2f * tM;   // >= max_j e (leaky monotone)
      float e = siv + sjv;
      e = e > 0.f ? e : 0.2f * e;
      float p = (adjv[r] == 0.f) ? 0.f : expf(e - Mi);
      unsigned short phi = f2bf_u(p);
      P1[i * 72 + lane] = phi;
      P2[i * 72 + lane] = f2bf_u(p - bfu2f(phi));
    }
    // P rows are wave-local (written and read by the same wave) -> no barrier.

    // ---- C: MFMA aggregation + row sums
    bhalf8 a1[2], a2[2];
#pragma unroll
    for (int ks = 0; ks < 2; ++ks) {
      a1[ks] = *(bhalf8*)&P1[(ibase + fr) * 72 + ks * 32 + kq];
      a2[ks] = *(bhalf8*)&P2[(ibase + fr) * 72 + ks * 32 + kq];
    }
    f32x4 accS = zf;
#pragma unroll
    for (int ks = 0; ks < 2; ++ks) {
      accS = __builtin_amdgcn_mfma_f32_16x16x32_bf16(a1[ks], ones, accS, 0, 0, 0);
      accS = __builtin_amdgcn_mfma_f32_16x16x32_bf16(a2[ks], ones, accS, 0, 0, 0);
    }
    f32x4 acc[4] = {zf, zf, zf, zf};
#pragma unroll
    for (int ks = 0; ks < 2; ++ks) {
#pragma unroll
      for (int t = 0; t < 4; ++t) {
        bhalf8 b1 = *(bhalf8*)&xT1[(16 * t + fr) * 72 + ks * 32 + kq];
        bhalf8 b2 = *(bhalf8*)&xT2[(16 * t + fr) * 72 + ks * 32 + kq];
        acc[t] = __builtin_amdgcn_mfma_f32_16x16x32_bf16(a1[ks], b1, acc[t], 0, 0, 0);
        acc[t] = __builtin_amdgcn_mfma_f32_16x16x32_bf16(a1[ks], b2, acc[t], 0, 0, 0);
        acc[t] = __builtin_amdgcn_mfma_f32_16x16x32_bf16(a2[ks], b1, acc[t], 0, 0, 0);
      }
    }
    f32x4 inv;
#pragma unroll
    for (int r = 0; r < 4; ++r) inv[r] = (accS[r] > 0.f) ? 1.f / accS[r] : 0.f;

    int rb = (lane >> 4) * 4;
    if (mode == 2) {
#pragma unroll
      for (int t = 0; t < 4; ++t) {
#pragma unroll
        for (int r = 0; r < 4; ++r) {
          int i = ibase + rb + r;
          float vv = acc[t][r] * inv[r];
          vv = vv > 0.f ? vv : expf(vv) - 1.f;
          out[((size_t)(b * 64 + i)) * 256 + h * 64 + 16 * t + fr] = vv;
        }
      }
    } else {
#pragma unroll
      for (int t = 0; t < 4; ++t)
#pragma unroll
        for (int r = 0; r < 4; ++r) accm[t][r] += 0.25f * acc[t][r] * inv[r];
    }
    __syncthreads();  // xT/si/sj reuse for next head
  }

  if (mode != 2) {
    int rb = (lane >> 4) * 4;
    float* cb = out + (size_t)b * 4096;
#pragma unroll
    for (int t = 0; t < 4; ++t) {
#pragma unroll
      for (int r = 0; r < 4; ++r) {
        int i = ibase + rb + r;
        int col = 16 * t + fr;
        if (mode == 1) cb[i * 64 + col] += accm[t][r];
        else cb[i * 64 + col] = accm[t][r];
      }
    }
  }
}

// ---------------- ai = [obs, comm] (B,N,192) ----------------
__global__ void build_ai_k(const float* __restrict__ obs, const float* __restrict__ comm,
                           float* __restrict__ ai) {
  size_t idx = (size_t)blockIdx.x * 256 + threadIdx.x;
  if (idx >= (size_t)NB * NAG * 192) return;
  int c = (int)(idx % 192);
  size_t bn = idx / 192;
  ai[idx] = (c < 128) ? obs[bn * 128 + c] : comm[bn * 64 + (c - 128)];
}

// ---------------- combined = [obs, actions] (B,N,144) ----------------
__global__ void build_combined_k(const float* __restrict__ obs, const float* __restrict__ act,
                                 float* __restrict__ cmb) {
  size_t idx = (size_t)blockIdx.x * 256 + threadIdx.x;
  if (idx >= (size_t)NB * NAG * 144) return;
  int c = (int)(idx % 144);
  size_t bn = idx / 144;
  cmb[idx] = (c < 128) ? obs[bn * 128 + c] : act[bn * 16 + (c - 128)];
}

// ---------------- split-K reduce + bias + relu for cent l1 ----------------
__global__ void reduce_bias_relu_k(const float* __restrict__ part, const float* __restrict__ bias,
                                   float* __restrict__ out) {
  int idx = blockIdx.x * 256 + threadIdx.x;
  float s = 0.f;
#pragma unroll
  for (int zz = 0; zz < 16; ++zz) s += part[(size_t)zz * 262144 + idx];
  s += bias[idx & 255];
  out[idx] = fmaxf(s, 0.f);
}

// ---------------- scm_pred = cw @ ce + noise (MFMA, hi/lo split) ----------------
__global__ __launch_bounds__(256, 4) void se_noise_mfma_k(
    const unsigned short* __restrict__ cw1, const unsigned short* __restrict__ cw2,
    const float* __restrict__ ce, const float* __restrict__ nz,
    float* __restrict__ out) {
  int b = blockIdx.x;
  int tid = threadIdx.x;
  int wave = tid >> 6, lane = tid & 63;
  __shared__ unsigned short xT1[128 * 72];  // ce^T hi [d][j]
  __shared__ unsigned short xT2[128 * 72];  // ce^T lo

  int dd = tid & 127;
  int jh = tid >> 7;  // 0 or 1 -> j block of 32
  const float* cecol = ce + (size_t)b * 8192 + dd;
#pragma unroll
  for (int c = 0; c < 2; ++c) {
    int j0 = jh * 32 + c * 16;
    float v[16];
#pragma unroll
    for (int u = 0; u < 16; ++u) v[u] = cecol[(size_t)(j0 + u) * 128];
    float hf[16];
#pragma unroll
    for (int u = 0; u < 16; ++u) hf[u] = bfu2f(f2bf_u(v[u]));
    uint4 h0, h1, l0, l1;
    h0.x = pk2(hf[0], hf[1]);   h0.y = pk2(hf[2], hf[3]);
    h0.z = pk2(hf[4], hf[5]);   h0.w = pk2(hf[6], hf[7]);
    h1.x = pk2(hf[8], hf[9]);   h1.y = pk2(hf[10], hf[11]);
    h1.z = pk2(hf[12], hf[13]); h1.w = pk2(hf[14], hf[15]);
    l0.x = pk2(v[0] - hf[0], v[1] - hf[1]);     l0.y = pk2(v[2] - hf[2], v[3] - hf[3]);
    l0.z = pk2(v[4] - hf[4], v[5] - hf[5]);     l0.w = pk2(v[6] - hf[6], v[7] - hf[7]);
    l1.x = pk2(v[8] - hf[8], v[9] - hf[9]);     l1.y = pk2(v[10] - hf[10], v[11] - hf[11]);
    l1.z = pk2(v[12] - hf[12], v[13] - hf[13]); l1.w = pk2(v[14] - hf[14], v[15] - hf[15]);
    int base = dd * 72 + j0;
    *(uint4*)&xT1[base] = h0;
    *(uint4*)&xT1[base + 8] = h1;
    *(uint4*)&xT2[base] = l0;
    *(uint4*)&xT2[base + 8] = l1;
  }
  __syncthreads();

  int fr = lane & 15;
  int kq = (lane >> 4) * 8;
  int dq = wave * 32;

  bhalf8 bb1[2][2], bb2[2][2];
#pragma unroll
  for (int dt = 0; dt < 2; ++dt)
#pragma unroll
    for (int ks = 0; ks < 2; ++ks) {
      bb1[dt][ks] = *(bhalf8*)&xT1[(dq + dt * 16 + fr) * 72 + ks * 32 + kq];
      bb2[dt][ks] = *(bhalf8*)&xT2[(dq + dt * 16 + fr) * 72 + ks * 32 + kq];
    }

  f32x4 zf = {0.f, 0.f, 0.f, 0.f};
  f32x4 acc[4][2];
#pragma unroll
  for (int it = 0; it < 4; ++it)
#pragma unroll
    for (int dt = 0; dt < 2; ++dt) acc[it][dt] = zf;

#pragma unroll
  for (int it = 0; it < 4; ++it) {
    bhalf8 a1[2], a2[2];
#pragma unroll
    for (int ks = 0; ks < 2; ++ks) {
      a1[ks] = *(const bhalf8*)(cw1 + (it * 16 + fr) * 64 + ks * 32 + kq);
      a2[ks] = *(const bhalf8*)(cw2 + (it * 16 + fr) * 64 + ks * 32 + kq);
    }
#pragma unroll
    for (int dt = 0; dt < 2; ++dt)
#pragma unroll
      for (int ks = 0; ks < 2; ++ks) {
        acc[it][dt] = __builtin_amdgcn_mfma_f32_16x16x32_bf16(a1[ks], bb1[dt][ks], acc[it][dt], 0, 0, 0);
        acc[it][dt] = __builtin_amdgcn_mfma_f32_16x16x32_bf16(a1[ks], bb2[dt][ks], acc[it][dt], 0, 0, 0);
        acc[it][dt] = __builtin_amdgcn_mfma_f32_16x16x32_bf16(a2[ks], bb1[dt][ks], acc[it][dt], 0, 0, 0);
      }
  }

  int rb = (lane >> 4) * 4;
#pragma unroll
  for (int it = 0; it < 4; ++it)
#pragma unroll
    for (int dt = 0; dt < 2; ++dt) {
      int dcol = dq + dt * 16 + fr;
#pragma unroll
      for (int r = 0; r < 4; ++r) {
        int i = it * 16 + rb + r;
        size_t off = (size_t)b * 8192 + (size_t)i * 128 + dcol;
        out[off] = acc[it][dt][r] + nz[off];
      }
    }
}

extern "C" void kernel_launch(void* const* d_in, const int* in_sizes, int n_in,
                              void* d_out, int out_size, void* d_ws, size_t ws_size,
                              hipStream_t stream) {
  (void)in_sizes; (void)n_in; (void)out_size; (void)ws_size;
  const float* obs = (const float*)d_in[0];
  const float* acts = (const float*)d_in[1];
  const float* adj = (const float*)d_in[2];
  const float* causal = (const float*)d_in[3];
  const float* gat_W = (const float*)d_in[4];
  const float* gat_a = (const float*)d_in[5];
  const float* cg_W0 = (const float*)d_in[6];
  const float* cg_a0 = (const float*)d_in[7];
  const float* cg_W1 = (const float*)d_in[8];
  const float* cg_a1 = (const float*)d_in[9];
  const float* aw1 = (const float*)d_in[10]; const float* ab1 = (const float*)d_in[11];
  const float* aw2 = (const float*)d_in[12]; const float* ab2 = (const float*)d_in[13];
  const float* aw3 = (const float*)d_in[14]; const float* ab3 = (const float*)d_in[15];
  const float* crw1 = (const float*)d_in[16]; const float* crb1 = (const float*)d_in[17];
  const float* crw2 = (const float*)d_in[18]; const float* crb2 = (const float*)d_in[19];
  const float* crw3 = (const float*)d_in[20]; const float* crb3 = (const float*)d_in[21];
  const float* cew1 = (const float*)d_in[22]; const float* ceb1 = (const float*)d_in[23];
  const float* cew2 = (const float*)d_in[24]; const float* ceb2 = (const float*)d_in[25];
  const float* cew3 = (const float*)d_in[26]; const float* ceb3 = (const float*)d_in[27];
  const float* scm_causal = (const float*)d_in[28];
  const float* mw1 = (const float*)d_in[29]; const float* mb1 = (const float*)d_in[30];
  const float* mw2 = (const float*)d_in[31]; const float* mb2 = (const float*)d_in[32];
  const float* mw3 = (const float*)d_in[33]; const float* mb3 = (const float*)d_in[34];
  const float* nw1 = (const float*)d_in[35]; const float* nb1 = (const float*)d_in[36];
  const float* nw2 = (const float*)d_in[37]; const float* nb2 = (const float*)d_in[38];

  // workspace layout (floats); total 65,515,520 floats = 249.9 MiB
  float* ws = (float*)d_ws;
  float* Ssm  = ws;               // 16384 (dead after TRN -> reused for cw1g/cw2g)
  float* cwsm = ws + 16384;       // 4096
  float* comm = ws + 20480;       // 4,194,304  (B,N,64)
  float* AI   = ws + 4214784;     // 12,582,912 (B,N,192): ai -> combined -> ce
  float* H1   = ws + 16797696;    // 16,777,216 (B,N,256)
  float* HCG  = ws + 33574912;    // 16,777,216 (B,N,256)
  unsigned short* wbf = (unsigned short*)(ws + 50352128);  // bf16 weights
  unsigned short* SsmT  = wbf;             // 16384
  unsigned short* wcT   = wbf + 16384;     // 65536 (reused per GAT layer)
  unsigned short* aw1T  = wbf + 81920;     // 3,145,728
  unsigned short* aw2T  = wbf + 3227648;   // 4,194,304
  unsigned short* aw3T  = wbf + 7421952;   // 262,144
  unsigned short* crw1T = wbf + 7684096;   // 3,145,728
  unsigned short* crw2T = wbf + 10829824;  // 4,194,304
  unsigned short* crw3T = wbf + 15024128;  // 16,384
  unsigned short* cew1T = wbf + 15040512;  // 2,359,296
  unsigned short* cew2T = wbf + 17399808;  // 65,536
  unsigned short* cew3T = wbf + 17465344;  // 16,384
  unsigned short* mw1T  = wbf + 17481728;  // 2,359,296
  unsigned short* mw2T  = wbf + 19841024;  // 4,194,304
  unsigned short* mw3T  = wbf + 24035328;  // 2,097,152
  unsigned short* nw1T  = wbf + 26132480;  // 2,097,152
  unsigned short* nw2T  = wbf + 28229632;  // 2,097,152
  // cw bf16 hi/lo live in the dead Ssm region (after TRN(Ssm) has consumed it)
  unsigned short* cw1g = (unsigned short*)ws;   // 4096
  unsigned short* cw2g = cw1g + 4096;           // 4096

  float* out_actor = (float*)d_out;
  float* out_critic = out_actor + 1048576;
  float* out_cent = out_critic + 65536;
  float* out_scm = out_cent + 65536;

  auto GEMM64 = [&](const float* A, const unsigned short* BT, const float* bias, float* C,
                    int M, int N, int K, long long lda, long long ldc,
                    long long aBS, long long btBS, long long biasBS, long long cBS,
                    int act, int gz, int kPerSplit) {
    dim3 grid(M / 64, (N + 63) / 64, gz);
    hipLaunchKernelGGL(gemm_mfma_k, grid, dim3(256), 0, stream, A, BT, bias, C, M, N, K,
                       lda, ldc, aBS, btBS, biasBS, cBS, act, kPerSplit);
  };
  auto GEMM128 = [&](const float* A, const unsigned short* BT, const float* bias, float* C,
                     int M, int N, int K, long long lda, long long ldc,
                     long long aBS, long long btBS, long long biasBS, long long cBS,
                     int act, int gz, int kPerSplit) {
    dim3 grid(M / 128, (N + 127) / 128, gz);
    hipLaunchKernelGGL(gemm_mfma128_k, grid, dim3(256), 0, stream, A, BT, bias, C, M, N, K,
                       lda, ldc, aBS, btBS, biasBS, cBS, act, kPerSplit);
  };
  auto TRN = [&](const float* in, unsigned short* out, int Z, int K, int N) {
    dim3 grid((K + 31) / 32, (N + 31) / 32, Z);
    hipLaunchKernelGGL(transpose_cvt_k, grid, dim3(32, 8), 0, stream, in, out, K, N);
  };

  // 0) small softmaxes + weight conversions (one-time per launch)
  hipLaunchKernelGGL(softmax_rows_k, dim3(128), dim3(64), 0, stream, causal, Ssm, 128);
  hipLaunchKernelGGL(softmax_rows_k, dim3(64), dim3(64), 0, stream, scm_causal, cwsm, 64);
  TRN(Ssm, SsmT, 1, 128, 128);
  hipLaunchKernelGGL(cwbf_k, dim3(16), dim3(256), 0, stream, cwsm, cw1g, cw2g);  // after TRN(Ssm)
  TRN(aw1, aw1T, 64, 192, 256);  TRN(aw2, aw2T, 64, 256, 256);  TRN(aw3, aw3T, 64, 256, 16);
  TRN(crw1, crw1T, 64, 192, 256); TRN(crw2, crw2T, 64, 256, 256); TRN(crw3, crw3T, 64, 256, 1);
  TRN(cew1, cew1T, 1, 9216, 256); TRN(cew2, cew2T, 1, 256, 256);  TRN(cew3, cew3T, 1, 256, 64);
  TRN(mw1, mw1T, 64, 144, 256);  TRN(mw2, mw2T, 64, 256, 256);  TRN(mw3, mw3T, 64, 256, 128);
  TRN(nw1, nw1T, 64, 128, 256);  TRN(nw2, nw2T, 64, 256, 128);

  // 1) plain GAT -> comm (init)
  hipLaunchKernelGGL(repack_wT_k, dim3((NH * 128 * 64 + 255) / 256), dim3(256), 0, stream, gat_W, wcT, 128);
  GEMM128(obs, wcT, nullptr, H1, 65536, 256, 128, 128, 256, 0, 0, 0, 0, 0, 1, 0);     // xt1
  hipLaunchKernelGGL(gat_attn4_k, dim3(1024), dim3(256), 0, stream, H1, gat_a, adj, comm, 0);

  // 2) causal GAT
  GEMM128(obs, SsmT, nullptr, HCG, 65536, 128, 128, 128, 128, 0, 0, 0, 0, 0, 1, 0);   // xm
  hipLaunchKernelGGL(repack_wT_k, dim3((NH * 128 * 64 + 255) / 256), dim3(256), 0, stream, cg_W0, wcT, 128);
  GEMM128(HCG, wcT, nullptr, H1, 65536, 256, 128, 128, 256, 0, 0, 0, 0, 0, 1, 0);     // xt_cg0
  hipLaunchKernelGGL(gat_attn4_k, dim3(1024), dim3(256), 0, stream, H1, cg_a0, adj, HCG, 2); // hcg (ELU)
  hipLaunchKernelGGL(repack_wT_k, dim3((NH * 256 * 64 + 255) / 256), dim3(256), 0, stream, cg_W1, wcT, 256);
  GEMM128(HCG, wcT, nullptr, H1, 65536, 256, 256, 256, 256, 0, 0, 0, 0, 0, 1, 0);     // xt_cg1
  hipLaunchKernelGGL(gat_attn4_k, dim3(1024), dim3(256), 0, stream, H1, cg_a1, adj, comm, 1);

  // 3) ai = [obs, comm]
  hipLaunchKernelGGL(build_ai_k, dim3((12582912 + 255) / 256), dim3(256), 0, stream, obs, comm, AI);

  // 4) actor MLP (per-agent)
  GEMM128(AI, aw1T, ab1, H1, 1024, 256, 192, 12288, 16384, 192, 49152, 256, 256, 1, 64, 0);
  GEMM128(H1, aw2T, ab2, HCG, 1024, 256, 256, 16384, 16384, 256, 65536, 256, 256, 1, 64, 0);
  GEMM64(HCG, aw3T, ab3, out_actor, 1024, 16, 256, 16384, 1024, 256, 4096, 16, 16, 0, 64, 0);

  // 5) critic MLP (per-agent)
  GEMM128(AI, crw1T, crb1, H1, 1024, 256, 192, 12288, 16384, 192, 49152, 256, 256, 1, 64, 0);
  GEMM128(H1, crw2T, crb2, HCG, 1024, 256, 256, 16384, 16384, 256, 65536, 256, 256, 1, 64, 0);
  GEMM64(HCG, crw3T, crb3, out_critic, 1024, 1, 256, 16384, 64, 256, 256, 1, 1, 0, 64, 0);

  // 6) centralized critic (combined -> AI)
  hipLaunchKernelGGL(build_combined_k, dim3((9437184 + 255) / 256), dim3(256), 0, stream, obs, acts, AI);
  GEMM128(AI, cew1T, nullptr, H1, 1024, 256, 9216, 9216, 256, 0, 0, 0, 262144, 0, 16, 576);
  hipLaunchKernelGGL(reduce_bias_relu_k, dim3(1024), dim3(256), 0, stream, H1, ceb1, HCG);
  GEMM64(HCG, cew2T, ceb2, H1, 1024, 256, 256, 256, 256, 0, 0, 0, 0, 1, 1, 0);
  GEMM64(H1, cew3T, ceb3, out_cent, 1024, 64, 256, 256, 64, 0, 0, 0, 0, 0, 1, 0);

  // 7) SCM mechanisms (input = combined in AI)
  GEMM128(AI, mw1T, mb1, H1, 1024, 256, 144, 9216, 16384, 144, 36864, 256, 256, 1, 64, 0);
  GEMM128(H1, mw2T, mb2, HCG, 1024, 256, 256, 16384, 16384, 256, 65536, 256, 256, 1, 64, 0);
  GEMM128(HCG, mw3T, mb3, AI, 1024, 128, 256, 16384, 8192, 256, 32768, 128, 128, 0, 64, 0); // ce -> AI

  // 8) noise model (input = obs)
  GEMM128(obs, nw1T, nb1, H1, 1024, 256, 128, 8192, 16384, 128, 32768, 256, 256, 1, 64, 0);
  GEMM128(H1, nw2T, nb2, HCG, 1024, 128, 256, 16384, 8192, 256, 32768, 128, 128, 0, 64, 0); // noise -> HCG

  // 9) scm_pred = softmax(scm_causal) @ ce + noise  (MFMA)
  hipLaunchKernelGGL(se_noise_mfma_k, dim3(1024), dim3(256), 0, stream, cw1g, cw2g, AI, HCG, out_scm);
}

// Round 5
// 929.199 us; speedup vs baseline: 1.2761x; 1.0078x over previous
//
#include <hip/hip_runtime.h>
#include <hip/hip_bf16.h>
#include <math.h>

// Problem constants
#define NB 1024    // batch
#define NAG 64     // agents
#define OBS 128
#define ACTD 16
#define HID 256
#define GD 64
#define NH 4       // heads

typedef short bhalf8 __attribute__((ext_vector_type(8)));
typedef float f32x4 __attribute__((ext_vector_type(4)));

__device__ inline unsigned short f2bf_u(float f) {
  __hip_bfloat16 h = __float2bfloat16(f);
  return *(unsigned short*)&h;
}
__device__ inline float bfu2f(unsigned short u) {
  unsigned v = ((unsigned)u) << 16;
  return *(float*)&v;
}
__device__ inline unsigned pk2(float x, float y) {
  float2 f2; f2.x = x; f2.y = y;
  __hip_bfloat162 h = __float22bfloat162_rn(f2);
  return *(unsigned*)&h;
}
// ---- truncation-split helpers (hi/lo bf16 split; rounding mode of hi is
// irrelevant because lo captures the residual exactly; 1-3 bit-ops each) ----
__device__ inline unsigned fbits(float x) { return *(unsigned*)&x; }
__device__ inline float bcast(unsigned u) { return *(float*)&u; }
__device__ inline unsigned pkhi(float x, float y) {  // trunc-pack 2 f32 -> 2 bf16
  return (fbits(x) >> 16) | (fbits(y) & 0xFFFF0000u);
}
__device__ inline float hif(float x) {               // hi part as f32
  return bcast(fbits(x) & 0xFFFF0000u);
}

// ---------------- row softmax ----------------
__global__ __launch_bounds__(64) void softmax_rows_k(const float* __restrict__ in,
                                                     float* __restrict__ out, int n) {
  int row = blockIdx.x;
  int lane = threadIdx.x;
  const float* r = in + (size_t)row * n;
  float m = -INFINITY;
  for (int j = lane; j < n; j += 64) m = fmaxf(m, r[j]);
#pragma unroll
  for (int off = 32; off; off >>= 1) m = fmaxf(m, __shfl_xor(m, off));
  float s = 0.f;
  for (int j = lane; j < n; j += 64) s += expf(r[j] - m);
#pragma unroll
  for (int off = 32; off; off >>= 1) s += __shfl_xor(s, off);
  float inv = 1.f / s;
  for (int j = lane; j < n; j += 64) out[(size_t)row * n + j] = expf(r[j] - m) * inv;
}

// ---------------- cw softmax -> bf16 hi/lo global ----------------
__global__ void cwbf_k(const float* __restrict__ cwsm, unsigned short* __restrict__ cw1,
                       unsigned short* __restrict__ cw2) {
  int idx = blockIdx.x * 256 + threadIdx.x;
  if (idx >= 4096) return;
  float v = cwsm[idx];
  unsigned short hi = f2bf_u(v);
  cw1[idx] = hi;
  cw2[idx] = f2bf_u(v - bfu2f(hi));
}

// ---------------- batched transpose+cvt: in (Z,K,N) f32 -> out (Z,N,K) bf16 ----------------
__global__ __launch_bounds__(256) void transpose_cvt_k(const float* __restrict__ in,
                                                       unsigned short* __restrict__ out,
                                                       int K, int N) {
  __shared__ float t[32][33];
  int k0 = blockIdx.x * 32, n0 = blockIdx.y * 32, z = blockIdx.z;
  int tx = threadIdx.x, ty = threadIdx.y;  // 32 x 8
  const float* ib = in + (size_t)z * K * N;
  unsigned short* ob = out + (size_t)z * N * K;
#pragma unroll
  for (int i = 0; i < 4; ++i) {
    int k = k0 + ty + 8 * i, n = n0 + tx;
    if (k < K && n < N) t[ty + 8 * i][tx] = ib[(size_t)k * N + n];
  }
  __syncthreads();
#pragma unroll
  for (int i = 0; i < 4; ++i) {
    int n = n0 + ty + 8 * i, k = k0 + tx;
    if (n < N && k < K) ob[(size_t)n * K + k] = f2bf_u(t[tx][ty + 8 * i]);
  }
}

// ---------------- GAT weight repack: W (H,F,D) -> WcT bf16 (H*D, F) ----------------
__global__ void repack_wT_k(const float* __restrict__ W, unsigned short* __restrict__ WcT, int F) {
  int idx = blockIdx.x * 256 + threadIdx.x;
  if (idx >= NH * F * 64) return;
  int d = idx & 63;
  int f = (idx >> 6) % F;
  int h = idx / (F * 64);
  WcT[((size_t)(h * 64 + d)) * F + f] = f2bf_u(W[idx]);
}

// ---------------- bf16 MFMA GEMM, 64x64 tile, pipelined (reg-prefetch + LDS ping-pong) ----
__global__ __launch_bounds__(256) void gemm_mfma_k(
    const float* __restrict__ A, const unsigned short* __restrict__ BT,
    const float* __restrict__ bias, float* __restrict__ C,
    int M, int N, int K,
    long long lda, long long ldc,
    long long aBS, long long btBS, long long biasBS, long long cBS,
    int act, int kPerSplit) {
  __shared__ unsigned short As[2][64 * 40];
  __shared__ unsigned short Bs[2][64 * 40];
  int tid = threadIdx.x;
  int wave = tid >> 6, lane = tid & 63;
  int m0 = blockIdx.x * 64, n0 = blockIdx.y * 64;
  int z = blockIdx.z;
  const float* Ab;
  const unsigned short* Bb;
  const float* biasb = nullptr;
  float* Cb;
  int k_begin, k_end;
  if (kPerSplit > 0) {
    Ab = A; Bb = BT; Cb = C + (long long)z * cBS;
    k_begin = z * kPerSplit;
    k_end = k_begin + kPerSplit;
    if (k_end > K) k_end = K;
  } else {
    Ab = A + (long long)z * aBS;
    Bb = BT + (long long)z * btBS;
    if (bias) biasb = bias + (long long)z * biasBS;
    Cb = C + (long long)z * cBS;
    k_begin = 0; k_end = K;
  }
  int sr = tid >> 2;
  int sk = (tid & 3) * 8;
  int fr = lane & 15;
  int kq = (lane >> 4) * 8;

  f32x4 zf = {0.f, 0.f, 0.f, 0.f};
  f32x4 acc[4] = {zf, zf, zf, zf};

  const unsigned short* bRow = Bb + (long long)(n0 + sr) * K;
  bool bValid = (n0 + sr) < N;
  const float* aRow = Ab + (long long)(m0 + sr) * lda;

  int nt = (k_end - k_begin + 31) / 32;

  float av[8];
  uint4 bv;

  auto LOADT = [&](int t) {
    int kk = k_begin + 32 * t + sk;
    if (kk + 7 < k_end) {
      const float* ap = aRow + kk;
      *(float4*)&av[0] = *(const float4*)ap;
      *(float4*)&av[4] = *(const float4*)(ap + 4);
    } else {
#pragma unroll
      for (int j = 0; j < 8; ++j) av[j] = (kk + j < k_end) ? aRow[kk + j] : 0.f;
    }
    bv.x = bv.y = bv.z = bv.w = 0u;
    if (bValid) {
      if (kk + 7 < k_end) {
        bv = *(const uint4*)(bRow + kk);
      } else {
        unsigned short tb[8];
#pragma unroll
        for (int j = 0; j < 8; ++j) tb[j] = (kk + j < k_end) ? bRow[kk + j] : (unsigned short)0;
        bv.x = (unsigned)tb[0] | ((unsigned)tb[1] << 16);
        bv.y = (unsigned)tb[2] | ((unsigned)tb[3] << 16);
        bv.z = (unsigned)tb[4] | ((unsigned)tb[5] << 16);
        bv.w = (unsigned)tb[6] | ((unsigned)tb[7] << 16);
      }
    }
  };
  auto STORE = [&](int buf) {
    uint4 aw;
    aw.x = pk2(av[0], av[1]); aw.y = pk2(av[2], av[3]);
    aw.z = pk2(av[4], av[5]); aw.w = pk2(av[6], av[7]);
    *(uint4*)&As[buf][sr * 40 + sk] = aw;
    *(uint4*)&Bs[buf][sr * 40 + sk] = bv;
  };

  LOADT(0);
  STORE(0);
  if (nt > 1) LOADT(1);
  __syncthreads();

  for (int t = 0; t < nt; ++t) {
    int cur = t & 1;
    if (t + 1 < nt) {
      STORE(cur ^ 1);               // regs hold tile t+1 (loaded last iter)
      if (t + 2 < nt) LOADT(t + 2); // issue next loads; hide under MFMA below
    }
    bhalf8 af = *(bhalf8*)&As[cur][(16 * wave + fr) * 40 + kq];
#pragma unroll
    for (int t4 = 0; t4 < 4; ++t4) {
      bhalf8 bf = *(bhalf8*)&Bs[cur][(16 * t4 + fr) * 40 + kq];
      acc[t4] = __builtin_amdgcn_mfma_f32_16x16x32_bf16(af, bf, acc[t4], 0, 0, 0);
    }
    if (t + 1 < nt) __syncthreads();
  }
  int rb = (lane >> 4) * 4;
#pragma unroll
  for (int t = 0; t < 4; ++t) {
    int col = n0 + 16 * t + fr;
    if (col < N) {
      float bv2 = biasb ? biasb[col] : 0.f;
#pragma unroll
      for (int r = 0; r < 4; ++r) {
        long long row = m0 + 16 * wave + rb + r;
        float v = acc[t][r] + bv2;
        if (act == 1) v = fmaxf(v, 0.f);
        Cb[row * ldc + col] = v;
      }
    }
  }
}

// ---------------- bf16 MFMA GEMM, 128x128 tile, pipelined (reg-prefetch + LDS ping-pong) ----
// Requires M % 128 == 0. N guarded. A (M,K) f32; BT (N,K) bf16.
__global__ __launch_bounds__(256, 4) void gemm_mfma128_k(
    const float* __restrict__ A, const unsigned short* __restrict__ BT,
    const float* __restrict__ bias, float* __restrict__ C,
    int M, int N, int K,
    long long lda, long long ldc,
    long long aBS, long long btBS, long long biasBS, long long cBS,
    int act, int kPerSplit) {
  __shared__ unsigned short As[2][128 * 40];
  __shared__ unsigned short Bs[2][128 * 40];
  int tid = threadIdx.x;
  int wave = tid >> 6, lane = tid & 63;
  int m0 = blockIdx.x * 128, n0 = blockIdx.y * 128;
  int z = blockIdx.z;
  const float* Ab;
  const unsigned short* Bb;
  const float* biasb = nullptr;
  float* Cb;
  int k_begin, k_end;
  if (kPerSplit > 0) {
    Ab = A; Bb = BT; Cb = C + (long long)z * cBS;
    k_begin = z * kPerSplit;
    k_end = k_begin + kPerSplit;
    if (k_end > K) k_end = K;
  } else {
    Ab = A + (long long)z * aBS;
    Bb = BT + (long long)z * btBS;
    if (bias) biasb = bias + (long long)z * biasBS;
    Cb = C + (long long)z * cBS;
    k_begin = 0; k_end = K;
  }
  int sr = tid >> 1;          // staging row 0..127
  int sk = (tid & 1) * 16;    // k-half
  int mq = (wave >> 1) * 64;  // wave quadrant
  int nq = (wave & 1) * 64;
  int fr = lane & 15;
  int kq = (lane >> 4) * 8;

  f32x4 zf = {0.f, 0.f, 0.f, 0.f};
  f32x4 acc[4][4];
#pragma unroll
  for (int i = 0; i < 4; ++i)
#pragma unroll
    for (int j = 0; j < 4; ++j) acc[i][j] = zf;

  const float* aRow = Ab + (long long)(m0 + sr) * lda;
  const unsigned short* bRow = Bb + (long long)(n0 + sr) * K;
  bool bValid = (n0 + sr) < N;

  int nt = (k_end - k_begin + 31) / 32;

  float av[16];
  uint4 bv0, bv1;

  auto LOADT = [&](int t) {
    int kk = k_begin + 32 * t + sk;
    if (kk + 15 < k_end) {
      const float* ap = aRow + kk;
      *(float4*)&av[0]  = *(const float4*)ap;
      *(float4*)&av[4]  = *(const float4*)(ap + 4);
      *(float4*)&av[8]  = *(const float4*)(ap + 8);
      *(float4*)&av[12] = *(const float4*)(ap + 12);
    } else {
#pragma unroll
      for (int j = 0; j < 16; ++j) av[j] = (kk + j < k_end) ? aRow[kk + j] : 0.f;
    }
    bv0.x = bv0.y = bv0.z = bv0.w = 0u;
    bv1.x = bv1.y = bv1.z = bv1.w = 0u;
    if (bValid) {
      if (kk + 15 < k_end) {
        bv0 = *(const uint4*)(bRow + kk);
        bv1 = *(const uint4*)(bRow + kk + 8);
      } else {
        unsigned short tb[16];
#pragma unroll
        for (int j = 0; j < 16; ++j) tb[j] = (kk + j < k_end) ? bRow[kk + j] : (unsigned short)0;
        bv0.x = (unsigned)tb[0] | ((unsigned)tb[1] << 16);
        bv0.y = (unsigned)tb[2] | ((unsigned)tb[3] << 16);
        bv0.z = (unsigned)tb[4] | ((unsigned)tb[5] << 16);
        bv0.w = (unsigned)tb[6] | ((unsigned)tb[7] << 16);
        bv1.x = (unsigned)tb[8] | ((unsigned)tb[9] << 16);
        bv1.y = (unsigned)tb[10] | ((unsigned)tb[11] << 16);
        bv1.z = (unsigned)tb[12] | ((unsigned)tb[13] << 16);
        bv1.w = (unsigned)tb[14] | ((unsigned)tb[15] << 16);
      }
    }
  };
  auto STORE = [&](int buf) {
    uint4 aw0, aw1;
    aw0.x = pk2(av[0], av[1]);   aw0.y = pk2(av[2], av[3]);
    aw0.z = pk2(av[4], av[5]);   aw0.w = pk2(av[6], av[7]);
    aw1.x = pk2(av[8], av[9]);   aw1.y = pk2(av[10], av[11]);
    aw1.z = pk2(av[12], av[13]); aw1.w = pk2(av[14], av[15]);
    *(uint4*)&As[buf][sr * 40 + sk] = aw0;
    *(uint4*)&As[buf][sr * 40 + sk + 8] = aw1;
    *(uint4*)&Bs[buf][sr * 40 + sk] = bv0;
    *(uint4*)&Bs[buf][sr * 40 + sk + 8] = bv1;
  };

  LOADT(0);
  STORE(0);
  if (nt > 1) LOADT(1);
  __syncthreads();

  for (int t = 0; t < nt; ++t) {
    int cur = t & 1;
    if (t + 1 < nt) {
      STORE(cur ^ 1);               // regs hold tile t+1 (loaded last iter)
      if (t + 2 < nt) LOADT(t + 2); // issue next loads; hide under MFMA below
    }
    bhalf8 af[4], bf[4];
#pragma unroll
    for (int i = 0; i < 4; ++i) af[i] = *(bhalf8*)&As[cur][(mq + 16 * i + fr) * 40 + kq];
#pragma unroll
    for (int j = 0; j < 4; ++j) bf[j] = *(bhalf8*)&Bs[cur][(nq + 16 * j + fr) * 40 + kq];
#pragma unroll
    for (int i = 0; i < 4; ++i)
#pragma unroll
      for (int j = 0; j < 4; ++j)
        acc[i][j] = __builtin_amdgcn_mfma_f32_16x16x32_bf16(af[i], bf[j], acc[i][j], 0, 0, 0);
    if (t + 1 < nt) __syncthreads();
  }
  // ---- epilogue
  int rb = (lane >> 4) * 4;
#pragma unroll
  for (int j = 0; j < 4; ++j) {
    int col = n0 + nq + 16 * j + fr;
    if (col < N) {
      float bv2 = biasb ? biasb[col] : 0.f;
#pragma unroll
      for (int i = 0; i < 4; ++i) {
#pragma unroll
        for (int r = 0; r < 4; ++r) {
          long long row = m0 + mq + 16 * i + rb + r;
          float v = acc[i][j][r] + bv2;
          if (act == 1) v = fmaxf(v, 0.f);
          Cb[row * ldc + col] = v;
        }
      }
    }
  }
}

// ---------------- GAT attention, 4 waves per graph, head loop inside ----------------
// xt layout: (B*N, NH*GD). mode: 0 = comm = 0.25*sum_h att ; 1 = comm += ; 2 = concat+ELU
// v5: truncation-split bf16 hi/lo (bit-ops, no RNE sequences) + __expf.
__global__ __launch_bounds__(256, 4) void gat_attn4_k(
    const float* __restrict__ xt, const float* __restrict__ a,
    const float* __restrict__ adj, float* __restrict__ out, int mode) {
  int b = blockIdx.x;
  int tid = threadIdx.x;
  int wave = tid >> 6, lane = tid & 63;
  __shared__ unsigned short xT1[64 * 72];  // X^T hi  [d][j]
  __shared__ unsigned short xT2[64 * 72];  // X^T lo
  __shared__ unsigned short P1[64 * 72];   // exp weights hi [i][j]
  __shared__ unsigned short P2[64 * 72];   // exp weights lo
  __shared__ float si_s[64], sj_s[64];

  const float* adjb = adj + (size_t)b * 4096;
  float adjv[16];
#pragma unroll
  for (int r = 0; r < 16; ++r) adjv[r] = adjb[(size_t)(wave * 16 + r) * 64 + lane];

  int lrow = tid >> 2;   // j (agent) this thread projects (phase A1)
  int cg = tid & 3;      // 16-wide column group
  int fr = lane & 15;
  int kq = (lane >> 4) * 8;
  int ibase = wave * 16;

  bhalf8 ones;
#pragma unroll
  for (int u = 0; u < 8; ++u) ones[u] = (short)0x3F80;  // 1.0 bf16

  f32x4 zf = {0.f, 0.f, 0.f, 0.f};
  f32x4 accm[4] = {zf, zf, zf, zf};  // head-mean accum (mode 0/1)

  for (int h = 0; h < 4; ++h) {
    // ---- A2 loads: column gather for X^T (coalesced across lanes; L2-hot)
    const float* xcol = xt + ((size_t)(b * 64 + 16 * wave)) * 256 + h * 64 + lane;
    float v[16];
#pragma unroll
    for (int u = 0; u < 16; ++u) v[u] = xcol[(size_t)u * 256];

    // ---- A1: si/sj projections (row loads)
    const float* xrow = xt + ((size_t)(b * 64 + lrow)) * 256 + h * 64 + cg * 16;
    const float* ah = a + h * 128;
    float p1 = 0.f, p2 = 0.f;
#pragma unroll
    for (int q = 0; q < 4; ++q) {
      float4 rv = *(const float4*)(xrow + 4 * q);
      int c = cg * 16 + 4 * q;
      p1 += rv.x * ah[c] + rv.y * ah[c + 1] + rv.z * ah[c + 2] + rv.w * ah[c + 3];
      p2 += rv.x * ah[64 + c] + rv.y * ah[64 + c + 1] + rv.z * ah[64 + c + 2] + rv.w * ah[64 + c + 3];
    }
    p1 += __shfl_xor(p1, 1); p1 += __shfl_xor(p1, 2);
    p2 += __shfl_xor(p2, 1); p2 += __shfl_xor(p2, 2);
    if (cg == 0) { si_s[lrow] = p1; sj_s[lrow] = p2; }

    // ---- A2 stores: trunc hi/lo split, b128 writes (row d=lane, j block 16*wave)
    {
      float lo[16];
      uint4 h0, h1, l0, l1;
#pragma unroll
      for (int u = 0; u < 16; ++u) lo[u] = v[u] - hif(v[u]);
      h0.x = pkhi(v[0], v[1]);    h0.y = pkhi(v[2], v[3]);
      h0.z = pkhi(v[4], v[5]);    h0.w = pkhi(v[6], v[7]);
      h1.x = pkhi(v[8], v[9]);    h1.y = pkhi(v[10], v[11]);
      h1.z = pkhi(v[12], v[13]);  h1.w = pkhi(v[14], v[15]);
      l0.x = pkhi(lo[0], lo[1]);   l0.y = pkhi(lo[2], lo[3]);
      l0.z = pkhi(lo[4], lo[5]);   l0.w = pkhi(lo[6], lo[7]);
      l1.x = pkhi(lo[8], lo[9]);   l1.y = pkhi(lo[10], lo[11]);
      l1.z = pkhi(lo[12], lo[13]); l1.w = pkhi(lo[14], lo[15]);
      int base = lane * 72 + 16 * wave;
      *(uint4*)&xT1[base] = h0;
      *(uint4*)&xT1[base + 8] = h1;
      *(uint4*)&xT2[base] = l0;
      *(uint4*)&xT2[base + 8] = l1;
    }
    __syncthreads();

    // ---- B: per-row exp weights, no reductions
    float sjv = sj_s[lane];
    float maxsj = sjv;
#pragma unroll
    for (int off = 32; off; off >>= 1) maxsj = fmaxf(maxsj, __shfl_xor(maxsj, off));
#pragma unroll
    for (int r = 0; r < 16; ++r) {
      int i = ibase + r;
      float siv = si_s[i];
      float tM = siv + maxsj;
      float Mi = tM > 0.f ? tM : 0.2f * tM;   // >= max_j e (leaky monotone)
      float e = siv + sjv;
      e = e > 0.f ? e : 0.2f * e;
      float p = (adjv[r] == 0.f) ? 0.f : __expf(e - Mi);
      unsigned up = fbits(p);
      float phf = bcast(up & 0xFFFF0000u);
      P1[i * 72 + lane] = (unsigned short)(up >> 16);
      float plo = p - phf;
      P2[i * 72 + lane] = (unsigned short)(fbits(plo) >> 16);
    }
    // P rows are wave-local (written and read by the same wave) -> no barrier.

    // ---- C: MFMA aggregation + row sums
    bhalf8 a1[2], a2[2];
#pragma unroll
    for (int ks = 0; ks < 2; ++ks) {
      a1[ks] = *(bhalf8*)&P1[(ibase + fr) * 72 + ks * 32 + kq];
      a2[ks] = *(bhalf8*)&P2[(ibase + fr) * 72 + ks * 32 + kq];
    }
    f32x4 accS = zf;
#pragma unroll
    for (int ks = 0; ks < 2; ++ks) {
      accS = __builtin_amdgcn_mfma_f32_16x16x32_bf16(a1[ks], ones, accS, 0, 0, 0);
      accS = __builtin_amdgcn_mfma_f32_16x16x32_bf16(a2[ks], ones, accS, 0, 0, 0);
    }
    f32x4 acc[4] = {zf, zf, zf, zf};
#pragma unroll
    for (int ks = 0; ks < 2; ++ks) {
#pragma unroll
      for (int t = 0; t < 4; ++t) {
        bhalf8 b1 = *(bhalf8*)&xT1[(16 * t + fr) * 72 + ks * 32 + kq];
        bhalf8 b2 = *(bhalf8*)&xT2[(16 * t + fr) * 72 + ks * 32 + kq];
        acc[t] = __builtin_amdgcn_mfma_f32_16x16x32_bf16(a1[ks], b1, acc[t], 0, 0, 0);
        acc[t] = __builtin_amdgcn_mfma_f32_16x16x32_bf16(a1[ks], b2, acc[t], 0, 0, 0);
        acc[t] = __builtin_amdgcn_mfma_f32_16x16x32_bf16(a2[ks], b1, acc[t], 0, 0, 0);
      }
    }
    f32x4 inv;
#pragma unroll
    for (int r = 0; r < 4; ++r) inv[r] = (accS[r] > 0.f) ? 1.f / accS[r] : 0.f;

    int rb = (lane >> 4) * 4;
    if (mode == 2) {
#pragma unroll
      for (int t = 0; t < 4; ++t) {
#pragma unroll
        for (int r = 0; r < 4; ++r) {
          int i = ibase + rb + r;
          float vv = acc[t][r] * inv[r];
          vv = vv > 0.f ? vv : __expf(vv) - 1.f;
          out[((size_t)(b * 64 + i)) * 256 + h * 64 + 16 * t + fr] = vv;
        }
      }
    } else {
#pragma unroll
      for (int t = 0; t < 4; ++t)
#pragma unroll
        for (int r = 0; r < 4; ++r) accm[t][r] += 0.25f * acc[t][r] * inv[r];
    }
    __syncthreads();  // xT/si/sj reuse for next head
  }

  if (mode != 2) {
    int rb = (lane >> 4) * 4;
    float* cb = out + (size_t)b * 4096;
#pragma unroll
    for (int t = 0; t < 4; ++t) {
#pragma unroll
      for (int r = 0; r < 4; ++r) {
        int i = ibase + rb + r;
        int col = 16 * t + fr;
        if (mode == 1) cb[i * 64 + col] += accm[t][r];
        else cb[i * 64 + col] = accm[t][r];
      }
    }
  }
}

// ---------------- ai = [obs, comm] (B,N,192) ----------------
__global__ void build_ai_k(const float* __restrict__ obs, const float* __restrict__ comm,
                           float* __restrict__ ai) {
  size_t idx = (size_t)blockIdx.x * 256 + threadIdx.x;
  if (idx >= (size_t)NB * NAG * 192) return;
  int c = (int)(idx % 192);
  size_t bn = idx / 192;
  ai[idx] = (c < 128) ? obs[bn * 128 + c] : comm[bn * 64 + (c - 128)];
}

// ---------------- combined = [obs, actions] (B,N,144) ----------------
__global__ void build_combined_k(const float* __restrict__ obs, const float* __restrict__ act,
                                 float* __restrict__ cmb) {
  size_t idx = (size_t)blockIdx.x * 256 + threadIdx.x;
  if (idx >= (size_t)NB * NAG * 144) return;
  int c = (int)(idx % 144);
  size_t bn = idx / 144;
  cmb[idx] = (c < 128) ? obs[bn * 128 + c] : act[bn * 16 + (c - 128)];
}

// ---------------- split-K reduce + bias + relu for cent l1 ----------------
__global__ void reduce_bias_relu_k(const float* __restrict__ part, const float* __restrict__ bias,
                                   float* __restrict__ out) {
  int idx = blockIdx.x * 256 + threadIdx.x;
  float s = 0.f;
#pragma unroll
  for (int zz = 0; zz < 16; ++zz) s += part[(size_t)zz * 262144 + idx];
  s += bias[idx & 255];
  out[idx] = fmaxf(s, 0.f);
}

// ---------------- scm_pred = cw @ ce + noise (MFMA, hi/lo split) ----------------
__global__ __launch_bounds__(256, 4) void se_noise_mfma_k(
    const unsigned short* __restrict__ cw1, const unsigned short* __restrict__ cw2,
    const float* __restrict__ ce, const float* __restrict__ nz,
    float* __restrict__ out) {
  int b = blockIdx.x;
  int tid = threadIdx.x;
  int wave = tid >> 6, lane = tid & 63;
  __shared__ unsigned short xT1[128 * 72];  // ce^T hi [d][j]
  __shared__ unsigned short xT2[128 * 72];  // ce^T lo

  int dd = tid & 127;
  int jh = tid >> 7;  // 0 or 1 -> j block of 32
  const float* cecol = ce + (size_t)b * 8192 + dd;
#pragma unroll
  for (int c = 0; c < 2; ++c) {
    int j0 = jh * 32 + c * 16;
    float v[16], lo[16];
#pragma unroll
    for (int u = 0; u < 16; ++u) v[u] = cecol[(size_t)(j0 + u) * 128];
#pragma unroll
    for (int u = 0; u < 16; ++u) lo[u] = v[u] - hif(v[u]);
    uint4 h0, h1, l0, l1;
    h0.x = pkhi(v[0], v[1]);    h0.y = pkhi(v[2], v[3]);
    h0.z = pkhi(v[4], v[5]);    h0.w = pkhi(v[6], v[7]);
    h1.x = pkhi(v[8], v[9]);    h1.y = pkhi(v[10], v[11]);
    h1.z = pkhi(v[12], v[13]);  h1.w = pkhi(v[14], v[15]);
    l0.x = pkhi(lo[0], lo[1]);   l0.y = pkhi(lo[2], lo[3]);
    l0.z = pkhi(lo[4], lo[5]);   l0.w = pkhi(lo[6], lo[7]);
    l1.x = pkhi(lo[8], lo[9]);   l1.y = pkhi(lo[10], lo[11]);
    l1.z = pkhi(lo[12], lo[13]); l1.w = pkhi(lo[14], lo[15]);
    int base = dd * 72 + j0;
    *(uint4*)&xT1[base] = h0;
    *(uint4*)&xT1[base + 8] = h1;
    *(uint4*)&xT2[base] = l0;
    *(uint4*)&xT2[base + 8] = l1;
  }
  __syncthreads();

  int fr = lane & 15;
  int kq = (lane >> 4) * 8;
  int dq = wave * 32;

  bhalf8 bb1[2][2], bb2[2][2];
#pragma unroll
  for (int dt = 0; dt < 2; ++dt)
#pragma unroll
    for (int ks = 0; ks < 2; ++ks) {
      bb1[dt][ks] = *(bhalf8*)&xT1[(dq + dt * 16 + fr) * 72 + ks * 32 + kq];
      bb2[dt][ks] = *(bhalf8*)&xT2[(dq + dt * 16 + fr) * 72 + ks * 32 + kq];
    }

  f32x4 zf = {0.f, 0.f, 0.f, 0.f};
  f32x4 acc[4][2];
#pragma unroll
  for (int it = 0; it < 4; ++it)
#pragma unroll
    for (int dt = 0; dt < 2; ++dt) acc[it][dt] = zf;

#pragma unroll
  for (int it = 0; it < 4; ++it) {
    bhalf8 a1[2], a2[2];
#pragma unroll
    for (int ks = 0; ks < 2; ++ks) {
      a1[ks] = *(const bhalf8*)(cw1 + (it * 16 + fr) * 64 + ks * 32 + kq);
      a2[ks] = *(const bhalf8*)(cw2 + (it * 16 + fr) * 64 + ks * 32 + kq);
    }
#pragma unroll
    for (int dt = 0; dt < 2; ++dt)
#pragma unroll
      for (int ks = 0; ks < 2; ++ks) {
        acc[it][dt] = __builtin_amdgcn_mfma_f32_16x16x32_bf16(a1[ks], bb1[dt][ks], acc[it][dt], 0, 0, 0);
        acc[it][dt] = __builtin_amdgcn_mfma_f32_16x16x32_bf16(a1[ks], bb2[dt][ks], acc[it][dt], 0, 0, 0);
        acc[it][dt] = __builtin_amdgcn_mfma_f32_16x16x32_bf16(a2[ks], bb1[dt][ks], acc[it][dt], 0, 0, 0);
      }
  }

  int rb = (lane >> 4) * 4;
#pragma unroll
  for (int it = 0; it < 4; ++it)
#pragma unroll
    for (int dt = 0; dt < 2; ++dt) {
      int dcol = dq + dt * 16 + fr;
#pragma unroll
      for (int r = 0; r < 4; ++r) {
        int i = it * 16 + rb + r;
        size_t off = (size_t)b * 8192 + (size_t)i * 128 + dcol;
        out[off] = acc[it][dt][r] + nz[off];
      }
    }
}

extern "C" void kernel_launch(void* const* d_in, const int* in_sizes, int n_in,
                              void* d_out, int out_size, void* d_ws, size_t ws_size,
                              hipStream_t stream) {
  (void)in_sizes; (void)n_in; (void)out_size; (void)ws_size;
  const float* obs = (const float*)d_in[0];
  const float* acts = (const float*)d_in[1];
  const float* adj = (const float*)d_in[2];
  const float* causal = (const float*)d_in[3];
  const float* gat_W = (const float*)d_in[4];
  const float* gat_a = (const float*)d_in[5];
  const float* cg_W0 = (const float*)d_in[6];
  const float* cg_a0 = (const float*)d_in[7];
  const float* cg_W1 = (const float*)d_in[8];
  const float* cg_a1 = (const float*)d_in[9];
  const float* aw1 = (const float*)d_in[10]; const float* ab1 = (const float*)d_in[11];
  const float* aw2 = (const float*)d_in[12]; const float* ab2 = (const float*)d_in[13];
  const float* aw3 = (const float*)d_in[14]; const float* ab3 = (const float*)d_in[15];
  const float* crw1 = (const float*)d_in[16]; const float* crb1 = (const float*)d_in[17];
  const float* crw2 = (const float*)d_in[18]; const float* crb2 = (const float*)d_in[19];
  const float* crw3 = (const float*)d_in[20]; const float* crb3 = (const float*)d_in[21];
  const float* cew1 = (const float*)d_in[22]; const float* ceb1 = (const float*)d_in[23];
  const float* cew2 = (const float*)d_in[24]; const float* ceb2 = (const float*)d_in[25];
  const float* cew3 = (const float*)d_in[26]; const float* ceb3 = (const float*)d_in[27];
  const float* scm_causal = (const float*)d_in[28];
  const float* mw1 = (const float*)d_in[29]; const float* mb1 = (const float*)d_in[30];
  const float* mw2 = (const float*)d_in[31]; const float* mb2 = (const float*)d_in[32];
  const float* mw3 = (const float*)d_in[33]; const float* mb3 = (const float*)d_in[34];
  const float* nw1 = (const float*)d_in[35]; const float* nb1 = (const float*)d_in[36];
  const float* nw2 = (const float*)d_in[37]; const float* nb2 = (const float*)d_in[38];

  // workspace layout (floats); total 65,515,520 floats = 249.9 MiB
  float* ws = (float*)d_ws;
  float* Ssm  = ws;               // 16384 (dead after TRN -> reused for cw1g/cw2g)
  float* cwsm = ws + 16384;       // 4096
  float* comm = ws + 20480;       // 4,194,304  (B,N,64)
  float* AI   = ws + 4214784;     // 12,582,912 (B,N,192): ai -> combined -> ce
  float* H1   = ws + 16797696;    // 16,777,216 (B,N,256)
  float* HCG  = ws + 33574912;    // 16,777,216 (B,N,256)
  unsigned short* wbf = (unsigned short*)(ws + 50352128);  // bf16 weights
  unsigned short* SsmT  = wbf;             // 16384
  unsigned short* wcT   = wbf + 16384;     // 65536 (reused per GAT layer)
  unsigned short* aw1T  = wbf + 81920;     // 3,145,728
  unsigned short* aw2T  = wbf + 3227648;   // 4,194,304
  unsigned short* aw3T  = wbf + 7421952;   // 262,144
  unsigned short* crw1T = wbf + 7684096;   // 3,145,728
  unsigned short* crw2T = wbf + 10829824;  // 4,194,304
  unsigned short* crw3T = wbf + 15024128;  // 16,384
  unsigned short* cew1T = wbf + 15040512;  // 2,359,296
  unsigned short* cew2T = wbf + 17399808;  // 65,536
  unsigned short* cew3T = wbf + 17465344;  // 16,384
  unsigned short* mw1T  = wbf + 17481728;  // 2,359,296
  unsigned short* mw2T  = wbf + 19841024;  // 4,194,304
  unsigned short* mw3T  = wbf + 24035328;  // 2,097,152
  unsigned short* nw1T  = wbf + 26132480;  // 2,097,152
  unsigned short* nw2T  = wbf + 28229632;  // 2,097,152
  // cw bf16 hi/lo live in the dead Ssm region (after TRN(Ssm) has consumed it)
  unsigned short* cw1g = (unsigned short*)ws;   // 4096
  unsigned short* cw2g = cw1g + 4096;           // 4096

  float* out_actor = (float*)d_out;
  float* out_critic = out_actor + 1048576;
  float* out_cent = out_critic + 65536;
  float* out_scm = out_cent + 65536;

  auto GEMM64 = [&](const float* A, const unsigned short* BT, const float* bias, float* C,
                    int M, int N, int K, long long lda, long long ldc,
                    long long aBS, long long btBS, long long biasBS, long long cBS,
                    int act, int gz, int kPerSplit) {
    dim3 grid(M / 64, (N + 63) / 64, gz);
    hipLaunchKernelGGL(gemm_mfma_k, grid, dim3(256), 0, stream, A, BT, bias, C, M, N, K,
                       lda, ldc, aBS, btBS, biasBS, cBS, act, kPerSplit);
  };
  auto GEMM128 = [&](const float* A, const unsigned short* BT, const float* bias, float* C,
                     int M, int N, int K, long long lda, long long ldc,
                     long long aBS, long long btBS, long long biasBS, long long cBS,
                     int act, int gz, int kPerSplit) {
    dim3 grid(M / 128, (N + 127) / 128, gz);
    hipLaunchKernelGGL(gemm_mfma128_k, grid, dim3(256), 0, stream, A, BT, bias, C, M, N, K,
                       lda, ldc, aBS, btBS, biasBS, cBS, act, kPerSplit);
  };
  auto TRN = [&](const float* in, unsigned short* out, int Z, int K, int N) {
    dim3 grid((K + 31) / 32, (N + 31) / 32, Z);
    hipLaunchKernelGGL(transpose_cvt_k, grid, dim3(32, 8), 0, stream, in, out, K, N);
  };

  // 0) small softmaxes + weight conversions (one-time per launch)
  hipLaunchKernelGGL(softmax_rows_k, dim3(128), dim3(64), 0, stream, causal, Ssm, 128);
  hipLaunchKernelGGL(softmax_rows_k, dim3(64), dim3(64), 0, stream, scm_causal, cwsm, 64);
  TRN(Ssm, SsmT, 1, 128, 128);
  hipLaunchKernelGGL(cwbf_k, dim3(16), dim3(256), 0, stream, cwsm, cw1g, cw2g);  // after TRN(Ssm)
  TRN(aw1, aw1T, 64, 192, 256);  TRN(aw2, aw2T, 64, 256, 256);  TRN(aw3, aw3T, 64, 256, 16);
  TRN(crw1, crw1T, 64, 192, 256); TRN(crw2, crw2T, 64, 256, 256); TRN(crw3, crw3T, 64, 256, 1);
  TRN(cew1, cew1T, 1, 9216, 256); TRN(cew2, cew2T, 1, 256, 256);  TRN(cew3, cew3T, 1, 256, 64);
  TRN(mw1, mw1T, 64, 144, 256);  TRN(mw2, mw2T, 64, 256, 256);  TRN(mw3, mw3T, 64, 256, 128);
  TRN(nw1, nw1T, 64, 128, 256);  TRN(nw2, nw2T, 64, 256, 128);

  // 1) plain GAT -> comm (init)
  hipLaunchKernelGGL(repack_wT_k, dim3((NH * 128 * 64 + 255) / 256), dim3(256), 0, stream, gat_W, wcT, 128);
  GEMM128(obs, wcT, nullptr, H1, 65536, 256, 128, 128, 256, 0, 0, 0, 0, 0, 1, 0);     // xt1
  hipLaunchKernelGGL(gat_attn4_k, dim3(1024), dim3(256), 0, stream, H1, gat_a, adj, comm, 0);

  // 2) causal GAT
  GEMM128(obs, SsmT, nullptr, HCG, 65536, 128, 128, 128, 128, 0, 0, 0, 0, 0, 1, 0);   // xm
  hipLaunchKernelGGL(repack_wT_k, dim3((NH * 128 * 64 + 255) / 256), dim3(256), 0, stream, cg_W0, wcT, 128);
  GEMM128(HCG, wcT, nullptr, H1, 65536, 256, 128, 128, 256, 0, 0, 0, 0, 0, 1, 0);     // xt_cg0
  hipLaunchKernelGGL(gat_attn4_k, dim3(1024), dim3(256), 0, stream, H1, cg_a0, adj, HCG, 2); // hcg (ELU)
  hipLaunchKernelGGL(repack_wT_k, dim3((NH * 256 * 64 + 255) / 256), dim3(256), 0, stream, cg_W1, wcT, 256);
  GEMM128(HCG, wcT, nullptr, H1, 65536, 256, 256, 256, 256, 0, 0, 0, 0, 0, 1, 0);     // xt_cg1
  hipLaunchKernelGGL(gat_attn4_k, dim3(1024), dim3(256), 0, stream, H1, cg_a1, adj, comm, 1);

  // 3) ai = [obs, comm]
  hipLaunchKernelGGL(build_ai_k, dim3((12582912 + 255) / 256), dim3(256), 0, stream, obs, comm, AI);

  // 4) actor MLP (per-agent)
  GEMM128(AI, aw1T, ab1, H1, 1024, 256, 192, 12288, 16384, 192, 49152, 256, 256, 1, 64, 0);
  GEMM128(H1, aw2T, ab2, HCG, 1024, 256, 256, 16384, 16384, 256, 65536, 256, 256, 1, 64, 0);
  GEMM64(HCG, aw3T, ab3, out_actor, 1024, 16, 256, 16384, 1024, 256, 4096, 16, 16, 0, 64, 0);

  // 5) critic MLP (per-agent)
  GEMM128(AI, crw1T, crb1, H1, 1024, 256, 192, 12288, 16384, 192, 49152, 256, 256, 1, 64, 0);
  GEMM128(H1, crw2T, crb2, HCG, 1024, 256, 256, 16384, 16384, 256, 65536, 256, 256, 1, 64, 0);
  GEMM64(HCG, crw3T, crb3, out_critic, 1024, 1, 256, 16384, 64, 256, 256, 1, 1, 0, 64, 0);

  // 6) centralized critic (combined -> AI)
  hipLaunchKernelGGL(build_combined_k, dim3((9437184 + 255) / 256), dim3(256), 0, stream, obs, acts, AI);
  GEMM128(AI, cew1T, nullptr, H1, 1024, 256, 9216, 9216, 256, 0, 0, 0, 262144, 0, 16, 576);
  hipLaunchKernelGGL(reduce_bias_relu_k, dim3(1024), dim3(256), 0, stream, H1, ceb1, HCG);
  GEMM64(HCG, cew2T, ceb2, H1, 1024, 256, 256, 256, 256, 0, 0, 0, 0, 1, 1, 0);
  GEMM64(H1, cew3T, ceb3, out_cent, 1024, 64, 256, 256, 64, 0, 0, 0, 0, 0, 1, 0);

  // 7) SCM mechanisms (input = combined in AI)
  GEMM128(AI, mw1T, mb1, H1, 1024, 256, 144, 9216, 16384, 144, 36864, 256, 256, 1, 64, 0);
  GEMM128(H1, mw2T, mb2, HCG, 1024, 256, 256, 16384, 16384, 256, 65536, 256, 256, 1, 64, 0);
  GEMM128(HCG, mw3T, mb3, AI, 1024, 128, 256, 16384, 8192, 256, 32768, 128, 128, 0, 64, 0); // ce -> AI

  // 8) noise model (input = obs)
  GEMM128(obs, nw1T, nb1, H1, 1024, 256, 128, 8192, 16384, 128, 32768, 256, 256, 1, 64, 0);
  GEMM128(H1, nw2T, nb2, HCG, 1024, 128, 256, 16384, 8192, 256, 32768, 128, 128, 0, 64, 0); // noise -> HCG

  // 9) scm_pred = softmax(scm_causal) @ ce + noise  (MFMA)
  hipLaunchKernelGGL(se_noise_mfma_k, dim3(1024), dim3(256), 0, stream, cw1g, cw2g, AI, HCG, out_scm);
}

// Round 6
// 906.371 us; speedup vs baseline: 1.3082x; 1.0252x over previous
//
#include <hip/hip_runtime.h>
#include <hip/hip_bf16.h>
#include <math.h>

// Problem constants
#define NB 1024    // batch
#define NAG 64     // agents
#define OBS 128
#define ACTD 16
#define HID 256
#define GD 64
#define NH 4       // heads

typedef short bhalf8 __attribute__((ext_vector_type(8)));
typedef float f32x4 __attribute__((ext_vector_type(4)));

__device__ inline unsigned short f2bf_u(float f) {
  __hip_bfloat16 h = __float2bfloat16(f);
  return *(unsigned short*)&h;
}
__device__ inline float bfu2f(unsigned short u) {
  unsigned v = ((unsigned)u) << 16;
  return *(float*)&v;
}
__device__ inline unsigned pk2(float x, float y) {
  float2 f2; f2.x = x; f2.y = y;
  __hip_bfloat162 h = __float22bfloat162_rn(f2);
  return *(unsigned*)&h;
}
// ---- truncation-split helpers (hi/lo bf16 split) ----
__device__ inline unsigned fbits(float x) { return *(unsigned*)&x; }
__device__ inline float bcast(unsigned u) { return *(float*)&u; }
__device__ inline unsigned pkhi(float x, float y) {
  return (fbits(x) >> 16) | (fbits(y) & 0xFFFF0000u);
}
__device__ inline float hif(float x) {
  return bcast(fbits(x) & 0xFFFF0000u);
}

// ---------------- row softmax ----------------
__global__ __launch_bounds__(64) void softmax_rows_k(const float* __restrict__ in,
                                                     float* __restrict__ out, int n) {
  int row = blockIdx.x;
  int lane = threadIdx.x;
  const float* r = in + (size_t)row * n;
  float m = -INFINITY;
  for (int j = lane; j < n; j += 64) m = fmaxf(m, r[j]);
#pragma unroll
  for (int off = 32; off; off >>= 1) m = fmaxf(m, __shfl_xor(m, off));
  float s = 0.f;
  for (int j = lane; j < n; j += 64) s += expf(r[j] - m);
#pragma unroll
  for (int off = 32; off; off >>= 1) s += __shfl_xor(s, off);
  float inv = 1.f / s;
  for (int j = lane; j < n; j += 64) out[(size_t)row * n + j] = expf(r[j] - m) * inv;
}

// ---------------- cw softmax -> bf16 hi/lo global ----------------
__global__ void cwbf_k(const float* __restrict__ cwsm, unsigned short* __restrict__ cw1,
                       unsigned short* __restrict__ cw2) {
  int idx = blockIdx.x * 256 + threadIdx.x;
  if (idx >= 4096) return;
  float v = cwsm[idx];
  unsigned short hi = f2bf_u(v);
  cw1[idx] = hi;
  cw2[idx] = f2bf_u(v - bfu2f(hi));
}

// ---------------- batched transpose+cvt: in (Z,K,N) f32 -> out (Z,N,K) bf16 ----------------
__global__ __launch_bounds__(256) void transpose_cvt_k(const float* __restrict__ in,
                                                       unsigned short* __restrict__ out,
                                                       int K, int N) {
  __shared__ float t[32][33];
  int k0 = blockIdx.x * 32, n0 = blockIdx.y * 32, z = blockIdx.z;
  int tx = threadIdx.x, ty = threadIdx.y;  // 32 x 8
  const float* ib = in + (size_t)z * K * N;
  unsigned short* ob = out + (size_t)z * N * K;
#pragma unroll
  for (int i = 0; i < 4; ++i) {
    int k = k0 + ty + 8 * i, n = n0 + tx;
    if (k < K && n < N) t[ty + 8 * i][tx] = ib[(size_t)k * N + n];
  }
  __syncthreads();
#pragma unroll
  for (int i = 0; i < 4; ++i) {
    int n = n0 + ty + 8 * i, k = k0 + tx;
    if (n < N && k < K) ob[(size_t)n * K + k] = f2bf_u(t[tx][ty + 8 * i]);
  }
}

// ---------------- GAT weight repack: W (H,F,D) -> WcT bf16 (H*D, F) ----------------
__global__ void repack_wT_k(const float* __restrict__ W, unsigned short* __restrict__ WcT, int F) {
  int idx = blockIdx.x * 256 + threadIdx.x;
  if (idx >= NH * F * 64) return;
  int d = idx & 63;
  int f = (idx >> 6) % F;
  int h = idx / (F * 64);
  WcT[((size_t)(h * 64 + d)) * F + f] = f2bf_u(W[idx]);
}

// ---------------- bf16 MFMA GEMM, 64x64 tile, pipelined, dual-dtype A/C ----------------
// aBf: A rows are bf16 (pass-through). cBf: C stored as bf16 RNE.
__global__ __launch_bounds__(256) void gemm_mfma_k(
    const void* __restrict__ A, const unsigned short* __restrict__ BT,
    const float* __restrict__ bias, void* __restrict__ C,
    int M, int N, int K,
    long long lda, long long ldc,
    long long aBS, long long btBS, long long biasBS, long long cBS,
    int act, int kPerSplit, int aBf, int cBf) {
  __shared__ unsigned short As[2][64 * 40];
  __shared__ unsigned short Bs[2][64 * 40];
  int tid = threadIdx.x;
  int wave = tid >> 6, lane = tid & 63;
  int m0 = blockIdx.x * 64, n0 = blockIdx.y * 64;
  int z = blockIdx.z;
  long long aOff, cOff;
  const unsigned short* Bb;
  const float* biasb = nullptr;
  int k_begin, k_end;
  if (kPerSplit > 0) {
    aOff = 0; Bb = BT; cOff = (long long)z * cBS;
    k_begin = z * kPerSplit;
    k_end = k_begin + kPerSplit;
    if (k_end > K) k_end = K;
  } else {
    aOff = (long long)z * aBS;
    Bb = BT + (long long)z * btBS;
    if (bias) biasb = bias + (long long)z * biasBS;
    cOff = (long long)z * cBS;
    k_begin = 0; k_end = K;
  }
  int sr = tid >> 2;
  int sk = (tid & 3) * 8;
  int fr = lane & 15;
  int kq = (lane >> 4) * 8;

  f32x4 zf = {0.f, 0.f, 0.f, 0.f};
  f32x4 acc[4] = {zf, zf, zf, zf};

  const unsigned short* bRow = Bb + (long long)(n0 + sr) * K;
  bool bValid = (n0 + sr) < N;
  const float* aRowF = (const float*)A + aOff + (long long)(m0 + sr) * lda;
  const unsigned short* aRowH = (const unsigned short*)A + aOff + (long long)(m0 + sr) * lda;
  float* CbF = (float*)C + cOff;
  unsigned short* CbH = (unsigned short*)C + cOff;

  int nt = (k_end - k_begin + 31) / 32;

  float av[8];
  uint4 awh;
  uint4 bv;

  auto LOADT = [&](int t) {
    int kk = k_begin + 32 * t + sk;
    if (aBf) {
      if (kk + 7 < k_end) {
        awh = *(const uint4*)(aRowH + kk);
      } else {
        unsigned short ta[8];
#pragma unroll
        for (int j = 0; j < 8; ++j) ta[j] = (kk + j < k_end) ? aRowH[kk + j] : (unsigned short)0;
        awh.x = (unsigned)ta[0] | ((unsigned)ta[1] << 16);
        awh.y = (unsigned)ta[2] | ((unsigned)ta[3] << 16);
        awh.z = (unsigned)ta[4] | ((unsigned)ta[5] << 16);
        awh.w = (unsigned)ta[6] | ((unsigned)ta[7] << 16);
      }
    } else {
      if (kk + 7 < k_end) {
        const float* ap = aRowF + kk;
        *(float4*)&av[0] = *(const float4*)ap;
        *(float4*)&av[4] = *(const float4*)(ap + 4);
      } else {
#pragma unroll
        for (int j = 0; j < 8; ++j) av[j] = (kk + j < k_end) ? aRowF[kk + j] : 0.f;
      }
    }
    bv.x = bv.y = bv.z = bv.w = 0u;
    if (bValid) {
      if (kk + 7 < k_end) {
        bv = *(const uint4*)(bRow + kk);
      } else {
        unsigned short tb[8];
#pragma unroll
        for (int j = 0; j < 8; ++j) tb[j] = (kk + j < k_end) ? bRow[kk + j] : (unsigned short)0;
        bv.x = (unsigned)tb[0] | ((unsigned)tb[1] << 16);
        bv.y = (unsigned)tb[2] | ((unsigned)tb[3] << 16);
        bv.z = (unsigned)tb[4] | ((unsigned)tb[5] << 16);
        bv.w = (unsigned)tb[6] | ((unsigned)tb[7] << 16);
      }
    }
  };
  auto STORE = [&](int buf) {
    uint4 aw;
    if (aBf) {
      aw = awh;
    } else {
      aw.x = pk2(av[0], av[1]); aw.y = pk2(av[2], av[3]);
      aw.z = pk2(av[4], av[5]); aw.w = pk2(av[6], av[7]);
    }
    *(uint4*)&As[buf][sr * 40 + sk] = aw;
    *(uint4*)&Bs[buf][sr * 40 + sk] = bv;
  };

  LOADT(0);
  STORE(0);
  if (nt > 1) LOADT(1);
  __syncthreads();

  for (int t = 0; t < nt; ++t) {
    int cur = t & 1;
    if (t + 1 < nt) {
      STORE(cur ^ 1);
      if (t + 2 < nt) LOADT(t + 2);
    }
    bhalf8 af = *(bhalf8*)&As[cur][(16 * wave + fr) * 40 + kq];
#pragma unroll
    for (int t4 = 0; t4 < 4; ++t4) {
      bhalf8 bf = *(bhalf8*)&Bs[cur][(16 * t4 + fr) * 40 + kq];
      acc[t4] = __builtin_amdgcn_mfma_f32_16x16x32_bf16(af, bf, acc[t4], 0, 0, 0);
    }
    if (t + 1 < nt) __syncthreads();
  }
  int rb = (lane >> 4) * 4;
#pragma unroll
  for (int t = 0; t < 4; ++t) {
    int col = n0 + 16 * t + fr;
    if (col < N) {
      float bv2 = biasb ? biasb[col] : 0.f;
#pragma unroll
      for (int r = 0; r < 4; ++r) {
        long long row = m0 + 16 * wave + rb + r;
        float v = acc[t][r] + bv2;
        if (act == 1) v = fmaxf(v, 0.f);
        if (cBf) CbH[row * ldc + col] = f2bf_u(v);
        else CbF[row * ldc + col] = v;
      }
    }
  }
}

// ---------------- bf16 MFMA GEMM, 128x128 tile, pipelined, dual-dtype A/C ----------------
// Requires M % 128 == 0. N guarded.
__global__ __launch_bounds__(256, 4) void gemm_mfma128_k(
    const void* __restrict__ A, const unsigned short* __restrict__ BT,
    const float* __restrict__ bias, void* __restrict__ C,
    int M, int N, int K,
    long long lda, long long ldc,
    long long aBS, long long btBS, long long biasBS, long long cBS,
    int act, int kPerSplit, int aBf, int cBf) {
  __shared__ unsigned short As[2][128 * 40];
  __shared__ unsigned short Bs[2][128 * 40];
  int tid = threadIdx.x;
  int wave = tid >> 6, lane = tid & 63;
  int m0 = blockIdx.x * 128, n0 = blockIdx.y * 128;
  int z = blockIdx.z;
  long long aOff, cOff;
  const unsigned short* Bb;
  const float* biasb = nullptr;
  int k_begin, k_end;
  if (kPerSplit > 0) {
    aOff = 0; Bb = BT; cOff = (long long)z * cBS;
    k_begin = z * kPerSplit;
    k_end = k_begin + kPerSplit;
    if (k_end > K) k_end = K;
  } else {
    aOff = (long long)z * aBS;
    Bb = BT + (long long)z * btBS;
    if (bias) biasb = bias + (long long)z * biasBS;
    cOff = (long long)z * cBS;
    k_begin = 0; k_end = K;
  }
  int sr = tid >> 1;          // staging row 0..127
  int sk = (tid & 1) * 16;    // k-half
  int mq = (wave >> 1) * 64;  // wave quadrant
  int nq = (wave & 1) * 64;
  int fr = lane & 15;
  int kq = (lane >> 4) * 8;

  f32x4 zf = {0.f, 0.f, 0.f, 0.f};
  f32x4 acc[4][4];
#pragma unroll
  for (int i = 0; i < 4; ++i)
#pragma unroll
    for (int j = 0; j < 4; ++j) acc[i][j] = zf;

  const float* aRowF = (const float*)A + aOff + (long long)(m0 + sr) * lda;
  const unsigned short* aRowH = (const unsigned short*)A + aOff + (long long)(m0 + sr) * lda;
  const unsigned short* bRow = Bb + (long long)(n0 + sr) * K;
  bool bValid = (n0 + sr) < N;
  float* CbF = (float*)C + cOff;
  unsigned short* CbH = (unsigned short*)C + cOff;

  int nt = (k_end - k_begin + 31) / 32;

  float av[16];
  uint4 awh0, awh1;
  uint4 bv0, bv1;

  auto LOADT = [&](int t) {
    int kk = k_begin + 32 * t + sk;
    if (aBf) {
      if (kk + 15 < k_end) {
        awh0 = *(const uint4*)(aRowH + kk);
        awh1 = *(const uint4*)(aRowH + kk + 8);
      } else {
        unsigned short ta[16];
#pragma unroll
        for (int j = 0; j < 16; ++j) ta[j] = (kk + j < k_end) ? aRowH[kk + j] : (unsigned short)0;
        awh0.x = (unsigned)ta[0] | ((unsigned)ta[1] << 16);
        awh0.y = (unsigned)ta[2] | ((unsigned)ta[3] << 16);
        awh0.z = (unsigned)ta[4] | ((unsigned)ta[5] << 16);
        awh0.w = (unsigned)ta[6] | ((unsigned)ta[7] << 16);
        awh1.x = (unsigned)ta[8] | ((unsigned)ta[9] << 16);
        awh1.y = (unsigned)ta[10] | ((unsigned)ta[11] << 16);
        awh1.z = (unsigned)ta[12] | ((unsigned)ta[13] << 16);
        awh1.w = (unsigned)ta[14] | ((unsigned)ta[15] << 16);
      }
    } else {
      if (kk + 15 < k_end) {
        const float* ap = aRowF + kk;
        *(float4*)&av[0]  = *(const float4*)ap;
        *(float4*)&av[4]  = *(const float4*)(ap + 4);
        *(float4*)&av[8]  = *(const float4*)(ap + 8);
        *(float4*)&av[12] = *(const float4*)(ap + 12);
      } else {
#pragma unroll
        for (int j = 0; j < 16; ++j) av[j] = (kk + j < k_end) ? aRowF[kk + j] : 0.f;
      }
    }
    bv0.x = bv0.y = bv0.z = bv0.w = 0u;
    bv1.x = bv1.y = bv1.z = bv1.w = 0u;
    if (bValid) {
      if (kk + 15 < k_end) {
        bv0 = *(const uint4*)(bRow + kk);
        bv1 = *(const uint4*)(bRow + kk + 8);
      } else {
        unsigned short tb[16];
#pragma unroll
        for (int j = 0; j < 16; ++j) tb[j] = (kk + j < k_end) ? bRow[kk + j] : (unsigned short)0;
        bv0.x = (unsigned)tb[0] | ((unsigned)tb[1] << 16);
        bv0.y = (unsigned)tb[2] | ((unsigned)tb[3] << 16);
        bv0.z = (unsigned)tb[4] | ((unsigned)tb[5] << 16);
        bv0.w = (unsigned)tb[6] | ((unsigned)tb[7] << 16);
        bv1.x = (unsigned)tb[8] | ((unsigned)tb[9] << 16);
        bv1.y = (unsigned)tb[10] | ((unsigned)tb[11] << 16);
        bv1.z = (unsigned)tb[12] | ((unsigned)tb[13] << 16);
        bv1.w = (unsigned)tb[14] | ((unsigned)tb[15] << 16);
      }
    }
  };
  auto STORE = [&](int buf) {
    uint4 aw0, aw1;
    if (aBf) {
      aw0 = awh0; aw1 = awh1;
    } else {
      aw0.x = pk2(av[0], av[1]);   aw0.y = pk2(av[2], av[3]);
      aw0.z = pk2(av[4], av[5]);   aw0.w = pk2(av[6], av[7]);
      aw1.x = pk2(av[8], av[9]);   aw1.y = pk2(av[10], av[11]);
      aw1.z = pk2(av[12], av[13]); aw1.w = pk2(av[14], av[15]);
    }
    *(uint4*)&As[buf][sr * 40 + sk] = aw0;
    *(uint4*)&As[buf][sr * 40 + sk + 8] = aw1;
    *(uint4*)&Bs[buf][sr * 40 + sk] = bv0;
    *(uint4*)&Bs[buf][sr * 40 + sk + 8] = bv1;
  };

  LOADT(0);
  STORE(0);
  if (nt > 1) LOADT(1);
  __syncthreads();

  for (int t = 0; t < nt; ++t) {
    int cur = t & 1;
    if (t + 1 < nt) {
      STORE(cur ^ 1);
      if (t + 2 < nt) LOADT(t + 2);
    }
    bhalf8 af[4], bf[4];
#pragma unroll
    for (int i = 0; i < 4; ++i) af[i] = *(bhalf8*)&As[cur][(mq + 16 * i + fr) * 40 + kq];
#pragma unroll
    for (int j = 0; j < 4; ++j) bf[j] = *(bhalf8*)&Bs[cur][(nq + 16 * j + fr) * 40 + kq];
#pragma unroll
    for (int i = 0; i < 4; ++i)
#pragma unroll
      for (int j = 0; j < 4; ++j)
        acc[i][j] = __builtin_amdgcn_mfma_f32_16x16x32_bf16(af[i], bf[j], acc[i][j], 0, 0, 0);
    if (t + 1 < nt) __syncthreads();
  }
  // ---- epilogue
  int rb = (lane >> 4) * 4;
#pragma unroll
  for (int j = 0; j < 4; ++j) {
    int col = n0 + nq + 16 * j + fr;
    if (col < N) {
      float bv2 = biasb ? biasb[col] : 0.f;
#pragma unroll
      for (int i = 0; i < 4; ++i) {
#pragma unroll
        for (int r = 0; r < 4; ++r) {
          long long row = m0 + mq + 16 * i + rb + r;
          float v = acc[i][j][r] + bv2;
          if (act == 1) v = fmaxf(v, 0.f);
          if (cBf) CbH[row * ldc + col] = f2bf_u(v);
          else CbF[row * ldc + col] = v;
        }
      }
    }
  }
}

// ---------------- GAT attention, 4 waves per graph, head loop inside ----------------
// xt layout: (B*N, NH*GD). mode: 0 = comm = 0.25*sum_h att ; 1 = comm += ; 2 = concat+ELU
// mode 2 writes bf16 (RNE) -- consumer is the next GEMM which would truncate anyway.
__global__ __launch_bounds__(256, 4) void gat_attn4_k(
    const float* __restrict__ xt, const float* __restrict__ a,
    const float* __restrict__ adj, float* __restrict__ out, int mode) {
  int b = blockIdx.x;
  int tid = threadIdx.x;
  int wave = tid >> 6, lane = tid & 63;
  __shared__ unsigned short xT1[64 * 72];  // X^T hi  [d][j]
  __shared__ unsigned short xT2[64 * 72];  // X^T lo
  __shared__ unsigned short P1[64 * 72];   // exp weights hi [i][j]
  __shared__ unsigned short P2[64 * 72];   // exp weights lo
  __shared__ float si_s[64], sj_s[64];

  const float* adjb = adj + (size_t)b * 4096;
  float adjv[16];
#pragma unroll
  for (int r = 0; r < 16; ++r) adjv[r] = adjb[(size_t)(wave * 16 + r) * 64 + lane];

  int lrow = tid >> 2;   // j (agent) this thread projects (phase A1)
  int cg = tid & 3;      // 16-wide column group
  int fr = lane & 15;
  int kq = (lane >> 4) * 8;
  int ibase = wave * 16;

  bhalf8 ones;
#pragma unroll
  for (int u = 0; u < 8; ++u) ones[u] = (short)0x3F80;  // 1.0 bf16

  f32x4 zf = {0.f, 0.f, 0.f, 0.f};
  f32x4 accm[4] = {zf, zf, zf, zf};  // head-mean accum (mode 0/1)

  for (int h = 0; h < 4; ++h) {
    // ---- A2 loads: column gather for X^T (coalesced across lanes; L2-hot)
    const float* xcol = xt + ((size_t)(b * 64 + 16 * wave)) * 256 + h * 64 + lane;
    float v[16];
#pragma unroll
    for (int u = 0; u < 16; ++u) v[u] = xcol[(size_t)u * 256];

    // ---- A1: si/sj projections (row loads)
    const float* xrow = xt + ((size_t)(b * 64 + lrow)) * 256 + h * 64 + cg * 16;
    const float* ah = a + h * 128;
    float p1 = 0.f, p2 = 0.f;
#pragma unroll
    for (int q = 0; q < 4; ++q) {
      float4 rv = *(const float4*)(xrow + 4 * q);
      int c = cg * 16 + 4 * q;
      p1 += rv.x * ah[c] + rv.y * ah[c + 1] + rv.z * ah[c + 2] + rv.w * ah[c + 3];
      p2 += rv.x * ah[64 + c] + rv.y * ah[64 + c + 1] + rv.z * ah[64 + c + 2] + rv.w * ah[64 + c + 3];
    }
    p1 += __shfl_xor(p1, 1); p1 += __shfl_xor(p1, 2);
    p2 += __shfl_xor(p2, 1); p2 += __shfl_xor(p2, 2);
    if (cg == 0) { si_s[lrow] = p1; sj_s[lrow] = p2; }

    // ---- A2 stores: trunc hi/lo split, b128 writes (row d=lane, j block 16*wave)
    {
      float lo[16];
      uint4 h0, h1, l0, l1;
#pragma unroll
      for (int u = 0; u < 16; ++u) lo[u] = v[u] - hif(v[u]);
      h0.x = pkhi(v[0], v[1]);    h0.y = pkhi(v[2], v[3]);
      h0.z = pkhi(v[4], v[5]);    h0.w = pkhi(v[6], v[7]);
      h1.x = pkhi(v[8], v[9]);    h1.y = pkhi(v[10], v[11]);
      h1.z = pkhi(v[12], v[13]);  h1.w = pkhi(v[14], v[15]);
      l0.x = pkhi(lo[0], lo[1]);   l0.y = pkhi(lo[2], lo[3]);
      l0.z = pkhi(lo[4], lo[5]);   l0.w = pkhi(lo[6], lo[7]);
      l1.x = pkhi(lo[8], lo[9]);   l1.y = pkhi(lo[10], lo[11]);
      l1.z = pkhi(lo[12], lo[13]); l1.w = pkhi(lo[14], lo[15]);
      int base = lane * 72 + 16 * wave;
      *(uint4*)&xT1[base] = h0;
      *(uint4*)&xT1[base + 8] = h1;
      *(uint4*)&xT2[base] = l0;
      *(uint4*)&xT2[base + 8] = l1;
    }
    __syncthreads();

    // ---- B: per-row exp weights, no reductions
    float sjv = sj_s[lane];
    float maxsj = sjv;
#pragma unroll
    for (int off = 32; off; off >>= 1) maxsj = fmaxf(maxsj, __shfl_xor(maxsj, off));
#pragma unroll
    for (int r = 0; r < 16; ++r) {
      int i = ibase + r;
      float siv = si_s[i];
      float tM = siv + maxsj;
      float Mi = tM > 0.f ? tM : 0.2f * tM;   // >= max_j e (leaky monotone)
      float e = siv + sjv;
      e = e > 0.f ? e : 0.2f * e;
      float p = (adjv[r] == 0.f) ? 0.f : __expf(e - Mi);
      unsigned up = fbits(p);
      float phf = bcast(up & 0xFFFF0000u);
      P1[i * 72 + lane] = (unsigned short)(up >> 16);
      float plo = p - phf;
      P2[i * 72 + lane] = (unsigned short)(fbits(plo) >> 16);
    }
    // P rows are wave-local (written and read by the same wave) -> no barrier.

    // ---- C: MFMA aggregation + row sums
    bhalf8 a1[2], a2[2];
#pragma unroll
    for (int ks = 0; ks < 2; ++ks) {
      a1[ks] = *(bhalf8*)&P1[(ibase + fr) * 72 + ks * 32 + kq];
      a2[ks] = *(bhalf8*)&P2[(ibase + fr) * 72 + ks * 32 + kq];
    }
    f32x4 accS = zf;
#pragma unroll
    for (int ks = 0; ks < 2; ++ks) {
      accS = __builtin_amdgcn_mfma_f32_16x16x32_bf16(a1[ks], ones, accS, 0, 0, 0);
      accS = __builtin_amdgcn_mfma_f32_16x16x32_bf16(a2[ks], ones, accS, 0, 0, 0);
    }
    f32x4 acc[4] = {zf, zf, zf, zf};
#pragma unroll
    for (int ks = 0; ks < 2; ++ks) {
#pragma unroll
      for (int t = 0; t < 4; ++t) {
        bhalf8 b1 = *(bhalf8*)&xT1[(16 * t + fr) * 72 + ks * 32 + kq];
        bhalf8 b2 = *(bhalf8*)&xT2[(16 * t + fr) * 72 + ks * 32 + kq];
        acc[t] = __builtin_amdgcn_mfma_f32_16x16x32_bf16(a1[ks], b1, acc[t], 0, 0, 0);
        acc[t] = __builtin_amdgcn_mfma_f32_16x16x32_bf16(a1[ks], b2, acc[t], 0, 0, 0);
        acc[t] = __builtin_amdgcn_mfma_f32_16x16x32_bf16(a2[ks], b1, acc[t], 0, 0, 0);
      }
    }
    f32x4 inv;
#pragma unroll
    for (int r = 0; r < 4; ++r) inv[r] = (accS[r] > 0.f) ? 1.f / accS[r] : 0.f;

    int rb = (lane >> 4) * 4;
    if (mode == 2) {
      unsigned short* outh = (unsigned short*)out;
#pragma unroll
      for (int t = 0; t < 4; ++t) {
#pragma unroll
        for (int r = 0; r < 4; ++r) {
          int i = ibase + rb + r;
          float vv = acc[t][r] * inv[r];
          vv = vv > 0.f ? vv : __expf(vv) - 1.f;
          outh[((size_t)(b * 64 + i)) * 256 + h * 64 + 16 * t + fr] = f2bf_u(vv);
        }
      }
    } else {
#pragma unroll
      for (int t = 0; t < 4; ++t)
#pragma unroll
        for (int r = 0; r < 4; ++r) accm[t][r] += 0.25f * acc[t][r] * inv[r];
    }
    __syncthreads();  // xT/si/sj reuse for next head
  }

  if (mode != 2) {
    int rb = (lane >> 4) * 4;
    float* cb = out + (size_t)b * 4096;
#pragma unroll
    for (int t = 0; t < 4; ++t) {
#pragma unroll
      for (int r = 0; r < 4; ++r) {
        int i = ibase + rb + r;
        int col = 16 * t + fr;
        if (mode == 1) cb[i * 64 + col] += accm[t][r];
        else cb[i * 64 + col] = accm[t][r];
      }
    }
  }
}

// ---------------- ai = [obs, comm] (B,N,192) -> bf16 ----------------
__global__ void build_ai_k(const float* __restrict__ obs, const float* __restrict__ comm,
                           unsigned short* __restrict__ ai) {
  size_t idx = (size_t)blockIdx.x * 256 + threadIdx.x;
  if (idx >= (size_t)NB * NAG * 192) return;
  int c = (int)(idx % 192);
  size_t bn = idx / 192;
  float v = (c < 128) ? obs[bn * 128 + c] : comm[bn * 64 + (c - 128)];
  ai[idx] = f2bf_u(v);
}

// ---------------- combined = [obs, actions] (B,N,144) -> bf16 ----------------
__global__ void build_combined_k(const float* __restrict__ obs, const float* __restrict__ act,
                                 unsigned short* __restrict__ cmb) {
  size_t idx = (size_t)blockIdx.x * 256 + threadIdx.x;
  if (idx >= (size_t)NB * NAG * 144) return;
  int c = (int)(idx % 144);
  size_t bn = idx / 144;
  float v = (c < 128) ? obs[bn * 128 + c] : act[bn * 16 + (c - 128)];
  cmb[idx] = f2bf_u(v);
}

// ---------------- split-K reduce + bias + relu for cent l1 (bf16 out) ----------------
__global__ void reduce_bias_relu_k(const float* __restrict__ part, const float* __restrict__ bias,
                                   unsigned short* __restrict__ out) {
  int idx = blockIdx.x * 256 + threadIdx.x;
  float s = 0.f;
#pragma unroll
  for (int zz = 0; zz < 16; ++zz) s += part[(size_t)zz * 262144 + idx];
  s += bias[idx & 255];
  out[idx] = f2bf_u(fmaxf(s, 0.f));
}

// ---------------- scm_pred = cw @ ce + noise (MFMA, hi/lo split) ----------------
__global__ __launch_bounds__(256, 4) void se_noise_mfma_k(
    const unsigned short* __restrict__ cw1, const unsigned short* __restrict__ cw2,
    const float* __restrict__ ce, const float* __restrict__ nz,
    float* __restrict__ out) {
  int b = blockIdx.x;
  int tid = threadIdx.x;
  int wave = tid >> 6, lane = tid & 63;
  __shared__ unsigned short xT1[128 * 72];  // ce^T hi [d][j]
  __shared__ unsigned short xT2[128 * 72];  // ce^T lo

  int dd = tid & 127;
  int jh = tid >> 7;  // 0 or 1 -> j block of 32
  const float* cecol = ce + (size_t)b * 8192 + dd;
#pragma unroll
  for (int c = 0; c < 2; ++c) {
    int j0 = jh * 32 + c * 16;
    float v[16], lo[16];
#pragma unroll
    for (int u = 0; u < 16; ++u) v[u] = cecol[(size_t)(j0 + u) * 128];
#pragma unroll
    for (int u = 0; u < 16; ++u) lo[u] = v[u] - hif(v[u]);
    uint4 h0, h1, l0, l1;
    h0.x = pkhi(v[0], v[1]);    h0.y = pkhi(v[2], v[3]);
    h0.z = pkhi(v[4], v[5]);    h0.w = pkhi(v[6], v[7]);
    h1.x = pkhi(v[8], v[9]);    h1.y = pkhi(v[10], v[11]);
    h1.z = pkhi(v[12], v[13]);  h1.w = pkhi(v[14], v[15]);
    l0.x = pkhi(lo[0], lo[1]);   l0.y = pkhi(lo[2], lo[3]);
    l0.z = pkhi(lo[4], lo[5]);   l0.w = pkhi(lo[6], lo[7]);
    l1.x = pkhi(lo[8], lo[9]);   l1.y = pkhi(lo[10], lo[11]);
    l1.z = pkhi(lo[12], lo[13]); l1.w = pkhi(lo[14], lo[15]);
    int base = dd * 72 + j0;
    *(uint4*)&xT1[base] = h0;
    *(uint4*)&xT1[base + 8] = h1;
    *(uint4*)&xT2[base] = l0;
    *(uint4*)&xT2[base + 8] = l1;
  }
  __syncthreads();

  int fr = lane & 15;
  int kq = (lane >> 4) * 8;
  int dq = wave * 32;

  bhalf8 bb1[2][2], bb2[2][2];
#pragma unroll
  for (int dt = 0; dt < 2; ++dt)
#pragma unroll
    for (int ks = 0; ks < 2; ++ks) {
      bb1[dt][ks] = *(bhalf8*)&xT1[(dq + dt * 16 + fr) * 72 + ks * 32 + kq];
      bb2[dt][ks] = *(bhalf8*)&xT2[(dq + dt * 16 + fr) * 72 + ks * 32 + kq];
    }

  f32x4 zf = {0.f, 0.f, 0.f, 0.f};
  f32x4 acc[4][2];
#pragma unroll
  for (int it = 0; it < 4; ++it)
#pragma unroll
    for (int dt = 0; dt < 2; ++dt) acc[it][dt] = zf;

#pragma unroll
  for (int it = 0; it < 4; ++it) {
    bhalf8 a1[2], a2[2];
#pragma unroll
    for (int ks = 0; ks < 2; ++ks) {
      a1[ks] = *(const bhalf8*)(cw1 + (it * 16 + fr) * 64 + ks * 32 + kq);
      a2[ks] = *(const bhalf8*)(cw2 + (it * 16 + fr) * 64 + ks * 32 + kq);
    }
#pragma unroll
    for (int dt = 0; dt < 2; ++dt)
#pragma unroll
      for (int ks = 0; ks < 2; ++ks) {
        acc[it][dt] = __builtin_amdgcn_mfma_f32_16x16x32_bf16(a1[ks], bb1[dt][ks], acc[it][dt], 0, 0, 0);
        acc[it][dt] = __builtin_amdgcn_mfma_f32_16x16x32_bf16(a1[ks], bb2[dt][ks], acc[it][dt], 0, 0, 0);
        acc[it][dt] = __builtin_amdgcn_mfma_f32_16x16x32_bf16(a2[ks], bb1[dt][ks], acc[it][dt], 0, 0, 0);
      }
  }

  int rb = (lane >> 4) * 4;
#pragma unroll
  for (int it = 0; it < 4; ++it)
#pragma unroll
    for (int dt = 0; dt < 2; ++dt) {
      int dcol = dq + dt * 16 + fr;
#pragma unroll
      for (int r = 0; r < 4; ++r) {
        int i = it * 16 + rb + r;
        size_t off = (size_t)b * 8192 + (size_t)i * 128 + dcol;
        out[off] = acc[it][dt][r] + nz[off];
      }
    }
}

extern "C" void kernel_launch(void* const* d_in, const int* in_sizes, int n_in,
                              void* d_out, int out_size, void* d_ws, size_t ws_size,
                              hipStream_t stream) {
  (void)in_sizes; (void)n_in; (void)out_size; (void)ws_size;
  const float* obs = (const float*)d_in[0];
  const float* acts = (const float*)d_in[1];
  const float* adj = (const float*)d_in[2];
  const float* causal = (const float*)d_in[3];
  const float* gat_W = (const float*)d_in[4];
  const float* gat_a = (const float*)d_in[5];
  const float* cg_W0 = (const float*)d_in[6];
  const float* cg_a0 = (const float*)d_in[7];
  const float* cg_W1 = (const float*)d_in[8];
  const float* cg_a1 = (const float*)d_in[9];
  const float* aw1 = (const float*)d_in[10]; const float* ab1 = (const float*)d_in[11];
  const float* aw2 = (const float*)d_in[12]; const float* ab2 = (const float*)d_in[13];
  const float* aw3 = (const float*)d_in[14]; const float* ab3 = (const float*)d_in[15];
  const float* crw1 = (const float*)d_in[16]; const float* crb1 = (const float*)d_in[17];
  const float* crw2 = (const float*)d_in[18]; const float* crb2 = (const float*)d_in[19];
  const float* crw3 = (const float*)d_in[20]; const float* crb3 = (const float*)d_in[21];
  const float* cew1 = (const float*)d_in[22]; const float* ceb1 = (const float*)d_in[23];
  const float* cew2 = (const float*)d_in[24]; const float* ceb2 = (const float*)d_in[25];
  const float* cew3 = (const float*)d_in[26]; const float* ceb3 = (const float*)d_in[27];
  const float* scm_causal = (const float*)d_in[28];
  const float* mw1 = (const float*)d_in[29]; const float* mb1 = (const float*)d_in[30];
  const float* mw2 = (const float*)d_in[31]; const float* mb2 = (const float*)d_in[32];
  const float* mw3 = (const float*)d_in[33]; const float* mb3 = (const float*)d_in[34];
  const float* nw1 = (const float*)d_in[35]; const float* nb1 = (const float*)d_in[36];
  const float* nw2 = (const float*)d_in[37]; const float* nb2 = (const float*)d_in[38];

  // workspace layout (floats); total 65,515,520 floats = 249.9 MiB
  float* ws = (float*)d_ws;
  float* Ssm  = ws;               // 16384 (dead after TRN -> reused for cw1g/cw2g)
  float* cwsm = ws + 16384;       // 4096
  float* comm = ws + 20480;       // 4,194,304  (B,N,64) f32
  float* AI   = ws + 4214784;     // 12,582,912: ai(bf16) -> combined(bf16) -> ce(f32)
  float* H1   = ws + 16797696;    // 16,777,216: xt(f32) / MLP activ (bf16) / partials(f32)
  float* HCG  = ws + 33574912;    // 16,777,216: xm,hcg(bf16) / MLP activ (bf16) / noise(f32)
  unsigned short* wbf = (unsigned short*)(ws + 50352128);  // bf16 weights
  unsigned short* SsmT  = wbf;             // 16384
  unsigned short* wcT   = wbf + 16384;     // 65536 (reused per GAT layer)
  unsigned short* aw1T  = wbf + 81920;     // 3,145,728
  unsigned short* aw2T  = wbf + 3227648;   // 4,194,304
  unsigned short* aw3T  = wbf + 7421952;   // 262,144
  unsigned short* crw1T = wbf + 7684096;   // 3,145,728
  unsigned short* crw2T = wbf + 10829824;  // 4,194,304
  unsigned short* crw3T = wbf + 15024128;  // 16,384
  unsigned short* cew1T = wbf + 15040512;  // 2,359,296
  unsigned short* cew2T = wbf + 17399808;  // 65,536
  unsigned short* cew3T = wbf + 17465344;  // 16,384
  unsigned short* mw1T  = wbf + 17481728;  // 2,359,296
  unsigned short* mw2T  = wbf + 19841024;  // 4,194,304
  unsigned short* mw3T  = wbf + 24035328;  // 2,097,152
  unsigned short* nw1T  = wbf + 26132480;  // 2,097,152
  unsigned short* nw2T  = wbf + 28229632;  // 2,097,152
  unsigned short* cw1g = (unsigned short*)ws;   // 4096 (dead Ssm region)
  unsigned short* cw2g = cw1g + 4096;           // 4096
  unsigned short* AIb  = (unsigned short*)AI;
  unsigned short* H1b  = (unsigned short*)H1;
  unsigned short* HCGb = (unsigned short*)HCG;

  float* out_actor = (float*)d_out;
  float* out_critic = out_actor + 1048576;
  float* out_cent = out_critic + 65536;
  float* out_scm = out_cent + 65536;

  auto GEMM64 = [&](const void* A, const unsigned short* BT, const float* bias, void* C,
                    int M, int N, int K, long long lda, long long ldc,
                    long long aBS, long long btBS, long long biasBS, long long cBS,
                    int act, int gz, int kPerSplit, int aBf, int cBf) {
    dim3 grid(M / 64, (N + 63) / 64, gz);
    hipLaunchKernelGGL(gemm_mfma_k, grid, dim3(256), 0, stream, A, BT, bias, C, M, N, K,
                       lda, ldc, aBS, btBS, biasBS, cBS, act, kPerSplit, aBf, cBf);
  };
  auto GEMM128 = [&](const void* A, const unsigned short* BT, const float* bias, void* C,
                     int M, int N, int K, long long lda, long long ldc,
                     long long aBS, long long btBS, long long biasBS, long long cBS,
                     int act, int gz, int kPerSplit, int aBf, int cBf) {
    dim3 grid(M / 128, (N + 127) / 128, gz);
    hipLaunchKernelGGL(gemm_mfma128_k, grid, dim3(256), 0, stream, A, BT, bias, C, M, N, K,
                       lda, ldc, aBS, btBS, biasBS, cBS, act, kPerSplit, aBf, cBf);
  };
  auto TRN = [&](const float* in, unsigned short* out, int Z, int K, int N) {
    dim3 grid((K + 31) / 32, (N + 31) / 32, Z);
    hipLaunchKernelGGL(transpose_cvt_k, grid, dim3(32, 8), 0, stream, in, out, K, N);
  };

  // 0) small softmaxes + weight conversions (one-time per launch)
  hipLaunchKernelGGL(softmax_rows_k, dim3(128), dim3(64), 0, stream, causal, Ssm, 128);
  hipLaunchKernelGGL(softmax_rows_k, dim3(64), dim3(64), 0, stream, scm_causal, cwsm, 64);
  TRN(Ssm, SsmT, 1, 128, 128);
  hipLaunchKernelGGL(cwbf_k, dim3(16), dim3(256), 0, stream, cwsm, cw1g, cw2g);  // after TRN(Ssm)
  TRN(aw1, aw1T, 64, 192, 256);  TRN(aw2, aw2T, 64, 256, 256);  TRN(aw3, aw3T, 64, 256, 16);
  TRN(crw1, crw1T, 64, 192, 256); TRN(crw2, crw2T, 64, 256, 256); TRN(crw3, crw3T, 64, 256, 1);
  TRN(cew1, cew1T, 1, 9216, 256); TRN(cew2, cew2T, 1, 256, 256);  TRN(cew3, cew3T, 1, 256, 64);
  TRN(mw1, mw1T, 64, 144, 256);  TRN(mw2, mw2T, 64, 256, 256);  TRN(mw3, mw3T, 64, 256, 128);
  TRN(nw1, nw1T, 64, 128, 256);  TRN(nw2, nw2T, 64, 256, 128);

  // 1) plain GAT -> comm (init)
  hipLaunchKernelGGL(repack_wT_k, dim3((NH * 128 * 64 + 255) / 256), dim3(256), 0, stream, gat_W, wcT, 128);
  GEMM128(obs, wcT, nullptr, H1, 65536, 256, 128, 128, 256, 0, 0, 0, 0, 0, 1, 0, 0, 0);     // xt1 f32
  hipLaunchKernelGGL(gat_attn4_k, dim3(1024), dim3(256), 0, stream, H1, gat_a, adj, comm, 0);

  // 2) causal GAT
  GEMM128(obs, SsmT, nullptr, HCG, 65536, 128, 128, 128, 128, 0, 0, 0, 0, 0, 1, 0, 0, 1);   // xm bf16
  hipLaunchKernelGGL(repack_wT_k, dim3((NH * 128 * 64 + 255) / 256), dim3(256), 0, stream, cg_W0, wcT, 128);
  GEMM128(HCGb, wcT, nullptr, H1, 65536, 256, 128, 128, 256, 0, 0, 0, 0, 0, 1, 0, 1, 0);    // xt_cg0 f32
  hipLaunchKernelGGL(gat_attn4_k, dim3(1024), dim3(256), 0, stream, H1, cg_a0, adj, HCG, 2); // hcg ELU bf16
  hipLaunchKernelGGL(repack_wT_k, dim3((NH * 256 * 64 + 255) / 256), dim3(256), 0, stream, cg_W1, wcT, 256);
  GEMM128(HCGb, wcT, nullptr, H1, 65536, 256, 256, 256, 256, 0, 0, 0, 0, 0, 1, 0, 1, 0);    // xt_cg1 f32
  hipLaunchKernelGGL(gat_attn4_k, dim3(1024), dim3(256), 0, stream, H1, cg_a1, adj, comm, 1);

  // 3) ai = [obs, comm] -> bf16
  hipLaunchKernelGGL(build_ai_k, dim3((12582912 + 255) / 256), dim3(256), 0, stream, obs, comm, AIb);

  // 4) actor MLP (per-agent), bf16 activations
  GEMM128(AIb, aw1T, ab1, H1b, 1024, 256, 192, 12288, 16384, 192, 49152, 256, 256, 1, 64, 0, 1, 1);
  GEMM128(H1b, aw2T, ab2, HCGb, 1024, 256, 256, 16384, 16384, 256, 65536, 256, 256, 1, 64, 0, 1, 1);
  GEMM64(HCGb, aw3T, ab3, out_actor, 1024, 16, 256, 16384, 1024, 256, 4096, 16, 16, 0, 64, 0, 1, 0);

  // 5) critic MLP (per-agent)
  GEMM128(AIb, crw1T, crb1, H1b, 1024, 256, 192, 12288, 16384, 192, 49152, 256, 256, 1, 64, 0, 1, 1);
  GEMM128(H1b, crw2T, crb2, HCGb, 1024, 256, 256, 16384, 16384, 256, 65536, 256, 256, 1, 64, 0, 1, 1);
  GEMM64(HCGb, crw3T, crb3, out_critic, 1024, 1, 256, 16384, 64, 256, 256, 1, 1, 0, 64, 0, 1, 0);

  // 6) centralized critic (combined bf16 -> AI region)
  hipLaunchKernelGGL(build_combined_k, dim3((9437184 + 255) / 256), dim3(256), 0, stream, obs, acts, AIb);
  GEMM128(AIb, cew1T, nullptr, H1, 1024, 256, 9216, 9216, 256, 0, 0, 0, 262144, 0, 16, 576, 1, 0); // f32 partials
  hipLaunchKernelGGL(reduce_bias_relu_k, dim3(1024), dim3(256), 0, stream, H1, ceb1, HCGb);
  GEMM64(HCGb, cew2T, ceb2, H1b, 1024, 256, 256, 256, 256, 0, 0, 0, 0, 1, 1, 0, 1, 1);
  GEMM64(H1b, cew3T, ceb3, out_cent, 1024, 64, 256, 256, 64, 0, 0, 0, 0, 0, 1, 0, 1, 0);

  // 7) SCM mechanisms (input = combined bf16 in AI)
  GEMM128(AIb, mw1T, mb1, H1b, 1024, 256, 144, 9216, 16384, 144, 36864, 256, 256, 1, 64, 0, 1, 1);
  GEMM128(H1b, mw2T, mb2, HCGb, 1024, 256, 256, 16384, 16384, 256, 65536, 256, 256, 1, 64, 0, 1, 1);
  GEMM128(HCGb, mw3T, mb3, AI, 1024, 128, 256, 16384, 8192, 256, 32768, 128, 128, 0, 64, 0, 1, 0); // ce f32 -> AI

  // 8) noise model (input = obs f32)
  GEMM128(obs, nw1T, nb1, H1b, 1024, 256, 128, 8192, 16384, 128, 32768, 256, 256, 1, 64, 0, 0, 1);
  GEMM128(H1b, nw2T, nb2, HCG, 1024, 128, 256, 16384, 8192, 256, 32768, 128, 128, 0, 64, 0, 1, 0); // noise f32

  // 9) scm_pred = softmax(scm_causal) @ ce + noise  (MFMA)
  hipLaunchKernelGGL(se_noise_mfma_k, dim3(1024), dim3(256), 0, stream, cw1g, cw2g, AI, HCG, out_scm);
}